// Round 1
// baseline (3091.449 us; speedup 1.0000x reference)
//
#include <hip/hip_runtime.h>
#include <hip/hip_bf16.h>

#define A_ 8
#define B_ 4096
#define OBS_ 512
#define ACT_ 64
#define H_ 1024
#define G_ 64
#define N_ 10000
#define E_ 40000

using bf16 = __hip_bfloat16;

__device__ __forceinline__ float wsum(float v) {
#pragma unroll
  for (int off = 32; off >= 1; off >>= 1) v += __shfl_xor(v, off, 64);
  return v;
}

__device__ __forceinline__ float toF(float x) { return x; }
__device__ __forceinline__ float toF(bf16 x) { return __bfloat162float(x); }
__device__ __forceinline__ void storeC(float* p, float v) { *p = v; }
__device__ __forceinline__ void storeC(bf16* p, float v) { *p = __float2bfloat16(v); }

// ---------------- GNN ----------------
__global__ void gnn_l0_k(const int* __restrict__ node_types, const int* __restrict__ node_agents,
                         const float* __restrict__ type_embed, const float* __restrict__ gagent_embed,
                         const float* __restrict__ W, const float* __restrict__ b,
                         const float* __restrict__ g, const float* __restrict__ be,
                         float* __restrict__ h0) {
  int n = blockIdx.x, t = threadIdx.x;  // 64 threads = 1 wave
  __shared__ float x[64];
  int ty = node_types[n], ag = node_agents[n];
  x[t] = (t < 32) ? type_embed[ty * 32 + t] : gagent_embed[ag * 32 + (t - 32)];
  __syncthreads();
  float acc = b[t];
#pragma unroll 8
  for (int i = 0; i < 64; i++) acc += x[i] * W[i * 64 + t];
  acc = fmaxf(acc, 0.f);
  float m = wsum(acc) * (1.f / 64.f);
  float d = acc - m;
  float v = wsum(d * d) * (1.f / 64.f);
  h0[(size_t)n * 64 + t] = d * rsqrtf(v + 1e-5f) * g[t] + be[t];
}

__global__ void edge_k(const int* __restrict__ edges, const float* __restrict__ h0,
                       float* __restrict__ agg, float* __restrict__ deg) {
  int idx = blockIdx.x * 256 + threadIdx.x;
  if (idx >= E_ * 64) return;
  int e = idx >> 6, c = idx & 63;
  int s = edges[e * 2 + 0], d = edges[e * 2 + 1];
  atomicAdd(&agg[(size_t)d * 64 + c], h0[(size_t)s * 64 + c]);
  atomicAdd(&agg[(size_t)s * 64 + c], h0[(size_t)d * 64 + c]);
  if (c == 0) { atomicAdd(&deg[d], 1.f); atomicAdd(&deg[s], 1.f); }
}

__global__ void gnn_l1_k(const float* __restrict__ h0, const float* __restrict__ agg,
                         const float* __restrict__ deg, const float* __restrict__ W,
                         const float* __restrict__ b, const float* __restrict__ g,
                         const float* __restrict__ be, float* __restrict__ h1) {
  int n = blockIdx.x, t = threadIdx.x;  // 64 threads
  __shared__ float x[128];
  x[t] = h0[(size_t)n * 64 + t];
  x[64 + t] = agg[(size_t)n * 64 + t] / fmaxf(deg[n], 1.0f);
  __syncthreads();
  float acc = b[t];
#pragma unroll 8
  for (int i = 0; i < 128; i++) acc += x[i] * W[i * 64 + t];
  acc = fmaxf(acc, 0.f);
  float m = wsum(acc) * (1.f / 64.f);
  float d = acc - m;
  float v = wsum(d * d) * (1.f / 64.f);
  h1[(size_t)n * 64 + t] = d * rsqrtf(v + 1e-5f) * g[t] + be[t];
}

__global__ void colmean_k(const float* __restrict__ h1, float* __restrict__ meanv) {
  int c = blockIdx.x, t = threadIdx.x;
  float s = 0.f;
  for (int n = t; n < N_; n += 256) s += h1[(size_t)n * 64 + c];
  __shared__ float red[256];
  red[t] = s;
  __syncthreads();
  for (int off = 128; off >= 1; off >>= 1) {
    if (t < off) red[t] += red[t + off];
    __syncthreads();
  }
  if (t == 0) meanv[c] = red[0] / (float)N_;
}

__global__ void ge_k(const float* __restrict__ meanv, const float* __restrict__ Wgp,
                     const float* __restrict__ bgp, float* __restrict__ ge) {
  int o = threadIdx.x;
  float s = bgp[o];
  for (int g2 = 0; g2 < 64; g2++) s += meanv[g2] * Wgp[g2 * 64 + o];
  ge[o] = s;
}

__global__ void biasA_k(const float* __restrict__ ge, const float* __restrict__ agent_embed,
                        const float* __restrict__ Wp1, const float* __restrict__ bp1,
                        float* __restrict__ biasA) {
  int idx = blockIdx.x * 256 + threadIdx.x;  // 8192
  int a = idx >> 10, o = idx & 1023;
  float s = bp1[o];
  for (int g2 = 0; g2 < 64; g2++) s += ge[g2] * Wp1[(size_t)(512 + g2) * 1024 + o];
  for (int e = 0; e < 16; e++) s += agent_embed[a * 16 + e] * Wp1[(size_t)(576 + e) * 1024 + o];
  biasA[idx] = s;
}

__global__ void biasV_k(const float* __restrict__ ge, const float* __restrict__ Wv1,
                        const float* __restrict__ bv1, float* __restrict__ biasV) {
  int o = blockIdx.x * 256 + threadIdx.x;
  float s = bv1[o];
  for (int g2 = 0; g2 < 64; g2++) s += ge[g2] * Wv1[(size_t)(4096 + g2) * 1024 + o];
  biasV[o] = s;
}

// ---------------- GEMM (fp32 vector, 128x128x8 / 8x8 per thread) ----------------
// AMODE 0: A row-major MxK.  AMODE 1: "joint" gather A[row][col] = obs[(col>>9)*B_*OBS_ + row*OBS_ + (col&511)]
// BIASMODE 0: bias[col].  BIASMODE 1: bias[(row>>12)*1024 + col]  (per-agent, B_=4096)
template <int BM, int BN, int BK, int TM, int TN, typename TA, typename TC, int AMODE, int BIASMODE, bool RELU>
__launch_bounds__(256)
__global__ void gemm_k(const TA* __restrict__ Ap, const float* __restrict__ Bp,
                       const float* __restrict__ biasp, TC* __restrict__ Cp,
                       int M, int N, int K) {
  __shared__ float As[BK][BM];
  __shared__ float Bs[BK][BN];
  const int tid = threadIdx.x;
  const int tx = tid & 15, ty = tid >> 4;
  const int m0 = blockIdx.y * BM, n0 = blockIdx.x * BN;

  float acc[TM][TN];
#pragma unroll
  for (int i = 0; i < TM; i++)
#pragma unroll
    for (int j = 0; j < TN; j++) acc[i][j] = 0.f;

  for (int k0 = 0; k0 < K; k0 += BK) {
#pragma unroll
    for (int e = tid; e < BM * BK; e += 256) {
      int m = e / BK, kk = e % BK;
      int row = m0 + m, col = k0 + kk;
      float v;
      if (AMODE == 0)
        v = toF(Ap[(size_t)row * K + col]);
      else
        v = toF(Ap[(size_t)(col >> 9) * ((size_t)B_ * OBS_) + (size_t)row * OBS_ + (col & 511)]);
      As[kk][m] = v;
    }
#pragma unroll
    for (int e = tid; e < BK * BN; e += 256) {
      int kk = e / BN, n = e % BN;
      Bs[kk][n] = Bp[(size_t)(k0 + kk) * N + n0 + n];
    }
    __syncthreads();
#pragma unroll
    for (int kk = 0; kk < BK; kk++) {
      float a[TM], b[TN];
#pragma unroll
      for (int i = 0; i < TM; i++) a[i] = As[kk][ty * TM + i];
#pragma unroll
      for (int j = 0; j < TN; j++) b[j] = Bs[kk][tx * TN + j];
#pragma unroll
      for (int i = 0; i < TM; i++)
#pragma unroll
        for (int j = 0; j < TN; j++) acc[i][j] += a[i] * b[j];
    }
    __syncthreads();
  }

#pragma unroll
  for (int i = 0; i < TM; i++) {
    int row = m0 + ty * TM + i;
#pragma unroll
    for (int j = 0; j < TN; j++) {
      int col = n0 + tx * TN + j;
      float bias = (BIASMODE == 0) ? biasp[col] : biasp[((row >> 12) << 10) + col];
      float v = acc[i][j] + bias;
      if (RELU) v = fmaxf(v, 0.f);
      storeC(&Cp[(size_t)row * N + col], v);
    }
  }
}

__global__ void v3_k(const bf16* __restrict__ hv2, const float* __restrict__ Wv3,
                     const float* __restrict__ bv3, float* __restrict__ out) {
  int wid = threadIdx.x >> 6, lane = threadIdx.x & 63;
  int row = blockIdx.x * 4 + wid;
  float s = 0.f;
#pragma unroll
  for (int k = lane; k < 1024; k += 64) s += __bfloat162float(hv2[(size_t)row * 1024 + k]) * Wv3[k];
  s = wsum(s);
  if (lane == 0) out[row] = s + bv3[0];
}

extern "C" void kernel_launch(void* const* d_in, const int* in_sizes, int n_in,
                              void* d_out, int out_size, void* d_ws, size_t ws_size,
                              hipStream_t stream) {
  const float* obs = (const float*)d_in[0];
  const int* node_types = (const int*)d_in[1];
  const int* node_agents = (const int*)d_in[2];
  const int* edges = (const int*)d_in[3];
  const float* type_embed = (const float*)d_in[4];
  const float* gagent_embed = (const float*)d_in[5];
  const float* W_l0 = (const float*)d_in[6];
  const float* b_l0 = (const float*)d_in[7];
  const float* g_l0 = (const float*)d_in[8];
  const float* be_l0 = (const float*)d_in[9];
  const float* W_l1 = (const float*)d_in[10];
  const float* b_l1 = (const float*)d_in[11];
  const float* g_l1 = (const float*)d_in[12];
  const float* be_l1 = (const float*)d_in[13];
  const float* W_gp = (const float*)d_in[14];
  const float* b_gp = (const float*)d_in[15];
  const float* agent_embed = (const float*)d_in[16];
  const float* Wp1 = (const float*)d_in[17];
  const float* bp1 = (const float*)d_in[18];
  const float* Wp2 = (const float*)d_in[19];
  const float* bp2 = (const float*)d_in[20];
  const float* Wp3 = (const float*)d_in[21];
  const float* bp3 = (const float*)d_in[22];
  const float* Wv1 = (const float*)d_in[23];
  const float* bv1 = (const float*)d_in[24];
  const float* Wv2 = (const float*)d_in[25];
  const float* bv2 = (const float*)d_in[26];
  const float* Wv3 = (const float*)d_in[27];
  const float* bv3 = (const float*)d_in[28];

  char* wsp = (char*)d_ws;
  auto alloc = [&](size_t bytes) {
    char* p = wsp;
    wsp += (bytes + 255) & ~(size_t)255;
    return p;
  };
  float* h0 = (float*)alloc((size_t)N_ * 64 * 4);
  float* agg = (float*)alloc((size_t)N_ * 64 * 4);
  float* deg = (float*)alloc((size_t)N_ * 4);
  float* h1 = (float*)alloc((size_t)N_ * 64 * 4);
  float* meanv = (float*)alloc(64 * 4);
  float* ge = (float*)alloc(64 * 4);
  float* biasA = (float*)alloc(8 * 1024 * 4);
  float* biasV = (float*)alloc(1024 * 4);
  bf16* C1 = (bf16*)alloc((size_t)32768 * 1024 * 2);
  bf16* C2 = (bf16*)alloc((size_t)32768 * 1024 * 2);
  bf16* hv = (bf16*)alloc((size_t)4096 * 1024 * 2);
  bf16* hv2 = (bf16*)alloc((size_t)4096 * 1024 * 2);

  float* logits = (float*)d_out;
  float* value = (float*)d_out + (size_t)A_ * B_ * ACT_;

  hipMemsetAsync(agg, 0, (size_t)N_ * 64 * 4, stream);
  hipMemsetAsync(deg, 0, (size_t)N_ * 4, stream);

  gnn_l0_k<<<N_, 64, 0, stream>>>(node_types, node_agents, type_embed, gagent_embed, W_l0, b_l0, g_l0, be_l0, h0);
  edge_k<<<(E_ * 64) / 256, 256, 0, stream>>>(edges, h0, agg, deg);
  gnn_l1_k<<<N_, 64, 0, stream>>>(h0, agg, deg, W_l1, b_l1, g_l1, be_l1, h1);
  colmean_k<<<64, 256, 0, stream>>>(h1, meanv);
  ge_k<<<1, 64, 0, stream>>>(meanv, W_gp, b_gp, ge);
  biasA_k<<<32, 256, 0, stream>>>(ge, agent_embed, Wp1, bp1, biasA);
  biasV_k<<<4, 256, 0, stream>>>(ge, Wv1, bv1, biasV);

  // P1: hp1 = relu(obs2d @ Wp1[0:512] + biasA[a])   (32768x512)@(512x1024)
  gemm_k<128, 128, 8, 8, 8, float, bf16, 0, 1, true>
      <<<dim3(1024 / 128, 32768 / 128), 256, 0, stream>>>(obs, Wp1, biasA, C1, 32768, 1024, 512);
  // P2: hp2 = relu(hp1 @ Wp2 + bp2)                 (32768x1024)@(1024x1024)
  gemm_k<128, 128, 8, 8, 8, bf16, bf16, 0, 0, true>
      <<<dim3(8, 256), 256, 0, stream>>>(C1, Wp2, bp2, C2, 32768, 1024, 1024);
  // P3: logits = hp2 @ Wp3 + bp3                    (32768x1024)@(1024x64)
  gemm_k<128, 64, 8, 8, 4, bf16, float, 0, 0, false>
      <<<dim3(1, 256), 256, 0, stream>>>(C2, Wp3, bp3, logits, 32768, 64, 1024);
  // V1: hv = relu(joint @ Wv1[0:4096] + biasV)      (4096x4096)@(4096x1024), joint gathered from obs
  gemm_k<128, 128, 8, 8, 8, float, bf16, 1, 0, true>
      <<<dim3(8, 32), 256, 0, stream>>>(obs, Wv1, biasV, hv, 4096, 1024, 4096);
  // V2: hv2 = relu(hv @ Wv2 + bv2)                  (4096x1024)@(1024x1024)
  gemm_k<128, 128, 8, 8, 8, bf16, bf16, 0, 0, true>
      <<<dim3(8, 32), 256, 0, stream>>>(hv, Wv2, bv2, hv2, 4096, 1024, 1024);
  // V3: value = hv2 @ Wv3 + bv3
  v3_k<<<1024, 256, 0, stream>>>(hv2, Wv3, bv3, value);
}

// Round 2
// 438.677 us; speedup vs baseline: 7.0472x; 7.0472x over previous
//
#include <hip/hip_runtime.h>
#include <hip/hip_bf16.h>

#define A_ 8
#define B_ 4096
#define OBS_ 512
#define ACT_ 64
#define H_ 1024
#define G_ 64
#define N_ 10000
#define E_ 40000

using bf16 = __hip_bfloat16;
typedef __attribute__((ext_vector_type(8))) short short8;
typedef __attribute__((ext_vector_type(4))) float f32x4;

__device__ __forceinline__ float wsum(float v) {
#pragma unroll
  for (int off = 32; off >= 1; off >>= 1) v += __shfl_xor(v, off, 64);
  return v;
}

__device__ __forceinline__ void storeC(float* p, float v) { *p = v; }
__device__ __forceinline__ void storeC(bf16* p, float v) { *p = __float2bfloat16(v); }

__device__ __forceinline__ unsigned short f2bu(float x) {
  bf16 h = __float2bfloat16(x);
  unsigned short u;
  __builtin_memcpy(&u, &h, 2);
  return u;
}

__device__ __forceinline__ void gload_lds16(const bf16* g, const void* lds_uniform) {
  __builtin_amdgcn_global_load_lds(
      (const __attribute__((address_space(1))) unsigned int*)g,
      (__attribute__((address_space(3))) unsigned int*)lds_uniform, 16, 0, 0);
}

// ---------------- GNN ----------------
__global__ void gnn_l0_k(const int* __restrict__ node_types, const int* __restrict__ node_agents,
                         const float* __restrict__ type_embed, const float* __restrict__ gagent_embed,
                         const float* __restrict__ W, const float* __restrict__ b,
                         const float* __restrict__ g, const float* __restrict__ be,
                         float* __restrict__ h0) {
  int n = blockIdx.x, t = threadIdx.x;  // 64 threads = 1 wave
  __shared__ float x[64];
  int ty = node_types[n], ag = node_agents[n];
  x[t] = (t < 32) ? type_embed[ty * 32 + t] : gagent_embed[ag * 32 + (t - 32)];
  __syncthreads();
  float acc = b[t];
#pragma unroll 8
  for (int i = 0; i < 64; i++) acc += x[i] * W[i * 64 + t];
  acc = fmaxf(acc, 0.f);
  float m = wsum(acc) * (1.f / 64.f);
  float d = acc - m;
  float v = wsum(d * d) * (1.f / 64.f);
  h0[(size_t)n * 64 + t] = d * rsqrtf(v + 1e-5f) * g[t] + be[t];
}

__global__ void edge_k(const int* __restrict__ edges, const float* __restrict__ h0,
                       float* __restrict__ agg, float* __restrict__ deg) {
  int idx = blockIdx.x * 256 + threadIdx.x;
  if (idx >= E_ * 64) return;
  int e = idx >> 6, c = idx & 63;
  int s = edges[e * 2 + 0], d = edges[e * 2 + 1];
  atomicAdd(&agg[(size_t)d * 64 + c], h0[(size_t)s * 64 + c]);
  atomicAdd(&agg[(size_t)s * 64 + c], h0[(size_t)d * 64 + c]);
  if (c == 0) { atomicAdd(&deg[d], 1.f); atomicAdd(&deg[s], 1.f); }
}

__global__ void gnn_l1_k(const float* __restrict__ h0, const float* __restrict__ agg,
                         const float* __restrict__ deg, const float* __restrict__ W,
                         const float* __restrict__ b, const float* __restrict__ g,
                         const float* __restrict__ be, float* __restrict__ h1) {
  int n = blockIdx.x, t = threadIdx.x;  // 64 threads
  __shared__ float x[128];
  x[t] = h0[(size_t)n * 64 + t];
  x[64 + t] = agg[(size_t)n * 64 + t] / fmaxf(deg[n], 1.0f);
  __syncthreads();
  float acc = b[t];
#pragma unroll 8
  for (int i = 0; i < 128; i++) acc += x[i] * W[i * 64 + t];
  acc = fmaxf(acc, 0.f);
  float m = wsum(acc) * (1.f / 64.f);
  float d = acc - m;
  float v = wsum(d * d) * (1.f / 64.f);
  h1[(size_t)n * 64 + t] = d * rsqrtf(v + 1e-5f) * g[t] + be[t];
}

__global__ void colmean_k(const float* __restrict__ h1, float* __restrict__ meanv) {
  int c = blockIdx.x, t = threadIdx.x;
  float s = 0.f;
  for (int n = t; n < N_; n += 256) s += h1[(size_t)n * 64 + c];
  __shared__ float red[256];
  red[t] = s;
  __syncthreads();
  for (int off = 128; off >= 1; off >>= 1) {
    if (t < off) red[t] += red[t + off];
    __syncthreads();
  }
  if (t == 0) meanv[c] = red[0] / (float)N_;
}

__global__ void ge_k(const float* __restrict__ meanv, const float* __restrict__ Wgp,
                     const float* __restrict__ bgp, float* __restrict__ ge) {
  int o = threadIdx.x;
  float s = bgp[o];
  for (int g2 = 0; g2 < 64; g2++) s += meanv[g2] * Wgp[g2 * 64 + o];
  ge[o] = s;
}

__global__ void biasA_k(const float* __restrict__ ge, const float* __restrict__ agent_embed,
                        const float* __restrict__ Wp1, const float* __restrict__ bp1,
                        float* __restrict__ biasA) {
  int idx = blockIdx.x * 256 + threadIdx.x;  // 8192
  int a = idx >> 10, o = idx & 1023;
  float s = bp1[o];
  for (int g2 = 0; g2 < 64; g2++) s += ge[g2] * Wp1[(size_t)(512 + g2) * 1024 + o];
  for (int e = 0; e < 16; e++) s += agent_embed[a * 16 + e] * Wp1[(size_t)(576 + e) * 1024 + o];
  biasA[idx] = s;
}

__global__ void biasV_k(const float* __restrict__ ge, const float* __restrict__ Wv1,
                        const float* __restrict__ bv1, float* __restrict__ biasV) {
  int o = blockIdx.x * 256 + threadIdx.x;
  float s = bv1[o];
  for (int g2 = 0; g2 < 64; g2++) s += ge[g2] * Wv1[(size_t)(4096 + g2) * 1024 + o];
  biasV[o] = s;
}

// ---------------- conversions ----------------
// joint_bf[b][a*512+k] = bf16(obs[a][b][k]); serves P1 (gathered) and V1 (row-major)
__global__ void conv_joint_k(const float* __restrict__ obs, bf16* __restrict__ joint) {
  size_t i = ((size_t)blockIdx.x * 256 + threadIdx.x) * 8;
  int a = (int)(i >> 21);
  int rem = (int)(i & ((1u << 21) - 1));
  int b = rem >> 9, k = rem & 511;
  const float* p = obs + i;
  short8 o;
#pragma unroll
  for (int t = 0; t < 8; t++) o[t] = (short)f2bu(p[t]);
  *(short8*)(joint + (size_t)b * 4096 + a * 512 + k) = o;
}

// Wt[n][k] = bf16(W[k][n]); W row-stride = N
__global__ void wtrans_k(const float* __restrict__ W, bf16* __restrict__ Wt, int K, int N) {
  __shared__ float t[32][33];
  int n0 = blockIdx.x * 32, k0 = blockIdx.y * 32;
  int tx = threadIdx.x & 31, ty = threadIdx.x >> 5;  // 32x8
#pragma unroll
  for (int r = ty; r < 32; r += 8) t[r][tx] = W[(size_t)(k0 + r) * N + n0 + tx];
  __syncthreads();
#pragma unroll
  for (int r = ty; r < 32; r += 8) Wt[(size_t)(n0 + r) * K + k0 + tx] = __float2bfloat16(t[tx][r]);
}

// ---------------- MFMA GEMM (m97 structure: 128-wide tiles, bf16 16x16x32) ----------------
// A: row-major [M][K] bf16 (AMODE 0) or joint-gather (AMODE 1: row -> obs agent blocks)
// Bt: [N][K] bf16 (pre-transposed weights)
// BIASMODE 0: bias[col]; 1: bias[(row>>12)*1024 + col]
template <int WM, int WN, int WAVES_M, int WAVES_N, int AMODE, int BIASMODE, bool RELU, typename TC>
__launch_bounds__(WAVES_M * WAVES_N * 64)
__global__ void mgemm_k(const bf16* __restrict__ Ap, const bf16* __restrict__ Bt,
                        const float* __restrict__ biasp, TC* __restrict__ Cp,
                        int M, int N, int K) {
  constexpr int BM = WAVES_M * WM * 16;
  constexpr int BN = WAVES_N * WN * 16;
  constexpr int NTHR = WAVES_M * WAVES_N * 64;
  __shared__ char smem[(BM + BN) * 64];  // A tile [BM][32]bf16, B tile [BN][32]bf16, 64B rows
  const short8* sv = (const short8*)smem;

  const int tid = threadIdx.x;
  const int wid = tid >> 6, lane = tid & 63;
  const int wm = wid / WAVES_N, wn = wid % WAVES_N;
  const int m0 = blockIdx.y * BM, n0 = blockIdx.x * BN;

  f32x4 acc[WM][WN];
#pragma unroll
  for (int i = 0; i < WM; i++)
#pragma unroll
    for (int j = 0; j < WN; j++) acc[i][j] = (f32x4){0.f, 0.f, 0.f, 0.f};

  // k0-invariant fragment chunk indices (16B units), XOR-swizzled
  int a_ch[WM], b_ch[WN];
  const int cfr = lane >> 4;  // k-chunk 0..3
#pragma unroll
  for (int i = 0; i < WM; i++) {
    int r = wm * WM * 16 + i * 16 + (lane & 15);
    a_ch[i] = r * 4 + (cfr ^ ((r >> 1) & 3));
  }
#pragma unroll
  for (int j = 0; j < WN; j++) {
    int n = wn * WN * 16 + j * 16 + (lane & 15);
    b_ch[j] = BM * 4 + n * 4 + (cfr ^ ((n >> 1) & 3));
  }

  for (int k0 = 0; k0 < K; k0 += 32) {
    // stage A tile (BM*4 16B chunks), swizzled via per-lane global address
#pragma unroll
    for (int it = 0; it < (BM * 4) / NTHR; ++it) {
      int li = it * NTHR + tid;
      int row = li >> 2;
      int c = (li & 3) ^ ((row >> 1) & 3);
      const bf16* g;
      if (AMODE == 0) {
        g = Ap + (size_t)(m0 + row) * K + k0 + c * 8;
      } else {
        int r = m0 + row;
        g = Ap + (((size_t)(r & (B_ - 1))) << 12) + ((r >> 12) << 9) + (k0 + c * 8);
      }
      gload_lds16(g, smem + it * (NTHR * 16) + wid * 1024);
    }
    // stage B tile (BN*4 chunks)
#pragma unroll
    for (int it = 0; it < (BN * 4) / NTHR; ++it) {
      int li = it * NTHR + tid;
      int row = li >> 2;
      int c = (li & 3) ^ ((row >> 1) & 3);
      const bf16* g = Bt + (size_t)(n0 + row) * K + k0 + c * 8;
      gload_lds16(g, smem + BM * 64 + it * (NTHR * 16) + wid * 1024);
    }
    __syncthreads();

    short8 af[WM], bfr[WN];
#pragma unroll
    for (int i = 0; i < WM; i++) af[i] = sv[a_ch[i]];
#pragma unroll
    for (int j = 0; j < WN; j++) bfr[j] = sv[b_ch[j]];
#pragma unroll
    for (int i = 0; i < WM; i++)
#pragma unroll
      for (int j = 0; j < WN; j++)
        acc[i][j] = __builtin_amdgcn_mfma_f32_16x16x32_bf16(af[i], bfr[j], acc[i][j], 0, 0, 0);
    __syncthreads();
  }

  // epilogue: C/D layout col=lane&15, row=(lane>>4)*4+reg (verified m89)
#pragma unroll
  for (int i = 0; i < WM; i++) {
    int rb = m0 + wm * WM * 16 + i * 16 + (lane >> 4) * 4;
#pragma unroll
    for (int j = 0; j < WN; j++) {
      int col = n0 + wn * WN * 16 + j * 16 + (lane & 15);
#pragma unroll
      for (int r = 0; r < 4; r++) {
        int row = rb + r;
        float bias = (BIASMODE == 0) ? biasp[col] : biasp[((row >> 12) << 10) + col];
        float v = acc[i][j][r] + bias;
        if (RELU) v = fmaxf(v, 0.f);
        storeC(&Cp[(size_t)row * N + col], v);
      }
    }
  }
}

__global__ void v3_k(const bf16* __restrict__ hv2, const float* __restrict__ Wv3,
                     const float* __restrict__ bv3, float* __restrict__ out) {
  int wid = threadIdx.x >> 6, lane = threadIdx.x & 63;
  int row = blockIdx.x * 4 + wid;
  float s = 0.f;
#pragma unroll
  for (int k = lane; k < 1024; k += 64) s += __bfloat162float(hv2[(size_t)row * 1024 + k]) * Wv3[k];
  s = wsum(s);
  if (lane == 0) out[row] = s + bv3[0];
}

extern "C" void kernel_launch(void* const* d_in, const int* in_sizes, int n_in,
                              void* d_out, int out_size, void* d_ws, size_t ws_size,
                              hipStream_t stream) {
  const float* obs = (const float*)d_in[0];
  const int* node_types = (const int*)d_in[1];
  const int* node_agents = (const int*)d_in[2];
  const int* edges = (const int*)d_in[3];
  const float* type_embed = (const float*)d_in[4];
  const float* gagent_embed = (const float*)d_in[5];
  const float* W_l0 = (const float*)d_in[6];
  const float* b_l0 = (const float*)d_in[7];
  const float* g_l0 = (const float*)d_in[8];
  const float* be_l0 = (const float*)d_in[9];
  const float* W_l1 = (const float*)d_in[10];
  const float* b_l1 = (const float*)d_in[11];
  const float* g_l1 = (const float*)d_in[12];
  const float* be_l1 = (const float*)d_in[13];
  const float* W_gp = (const float*)d_in[14];
  const float* b_gp = (const float*)d_in[15];
  const float* agent_embed = (const float*)d_in[16];
  const float* Wp1 = (const float*)d_in[17];
  const float* bp1 = (const float*)d_in[18];
  const float* Wp2 = (const float*)d_in[19];
  const float* bp2 = (const float*)d_in[20];
  const float* Wp3 = (const float*)d_in[21];
  const float* bp3 = (const float*)d_in[22];
  const float* Wv1 = (const float*)d_in[23];
  const float* bv1 = (const float*)d_in[24];
  const float* Wv2 = (const float*)d_in[25];
  const float* bv2 = (const float*)d_in[26];
  const float* Wv3 = (const float*)d_in[27];
  const float* bv3 = (const float*)d_in[28];

  char* wsp = (char*)d_ws;
  auto alloc = [&](size_t bytes) {
    char* p = wsp;
    wsp += (bytes + 255) & ~(size_t)255;
    return p;
  };
  float* h0 = (float*)alloc((size_t)N_ * 64 * 4);
  float* agg = (float*)alloc((size_t)N_ * 64 * 4);
  float* deg = (float*)alloc((size_t)N_ * 4);
  float* h1 = (float*)alloc((size_t)N_ * 64 * 4);
  float* meanv = (float*)alloc(64 * 4);
  float* ge = (float*)alloc(64 * 4);
  float* biasA = (float*)alloc(8 * 1024 * 4);
  float* biasV = (float*)alloc(1024 * 4);
  bf16* joint = (bf16*)alloc((size_t)4096 * 4096 * 2);     // 33.5 MB
  bf16* Wp1t = (bf16*)alloc((size_t)1024 * 512 * 2);
  bf16* Wp2t = (bf16*)alloc((size_t)1024 * 1024 * 2);
  bf16* Wp3t = (bf16*)alloc((size_t)64 * 1024 * 2);
  bf16* Wv1t = (bf16*)alloc((size_t)1024 * 4096 * 2);
  bf16* Wv2t = (bf16*)alloc((size_t)1024 * 1024 * 2);
  bf16* C1 = (bf16*)alloc((size_t)32768 * 1024 * 2);       // 64 MB
  bf16* C2 = (bf16*)alloc((size_t)32768 * 1024 * 2);       // 64 MB
  bf16* hv = (bf16*)alloc((size_t)4096 * 1024 * 2);
  bf16* hv2 = (bf16*)alloc((size_t)4096 * 1024 * 2);

  float* logits = (float*)d_out;
  float* value = (float*)d_out + (size_t)A_ * B_ * ACT_;

  hipMemsetAsync(agg, 0, (size_t)N_ * 64 * 4, stream);
  hipMemsetAsync(deg, 0, (size_t)N_ * 4, stream);

  gnn_l0_k<<<N_, 64, 0, stream>>>(node_types, node_agents, type_embed, gagent_embed, W_l0, b_l0, g_l0, be_l0, h0);
  edge_k<<<(E_ * 64) / 256, 256, 0, stream>>>(edges, h0, agg, deg);
  gnn_l1_k<<<N_, 64, 0, stream>>>(h0, agg, deg, W_l1, b_l1, g_l1, be_l1, h1);
  colmean_k<<<64, 256, 0, stream>>>(h1, meanv);
  ge_k<<<1, 64, 0, stream>>>(meanv, W_gp, b_gp, ge);
  biasA_k<<<32, 256, 0, stream>>>(ge, agent_embed, Wp1, bp1, biasA);
  biasV_k<<<4, 256, 0, stream>>>(ge, Wv1, bv1, biasV);

  conv_joint_k<<<(A_ * B_ * OBS_) / 8 / 256, 256, 0, stream>>>(obs, joint);
  wtrans_k<<<dim3(1024 / 32, 512 / 32), 256, 0, stream>>>(Wp1, Wp1t, 512, 1024);
  wtrans_k<<<dim3(1024 / 32, 1024 / 32), 256, 0, stream>>>(Wp2, Wp2t, 1024, 1024);
  wtrans_k<<<dim3(64 / 32, 1024 / 32), 256, 0, stream>>>(Wp3, Wp3t, 1024, 64);
  wtrans_k<<<dim3(1024 / 32, 4096 / 32), 256, 0, stream>>>(Wv1, Wv1t, 4096, 1024);
  wtrans_k<<<dim3(1024 / 32, 1024 / 32), 256, 0, stream>>>(Wv2, Wv2t, 1024, 1024);

  // P1: C1 = relu(obs2d @ Wp1[0:512] + biasA[agent])  M=32768 N=1024 K=512
  mgemm_k<4, 4, 2, 2, 1, 1, true, bf16>
      <<<dim3(1024 / 128, 32768 / 128), 256, 0, stream>>>(joint, Wp1t, biasA, C1, 32768, 1024, 512);
  // P2: C2 = relu(C1 @ Wp2 + bp2)                     M=32768 N=1024 K=1024
  mgemm_k<4, 4, 2, 2, 0, 0, true, bf16>
      <<<dim3(8, 256), 256, 0, stream>>>(C1, Wp2t, bp2, C2, 32768, 1024, 1024);
  // P3: logits = C2 @ Wp3 + bp3                       M=32768 N=64 K=1024
  mgemm_k<2, 4, 4, 1, 0, 0, false, float>
      <<<dim3(1, 32768 / 128), 256, 0, stream>>>(C2, Wp3t, bp3, logits, 32768, 64, 1024);
  // V1: hv = relu(joint @ Wv1[0:4096] + biasV)        M=4096 N=1024 K=4096
  mgemm_k<4, 4, 2, 2, 0, 0, true, bf16>
      <<<dim3(8, 4096 / 128), 256, 0, stream>>>(joint, Wv1t, biasV, hv, 4096, 1024, 4096);
  // V2: hv2 = relu(hv @ Wv2 + bv2)                    M=4096 N=1024 K=1024
  mgemm_k<4, 4, 2, 2, 0, 0, true, bf16>
      <<<dim3(8, 4096 / 128), 256, 0, stream>>>(hv, Wv2t, bv2, hv2, 4096, 1024, 1024);
  // V3: value = hv2 @ Wv3 + bv3
  v3_k<<<1024, 256, 0, stream>>>(hv2, Wv3, bv3, value);
}

// Round 3
// 357.479 us; speedup vs baseline: 8.6479x; 1.2271x over previous
//
#include <hip/hip_runtime.h>
#include <hip/hip_bf16.h>

#define A_ 8
#define B_ 4096
#define OBS_ 512
#define ACT_ 64
#define H_ 1024
#define G_ 64
#define N_ 10000
#define E_ 40000

using bf16 = __hip_bfloat16;
typedef __attribute__((ext_vector_type(8))) short short8;
typedef __attribute__((ext_vector_type(4))) float f32x4;

__device__ __forceinline__ float wsum(float v) {
#pragma unroll
  for (int off = 32; off >= 1; off >>= 1) v += __shfl_xor(v, off, 64);
  return v;
}

__device__ __forceinline__ void storeC(float* p, float v) { *p = v; }
__device__ __forceinline__ void storeC(bf16* p, float v) { *p = __float2bfloat16(v); }

__device__ __forceinline__ unsigned short f2bu(float x) {
  bf16 h = __float2bfloat16(x);
  unsigned short u;
  __builtin_memcpy(&u, &h, 2);
  return u;
}

__device__ __forceinline__ void gload_lds16(const bf16* g, const void* lds_uniform) {
  __builtin_amdgcn_global_load_lds(
      (const __attribute__((address_space(1))) unsigned int*)g,
      (__attribute__((address_space(3))) unsigned int*)lds_uniform, 16, 0, 0);
}

// ---------------- GNN ----------------
__global__ void gnn_l0_k(const int* __restrict__ node_types, const int* __restrict__ node_agents,
                         const float* __restrict__ type_embed, const float* __restrict__ gagent_embed,
                         const float* __restrict__ W, const float* __restrict__ b,
                         const float* __restrict__ g, const float* __restrict__ be,
                         float* __restrict__ h0) {
  int n = blockIdx.x, t = threadIdx.x;  // 64 threads = 1 wave
  __shared__ float x[64];
  int ty = node_types[n], ag = node_agents[n];
  x[t] = (t < 32) ? type_embed[ty * 32 + t] : gagent_embed[ag * 32 + (t - 32)];
  __syncthreads();
  float acc = b[t];
#pragma unroll 8
  for (int i = 0; i < 64; i++) acc += x[i] * W[i * 64 + t];
  acc = fmaxf(acc, 0.f);
  float m = wsum(acc) * (1.f / 64.f);
  float d = acc - m;
  float v = wsum(d * d) * (1.f / 64.f);
  h0[(size_t)n * 64 + t] = d * rsqrtf(v + 1e-5f) * g[t] + be[t];
}

__global__ void edge_k(const int* __restrict__ edges, const float* __restrict__ h0,
                       float* __restrict__ agg, float* __restrict__ deg) {
  int idx = blockIdx.x * 256 + threadIdx.x;
  if (idx >= E_ * 64) return;
  int e = idx >> 6, c = idx & 63;
  int s = edges[e * 2 + 0], d = edges[e * 2 + 1];
  atomicAdd(&agg[(size_t)d * 64 + c], h0[(size_t)s * 64 + c]);
  atomicAdd(&agg[(size_t)s * 64 + c], h0[(size_t)d * 64 + c]);
  if (c == 0) { atomicAdd(&deg[d], 1.f); atomicAdd(&deg[s], 1.f); }
}

__global__ void gnn_l1_k(const float* __restrict__ h0, const float* __restrict__ agg,
                         const float* __restrict__ deg, const float* __restrict__ W,
                         const float* __restrict__ b, const float* __restrict__ g,
                         const float* __restrict__ be, float* __restrict__ h1) {
  int n = blockIdx.x, t = threadIdx.x;  // 64 threads
  __shared__ float x[128];
  x[t] = h0[(size_t)n * 64 + t];
  x[64 + t] = agg[(size_t)n * 64 + t] / fmaxf(deg[n], 1.0f);
  __syncthreads();
  float acc = b[t];
#pragma unroll 8
  for (int i = 0; i < 128; i++) acc += x[i] * W[i * 64 + t];
  acc = fmaxf(acc, 0.f);
  float m = wsum(acc) * (1.f / 64.f);
  float d = acc - m;
  float v = wsum(d * d) * (1.f / 64.f);
  h1[(size_t)n * 64 + t] = d * rsqrtf(v + 1e-5f) * g[t] + be[t];
}

__global__ void colmean_k(const float* __restrict__ h1, float* __restrict__ meanv) {
  int c = blockIdx.x, t = threadIdx.x;
  float s = 0.f;
  for (int n = t; n < N_; n += 256) s += h1[(size_t)n * 64 + c];
  __shared__ float red[256];
  red[t] = s;
  __syncthreads();
  for (int off = 128; off >= 1; off >>= 1) {
    if (t < off) red[t] += red[t + off];
    __syncthreads();
  }
  if (t == 0) meanv[c] = red[0] / (float)N_;
}

__global__ void ge_k(const float* __restrict__ meanv, const float* __restrict__ Wgp,
                     const float* __restrict__ bgp, float* __restrict__ ge) {
  int o = threadIdx.x;
  float s = bgp[o];
  for (int g2 = 0; g2 < 64; g2++) s += meanv[g2] * Wgp[g2 * 64 + o];
  ge[o] = s;
}

__global__ void biasA_k(const float* __restrict__ ge, const float* __restrict__ agent_embed,
                        const float* __restrict__ Wp1, const float* __restrict__ bp1,
                        float* __restrict__ biasA) {
  int idx = blockIdx.x * 256 + threadIdx.x;  // 8192
  int a = idx >> 10, o = idx & 1023;
  float s = bp1[o];
  for (int g2 = 0; g2 < 64; g2++) s += ge[g2] * Wp1[(size_t)(512 + g2) * 1024 + o];
  for (int e = 0; e < 16; e++) s += agent_embed[a * 16 + e] * Wp1[(size_t)(576 + e) * 1024 + o];
  biasA[idx] = s;
}

__global__ void biasV_k(const float* __restrict__ ge, const float* __restrict__ Wv1,
                        const float* __restrict__ bv1, float* __restrict__ biasV) {
  int o = blockIdx.x * 256 + threadIdx.x;
  float s = bv1[o];
  for (int g2 = 0; g2 < 64; g2++) s += ge[g2] * Wv1[(size_t)(4096 + g2) * 1024 + o];
  biasV[o] = s;
}

// ---------------- conversions ----------------
__global__ void conv_joint_k(const float* __restrict__ obs, bf16* __restrict__ joint) {
  size_t i = ((size_t)blockIdx.x * 256 + threadIdx.x) * 8;
  int a = (int)(i >> 21);
  int rem = (int)(i & ((1u << 21) - 1));
  int b = rem >> 9, k = rem & 511;
  const float* p = obs + i;
  short8 o;
#pragma unroll
  for (int t = 0; t < 8; t++) o[t] = (short)f2bu(p[t]);
  *(short8*)(joint + (size_t)b * 4096 + a * 512 + k) = o;
}

__global__ void wtrans_k(const float* __restrict__ W, bf16* __restrict__ Wt, int K, int N) {
  __shared__ float t[32][33];
  int n0 = blockIdx.x * 32, k0 = blockIdx.y * 32;
  int tx = threadIdx.x & 31, ty = threadIdx.x >> 5;  // 32x8
#pragma unroll
  for (int r = ty; r < 32; r += 8) t[r][tx] = W[(size_t)(k0 + r) * N + n0 + tx];
  __syncthreads();
#pragma unroll
  for (int r = ty; r < 32; r += 8) Wt[(size_t)(n0 + r) * K + k0 + tx] = __float2bfloat16(t[tx][r]);
}

// ---------------- MFMA GEMM: double-buffered 2-phase, hoisted addressing ----------------
// A: row-major [M][K] bf16 (AMODE 0) or joint-gather (AMODE 1)
// Bt: [N][K] bf16. BIASMODE 0: bias[col]; 1: bias[(row>>12)*1024 + col]
template <int WM, int WN, int WAVES_M, int WAVES_N, int AMODE, int BIASMODE, bool RELU, typename TC>
__launch_bounds__(WAVES_M * WAVES_N * 64)
__global__ void mgemm_k(const bf16* __restrict__ Ap, const bf16* __restrict__ Bt,
                        const float* __restrict__ biasp, TC* __restrict__ Cp,
                        int M, int N, int K) {
  constexpr int BM = WAVES_M * WM * 16;
  constexpr int BN = WAVES_N * WN * 16;
  constexpr int NTHR = WAVES_M * WAVES_N * 64;
  constexpr int SBUF = (BM + BN) * 64;            // bytes per buffer
  constexpr int AIT = (BM * 4) / NTHR;            // stage iters for A
  constexpr int BIT = (BN * 4) / NTHR;
  __shared__ char smem[2 * SBUF];

  const int tid = threadIdx.x;
  const int wid = tid >> 6, lane = tid & 63;
  const int wm = wid / WAVES_N, wn = wid % WAVES_N;

  // T1: bijective XCD swizzle of the flat block id (nwg % 8 == 0 for all launches)
  const int nwg = gridDim.x * gridDim.y;
  int fid = blockIdx.y * gridDim.x + blockIdx.x;
  int swz = (fid & 7) * (nwg >> 3) + (fid >> 3);
  const int m0 = (swz / gridDim.x) * BM;
  const int n0 = (swz % gridDim.x) * BN;

  f32x4 acc[WM][WN];
#pragma unroll
  for (int i = 0; i < WM; i++)
#pragma unroll
    for (int j = 0; j < WN; j++) acc[i][j] = (f32x4){0.f, 0.f, 0.f, 0.f};

  // ---- hoisted staging addresses (pre-swizzled global src, linear LDS dst) ----
  const bf16* pa[AIT];
  const bf16* pb[BIT];
#pragma unroll
  for (int it = 0; it < AIT; ++it) {
    int li = it * NTHR + tid;
    int row = li >> 2;
    int c = (li & 3) ^ ((row >> 1) & 3);
    if (AMODE == 0) {
      pa[it] = Ap + (size_t)(m0 + row) * K + c * 8;
    } else {
      int r = m0 + row;
      pa[it] = Ap + (((size_t)(r & (B_ - 1))) << 12) + ((size_t)(r >> 12) << 9) + c * 8;
    }
  }
#pragma unroll
  for (int it = 0; it < BIT; ++it) {
    int li = it * NTHR + tid;
    int row = li >> 2;
    int c = (li & 3) ^ ((row >> 1) & 3);
    pb[it] = Bt + (size_t)(n0 + row) * K + c * 8;
  }

  // k0-invariant fragment chunk indices (16B units) with matching XOR swizzle
  int a_ch[WM], b_ch[WN];
  const int cfr = lane >> 4;
#pragma unroll
  for (int i = 0; i < WM; i++) {
    int r = wm * WM * 16 + i * 16 + (lane & 15);
    a_ch[i] = r * 4 + (cfr ^ ((r >> 1) & 3));
  }
#pragma unroll
  for (int j = 0; j < WN; j++) {
    int n = wn * WN * 16 + j * 16 + (lane & 15);
    b_ch[j] = BM * 4 + n * 4 + (cfr ^ ((n >> 1) & 3));
  }

  auto stage = [&](int bufoff) {
#pragma unroll
    for (int it = 0; it < AIT; ++it) {
      gload_lds16(pa[it], smem + bufoff + it * (NTHR * 16) + wid * 1024);
      pa[it] += 32;
    }
#pragma unroll
    for (int it = 0; it < BIT; ++it) {
      gload_lds16(pb[it], smem + bufoff + BM * 64 + it * (NTHR * 16) + wid * 1024);
      pb[it] += 32;
    }
  };
  auto compute = [&](int bufoff) {
    const short8* sv = (const short8*)(smem + bufoff);
    short8 af[WM], bfr[WN];
#pragma unroll
    for (int i = 0; i < WM; i++) af[i] = sv[a_ch[i]];
#pragma unroll
    for (int j = 0; j < WN; j++) bfr[j] = sv[b_ch[j]];
#pragma unroll
    for (int i = 0; i < WM; i++)
#pragma unroll
      for (int j = 0; j < WN; j++)
        acc[i][j] = __builtin_amdgcn_mfma_f32_16x16x32_bf16(af[i], bfr[j], acc[i][j], 0, 0, 0);
  };

  const int nt = K >> 5;
  stage(0);
  __syncthreads();
  int cur = 0;
  for (int t = 0; t < nt - 1; ++t) {
    stage((cur ^ 1) * SBUF);   // issue next tile's loads first (overlap with compute)
    compute(cur * SBUF);
    __syncthreads();           // drains vmcnt+lgkmcnt, then barrier
    cur ^= 1;
  }
  compute(cur * SBUF);

  // epilogue: C/D layout col=lane&15, row=(lane>>4)*4+reg
#pragma unroll
  for (int i = 0; i < WM; i++) {
    int rb = m0 + wm * WM * 16 + i * 16 + (lane >> 4) * 4;
#pragma unroll
    for (int j = 0; j < WN; j++) {
      int col = n0 + wn * WN * 16 + j * 16 + (lane & 15);
#pragma unroll
      for (int r = 0; r < 4; r++) {
        int row = rb + r;
        float bias = (BIASMODE == 0) ? biasp[col] : biasp[((row >> 12) << 10) + col];
        float v = acc[i][j][r] + bias;
        if (RELU) v = fmaxf(v, 0.f);
        storeC(&Cp[(size_t)row * N + col], v);
      }
    }
  }
}

__global__ void v3_k(const bf16* __restrict__ hv2, const float* __restrict__ Wv3,
                     const float* __restrict__ bv3, float* __restrict__ out) {
  int wid = threadIdx.x >> 6, lane = threadIdx.x & 63;
  int row = blockIdx.x * 4 + wid;
  float s = 0.f;
#pragma unroll
  for (int k = lane; k < 1024; k += 64) s += __bfloat162float(hv2[(size_t)row * 1024 + k]) * Wv3[k];
  s = wsum(s);
  if (lane == 0) out[row] = s + bv3[0];
}

extern "C" void kernel_launch(void* const* d_in, const int* in_sizes, int n_in,
                              void* d_out, int out_size, void* d_ws, size_t ws_size,
                              hipStream_t stream) {
  const float* obs = (const float*)d_in[0];
  const int* node_types = (const int*)d_in[1];
  const int* node_agents = (const int*)d_in[2];
  const int* edges = (const int*)d_in[3];
  const float* type_embed = (const float*)d_in[4];
  const float* gagent_embed = (const float*)d_in[5];
  const float* W_l0 = (const float*)d_in[6];
  const float* b_l0 = (const float*)d_in[7];
  const float* g_l0 = (const float*)d_in[8];
  const float* be_l0 = (const float*)d_in[9];
  const float* W_l1 = (const float*)d_in[10];
  const float* b_l1 = (const float*)d_in[11];
  const float* g_l1 = (const float*)d_in[12];
  const float* be_l1 = (const float*)d_in[13];
  const float* W_gp = (const float*)d_in[14];
  const float* b_gp = (const float*)d_in[15];
  const float* agent_embed = (const float*)d_in[16];
  const float* Wp1 = (const float*)d_in[17];
  const float* bp1 = (const float*)d_in[18];
  const float* Wp2 = (const float*)d_in[19];
  const float* bp2 = (const float*)d_in[20];
  const float* Wp3 = (const float*)d_in[21];
  const float* bp3 = (const float*)d_in[22];
  const float* Wv1 = (const float*)d_in[23];
  const float* bv1 = (const float*)d_in[24];
  const float* Wv2 = (const float*)d_in[25];
  const float* bv2 = (const float*)d_in[26];
  const float* Wv3 = (const float*)d_in[27];
  const float* bv3 = (const float*)d_in[28];

  char* wsp = (char*)d_ws;
  auto alloc = [&](size_t bytes) {
    char* p = wsp;
    wsp += (bytes + 255) & ~(size_t)255;
    return p;
  };
  float* h0 = (float*)alloc((size_t)N_ * 64 * 4);
  float* agg = (float*)alloc((size_t)N_ * 64 * 4);
  float* deg = (float*)alloc((size_t)N_ * 4);
  float* h1 = (float*)alloc((size_t)N_ * 64 * 4);
  float* meanv = (float*)alloc(64 * 4);
  float* ge = (float*)alloc(64 * 4);
  float* biasA = (float*)alloc(8 * 1024 * 4);
  float* biasV = (float*)alloc(1024 * 4);
  bf16* joint = (bf16*)alloc((size_t)4096 * 4096 * 2);
  bf16* Wp1t = (bf16*)alloc((size_t)1024 * 512 * 2);
  bf16* Wp2t = (bf16*)alloc((size_t)1024 * 1024 * 2);
  bf16* Wp3t = (bf16*)alloc((size_t)64 * 1024 * 2);
  bf16* Wv1t = (bf16*)alloc((size_t)1024 * 4096 * 2);
  bf16* Wv2t = (bf16*)alloc((size_t)1024 * 1024 * 2);
  bf16* C1 = (bf16*)alloc((size_t)32768 * 1024 * 2);
  bf16* C2 = (bf16*)alloc((size_t)32768 * 1024 * 2);
  bf16* hv = (bf16*)alloc((size_t)4096 * 1024 * 2);
  bf16* hv2 = (bf16*)alloc((size_t)4096 * 1024 * 2);

  float* logits = (float*)d_out;
  float* value = (float*)d_out + (size_t)A_ * B_ * ACT_;

  hipMemsetAsync(agg, 0, (size_t)N_ * 64 * 4, stream);
  hipMemsetAsync(deg, 0, (size_t)N_ * 4, stream);

  gnn_l0_k<<<N_, 64, 0, stream>>>(node_types, node_agents, type_embed, gagent_embed, W_l0, b_l0, g_l0, be_l0, h0);
  edge_k<<<(E_ * 64) / 256, 256, 0, stream>>>(edges, h0, agg, deg);
  gnn_l1_k<<<N_, 64, 0, stream>>>(h0, agg, deg, W_l1, b_l1, g_l1, be_l1, h1);
  colmean_k<<<64, 256, 0, stream>>>(h1, meanv);
  ge_k<<<1, 64, 0, stream>>>(meanv, W_gp, b_gp, ge);
  biasA_k<<<32, 256, 0, stream>>>(ge, agent_embed, Wp1, bp1, biasA);
  biasV_k<<<4, 256, 0, stream>>>(ge, Wv1, bv1, biasV);

  conv_joint_k<<<(A_ * B_ * OBS_) / 8 / 256, 256, 0, stream>>>(obs, joint);
  wtrans_k<<<dim3(1024 / 32, 512 / 32), 256, 0, stream>>>(Wp1, Wp1t, 512, 1024);
  wtrans_k<<<dim3(1024 / 32, 1024 / 32), 256, 0, stream>>>(Wp2, Wp2t, 1024, 1024);
  wtrans_k<<<dim3(64 / 32, 1024 / 32), 256, 0, stream>>>(Wp3, Wp3t, 1024, 64);
  wtrans_k<<<dim3(1024 / 32, 4096 / 32), 256, 0, stream>>>(Wv1, Wv1t, 4096, 1024);
  wtrans_k<<<dim3(1024 / 32, 1024 / 32), 256, 0, stream>>>(Wv2, Wv2t, 1024, 1024);

  // P1: C1 = relu(obs2d @ Wp1[0:512] + biasA[agent])  M=32768 N=1024 K=512  (2048 blocks)
  mgemm_k<4, 4, 2, 2, 1, 1, true, bf16>
      <<<dim3(8, 256), 256, 0, stream>>>(joint, Wp1t, biasA, C1, 32768, 1024, 512);
  // P2: C2 = relu(C1 @ Wp2 + bp2)                     M=32768 N=1024 K=1024 (2048 blocks)
  mgemm_k<4, 4, 2, 2, 0, 0, true, bf16>
      <<<dim3(8, 256), 256, 0, stream>>>(C1, Wp2t, bp2, C2, 32768, 1024, 1024);
  // P3: logits = C2 @ Wp3 + bp3                       M=32768 N=64 K=1024  (256 blocks, 128x64)
  mgemm_k<4, 2, 2, 2, 0, 0, false, float>
      <<<dim3(1, 256), 256, 0, stream>>>(C2, Wp3t, bp3, logits, 32768, 64, 1024);
  // V1: hv = relu(joint @ Wv1 + biasV)                M=4096 N=1024 K=4096 (512 blocks, 128x64)
  mgemm_k<4, 2, 2, 2, 0, 0, true, bf16>
      <<<dim3(16, 32), 256, 0, stream>>>(joint, Wv1t, biasV, hv, 4096, 1024, 4096);
  // V2: hv2 = relu(hv @ Wv2 + bv2)                    M=4096 N=1024 K=1024 (512 blocks, 128x64)
  mgemm_k<4, 2, 2, 2, 0, 0, true, bf16>
      <<<dim3(16, 32), 256, 0, stream>>>(hv, Wv2t, bv2, hv2, 4096, 1024, 1024);
  // V3: value = hv2 @ Wv3 + bv3
  v3_k<<<1024, 256, 0, stream>>>(hv2, Wv3, bv3, value);
}

// Round 4
// 345.579 us; speedup vs baseline: 8.9457x; 1.0344x over previous
//
#include <hip/hip_runtime.h>
#include <hip/hip_bf16.h>

#define A_ 8
#define B_ 4096
#define OBS_ 512
#define ACT_ 64
#define H_ 1024
#define G_ 64
#define N_ 10000
#define E_ 40000

using bf16 = __hip_bfloat16;
typedef __attribute__((ext_vector_type(8))) short short8;
typedef __attribute__((ext_vector_type(4))) float f32x4;

__device__ __forceinline__ float wsum(float v) {
#pragma unroll
  for (int off = 32; off >= 1; off >>= 1) v += __shfl_xor(v, off, 64);
  return v;
}

__device__ __forceinline__ void storeC(float* p, float v) { *p = v; }
__device__ __forceinline__ void storeC(bf16* p, float v) { *p = __float2bfloat16(v); }

__device__ __forceinline__ unsigned short f2bu(float x) {
  bf16 h = __float2bfloat16(x);
  unsigned short u;
  __builtin_memcpy(&u, &h, 2);
  return u;
}

__device__ __forceinline__ void gload_lds16(const bf16* g, const void* lds_uniform) {
  __builtin_amdgcn_global_load_lds(
      (const __attribute__((address_space(1))) unsigned int*)g,
      (__attribute__((address_space(3))) unsigned int*)lds_uniform, 16, 0, 0);
}

template <int N>
__device__ __forceinline__ void waitvm() {
  static_assert(N == 0 || N == 2 || N == 3 || N == 4 || N == 5 || N == 6, "vmcnt");
  if constexpr (N == 0) asm volatile("s_waitcnt vmcnt(0)" ::: "memory");
  if constexpr (N == 2) asm volatile("s_waitcnt vmcnt(2)" ::: "memory");
  if constexpr (N == 3) asm volatile("s_waitcnt vmcnt(3)" ::: "memory");
  if constexpr (N == 4) asm volatile("s_waitcnt vmcnt(4)" ::: "memory");
  if constexpr (N == 5) asm volatile("s_waitcnt vmcnt(5)" ::: "memory");
  if constexpr (N == 6) asm volatile("s_waitcnt vmcnt(6)" ::: "memory");
}

// ---------------- GNN ----------------
__global__ void gnn_l0_k(const int* __restrict__ node_types, const int* __restrict__ node_agents,
                         const float* __restrict__ type_embed, const float* __restrict__ gagent_embed,
                         const float* __restrict__ W, const float* __restrict__ b,
                         const float* __restrict__ g, const float* __restrict__ be,
                         float* __restrict__ h0) {
  int n = blockIdx.x, t = threadIdx.x;  // 64 threads = 1 wave
  __shared__ float x[64];
  int ty = node_types[n], ag = node_agents[n];
  x[t] = (t < 32) ? type_embed[ty * 32 + t] : gagent_embed[ag * 32 + (t - 32)];
  __syncthreads();
  float acc = b[t];
#pragma unroll 8
  for (int i = 0; i < 64; i++) acc += x[i] * W[i * 64 + t];
  acc = fmaxf(acc, 0.f);
  float m = wsum(acc) * (1.f / 64.f);
  float d = acc - m;
  float v = wsum(d * d) * (1.f / 64.f);
  h0[(size_t)n * 64 + t] = d * rsqrtf(v + 1e-5f) * g[t] + be[t];
}

__global__ void edge_k(const int* __restrict__ edges, const float* __restrict__ h0,
                       float* __restrict__ agg, float* __restrict__ deg) {
  int idx = blockIdx.x * 256 + threadIdx.x;
  if (idx >= E_ * 64) return;
  int e = idx >> 6, c = idx & 63;
  int s = edges[e * 2 + 0], d = edges[e * 2 + 1];
  atomicAdd(&agg[(size_t)d * 64 + c], h0[(size_t)s * 64 + c]);
  atomicAdd(&agg[(size_t)s * 64 + c], h0[(size_t)d * 64 + c]);
  if (c == 0) { atomicAdd(&deg[d], 1.f); atomicAdd(&deg[s], 1.f); }
}

__global__ void gnn_l1_k(const float* __restrict__ h0, const float* __restrict__ agg,
                         const float* __restrict__ deg, const float* __restrict__ W,
                         const float* __restrict__ b, const float* __restrict__ g,
                         const float* __restrict__ be, float* __restrict__ h1) {
  int n = blockIdx.x, t = threadIdx.x;  // 64 threads
  __shared__ float x[128];
  x[t] = h0[(size_t)n * 64 + t];
  x[64 + t] = agg[(size_t)n * 64 + t] / fmaxf(deg[n], 1.0f);
  __syncthreads();
  float acc = b[t];
#pragma unroll 8
  for (int i = 0; i < 128; i++) acc += x[i] * W[i * 64 + t];
  acc = fmaxf(acc, 0.f);
  float m = wsum(acc) * (1.f / 64.f);
  float d = acc - m;
  float v = wsum(d * d) * (1.f / 64.f);
  h1[(size_t)n * 64 + t] = d * rsqrtf(v + 1e-5f) * g[t] + be[t];
}

__global__ void colmean_k(const float* __restrict__ h1, float* __restrict__ meanv) {
  int c = blockIdx.x, t = threadIdx.x;
  float s = 0.f;
  for (int n = t; n < N_; n += 256) s += h1[(size_t)n * 64 + c];
  __shared__ float red[256];
  red[t] = s;
  __syncthreads();
  for (int off = 128; off >= 1; off >>= 1) {
    if (t < off) red[t] += red[t + off];
    __syncthreads();
  }
  if (t == 0) meanv[c] = red[0] / (float)N_;
}

__global__ void ge_k(const float* __restrict__ meanv, const float* __restrict__ Wgp,
                     const float* __restrict__ bgp, float* __restrict__ ge) {
  int o = threadIdx.x;
  float s = bgp[o];
  for (int g2 = 0; g2 < 64; g2++) s += meanv[g2] * Wgp[g2 * 64 + o];
  ge[o] = s;
}

__global__ void biasA_k(const float* __restrict__ ge, const float* __restrict__ agent_embed,
                        const float* __restrict__ Wp1, const float* __restrict__ bp1,
                        float* __restrict__ biasA) {
  int idx = blockIdx.x * 256 + threadIdx.x;  // 8192
  int a = idx >> 10, o = idx & 1023;
  float s = bp1[o];
  for (int g2 = 0; g2 < 64; g2++) s += ge[g2] * Wp1[(size_t)(512 + g2) * 1024 + o];
  for (int e = 0; e < 16; e++) s += agent_embed[a * 16 + e] * Wp1[(size_t)(576 + e) * 1024 + o];
  biasA[idx] = s;
}

__global__ void biasV_k(const float* __restrict__ ge, const float* __restrict__ Wv1,
                        const float* __restrict__ bv1, float* __restrict__ biasV) {
  int o = blockIdx.x * 256 + threadIdx.x;
  float s = bv1[o];
  for (int g2 = 0; g2 < 64; g2++) s += ge[g2] * Wv1[(size_t)(4096 + g2) * 1024 + o];
  biasV[o] = s;
}

// ---------------- conversions ----------------
__global__ void conv_joint_k(const float* __restrict__ obs, bf16* __restrict__ joint) {
  size_t i = ((size_t)blockIdx.x * 256 + threadIdx.x) * 8;
  int a = (int)(i >> 21);
  int rem = (int)(i & ((1u << 21) - 1));
  int b = rem >> 9, k = rem & 511;
  const float* p = obs + i;
  short8 o;
#pragma unroll
  for (int t = 0; t < 8; t++) o[t] = (short)f2bu(p[t]);
  *(short8*)(joint + (size_t)b * 4096 + a * 512 + k) = o;
}

__global__ void wtrans_k(const float* __restrict__ W, bf16* __restrict__ Wt, int K, int N) {
  __shared__ float t[32][33];
  int n0 = blockIdx.x * 32, k0 = blockIdx.y * 32;
  int tx = threadIdx.x & 31, ty = threadIdx.x >> 5;  // 32x8
#pragma unroll
  for (int r = ty; r < 32; r += 8) t[r][tx] = W[(size_t)(k0 + r) * N + n0 + tx];
  __syncthreads();
#pragma unroll
  for (int r = ty; r < 32; r += 8) Wt[(size_t)(n0 + r) * K + k0 + tx] = __float2bfloat16(t[tx][r]);
}

// ---------------- MFMA GEMM: phase-split pipeline, counted vmcnt (T3+T4+T5) ----------------
// Per-wave output (FM*16) x (FN*16); tile (WAVES_M*FM*16) x (WAVES_N*FN*16); BK=32.
// A: row-major [M][K] bf16 (AMODE 0) or joint-gather (AMODE 1). Bt: [N][K] bf16.
// BIASMODE 0: bias[col]; 1: bias[(row>>12)*1024 + col]
template <int FM, int FN, int WAVES_M, int WAVES_N, int AMODE, int BIASMODE, bool RELU, typename TC>
__launch_bounds__(WAVES_M * WAVES_N * 64, 2)
__global__ void pgemm_k(const bf16* __restrict__ Ap, const bf16* __restrict__ Bt,
                        const float* __restrict__ biasp, TC* __restrict__ Cp,
                        int M, int N, int K) {
  constexpr int NTHR = WAVES_M * WAVES_N * 64;
  constexpr int AR = WAVES_M * FM * 16;  // tile A-rows (BM)
  constexpr int BR = WAVES_N * FN * 16;  // tile B-rows (BN)
  constexpr int RPG = NTHR / 4;          // rows per stage group (64B rows, 16B/lane)
  constexpr int AG = AR / RPG;
  constexpr int BG = BR / RPG;
  constexpr int G = AG + BG;             // gload instrs per K-tile (per wave)
  constexpr int H1 = (G + 1) / 2;
  constexpr int GRP = NTHR * 16;         // bytes per stage group
  constexpr int ABYTES = AR * 64;
  constexpr int SBUF = (AR + BR) * 64;
  constexpr int FMH = FM / 2;
  __shared__ char smem[2 * SBUF];

  const int tid = threadIdx.x;
  const int wid = tid >> 6, lane = tid & 63;
  const int wm = wid / WAVES_N, wn = wid % WAVES_N;
  const int l15 = lane & 15;

  // T1: bijective XCD swizzle (nwg % 8 == 0 for all launches here)
  const int nwg = gridDim.x * gridDim.y;
  int fid = blockIdx.y * gridDim.x + blockIdx.x;
  int swz = (fid & 7) * (nwg >> 3) + (fid >> 3);
  const int m0 = (swz / gridDim.x) * AR;
  const int n0 = (swz % gridDim.x) * BR;

  f32x4 acc[FM][FN];
#pragma unroll
  for (int i = 0; i < FM; i++)
#pragma unroll
    for (int j = 0; j < FN; j++) acc[i][j] = (f32x4){0.f, 0.f, 0.f, 0.f};

  // hoisted per-thread staging pointers (pre-swizzled global src, linear LDS dst)
  const bf16* pa[AG];
  const bf16* pb[BG];
  {
    int row = tid >> 2;
    int c = (tid & 3) ^ ((tid >> 3) & 3);
#pragma unroll
    for (int q = 0; q < AG; ++q) {
      int r = m0 + q * RPG + row;
      if (AMODE == 0)
        pa[q] = Ap + (size_t)r * K + c * 8;
      else
        pa[q] = Ap + (((size_t)(r & (B_ - 1))) << 12) + ((size_t)(r >> 12) << 9) + c * 8;
    }
#pragma unroll
    for (int q = 0; q < BG; ++q) {
      int r = n0 + q * RPG + row;
      pb[q] = Bt + (size_t)r * K + c * 8;
    }
  }

  // fragment LDS byte offsets (i/j-invariant swizzle term)
  const int cA = (lane >> 4) ^ ((l15 >> 1) & 3);
  const int offA0 = (wm * FM * 16 + l15) * 64 + cA * 16;
  const int offB0 = ABYTES + (wn * FN * 16 + l15) * 64 + cA * 16;

  auto stage_half = [&](int sbase, int qlo, int qhi) {
#pragma unroll
    for (int q = 0; q < G; ++q) {
      if (q < qlo || q >= qhi) continue;
      if (q < AG) {
        gload_lds16(pa[q], smem + sbase + q * GRP + wid * 1024);
        pa[q] += 32;
      } else {
        int qq = q - AG;
        gload_lds16(pb[qq], smem + sbase + ABYTES + qq * GRP + wid * 1024);
        pb[qq] += 32;
      }
    }
  };

  const int nt = K >> 5;
  stage_half(0, 0, G);  // prologue: all of tile 0 -> buf 0
  int cur = 0;
  for (int T = 0; T < nt; ++T) {
    const bool last = (T == nt - 1);
    const int sb = cur * SBUF, so = (cur ^ 1) * SBUF;
    short8 bfr[FN];
    // ---------- phase 1: B + A-low ----------
    if (!last) stage_half(so, 0, H1);
    if (last) waitvm<0>(); else waitvm<H1>();
    __builtin_amdgcn_s_barrier();
    asm volatile("" ::: "memory");
    {
      short8 afr[FMH];
#pragma unroll
      for (int j = 0; j < FN; ++j) bfr[j] = *(const short8*)(smem + sb + offB0 + j * 1024);
#pragma unroll
      for (int i = 0; i < FMH; ++i) afr[i] = *(const short8*)(smem + sb + offA0 + i * 1024);
      __builtin_amdgcn_s_setprio(1);
#pragma unroll
      for (int i = 0; i < FMH; ++i)
#pragma unroll
        for (int j = 0; j < FN; ++j)
          acc[i][j] = __builtin_amdgcn_mfma_f32_16x16x32_bf16(afr[i], bfr[j], acc[i][j], 0, 0, 0);
      __builtin_amdgcn_s_setprio(0);
    }
    asm volatile("s_waitcnt lgkmcnt(0)" ::: "memory");
    __builtin_amdgcn_s_barrier();
    asm volatile("" ::: "memory");
    // ---------- phase 2: A-high ----------
    if (!last) stage_half(so, H1, G);
    __builtin_amdgcn_s_barrier();
    asm volatile("" ::: "memory");
    {
      short8 afr[FMH];
#pragma unroll
      for (int i = 0; i < FMH; ++i)
        afr[i] = *(const short8*)(smem + sb + offA0 + (FMH + i) * 1024);
      __builtin_amdgcn_s_setprio(1);
#pragma unroll
      for (int i = 0; i < FMH; ++i)
#pragma unroll
        for (int j = 0; j < FN; ++j)
          acc[FMH + i][j] = __builtin_amdgcn_mfma_f32_16x16x32_bf16(afr[i], bfr[j], acc[FMH + i][j], 0, 0, 0);
      __builtin_amdgcn_s_setprio(0);
    }
    asm volatile("s_waitcnt lgkmcnt(0)" ::: "memory");
    __builtin_amdgcn_s_barrier();
    asm volatile("" ::: "memory");
    cur ^= 1;
  }

  // epilogue: C/D layout col=lane&15, row=(lane>>4)*4+reg
#pragma unroll
  for (int i = 0; i < FM; ++i) {
    int rb = m0 + wm * FM * 16 + i * 16 + (lane >> 4) * 4;
#pragma unroll
    for (int j = 0; j < FN; ++j) {
      int col = n0 + wn * FN * 16 + j * 16 + l15;
#pragma unroll
      for (int r = 0; r < 4; r++) {
        int row = rb + r;
        float bias = (BIASMODE == 0) ? biasp[col] : biasp[((row >> 12) << 10) + col];
        float v = acc[i][j][r] + bias;
        if (RELU) v = fmaxf(v, 0.f);
        storeC(&Cp[(size_t)row * N + col], v);
      }
    }
  }
}

__global__ void v3_k(const bf16* __restrict__ hv2, const float* __restrict__ Wv3,
                     const float* __restrict__ bv3, float* __restrict__ out) {
  int wid = threadIdx.x >> 6, lane = threadIdx.x & 63;
  int row = blockIdx.x * 4 + wid;
  float s = 0.f;
#pragma unroll
  for (int k = lane; k < 1024; k += 64) s += __bfloat162float(hv2[(size_t)row * 1024 + k]) * Wv3[k];
  s = wsum(s);
  if (lane == 0) out[row] = s + bv3[0];
}

extern "C" void kernel_launch(void* const* d_in, const int* in_sizes, int n_in,
                              void* d_out, int out_size, void* d_ws, size_t ws_size,
                              hipStream_t stream) {
  const float* obs = (const float*)d_in[0];
  const int* node_types = (const int*)d_in[1];
  const int* node_agents = (const int*)d_in[2];
  const int* edges = (const int*)d_in[3];
  const float* type_embed = (const float*)d_in[4];
  const float* gagent_embed = (const float*)d_in[5];
  const float* W_l0 = (const float*)d_in[6];
  const float* b_l0 = (const float*)d_in[7];
  const float* g_l0 = (const float*)d_in[8];
  const float* be_l0 = (const float*)d_in[9];
  const float* W_l1 = (const float*)d_in[10];
  const float* b_l1 = (const float*)d_in[11];
  const float* g_l1 = (const float*)d_in[12];
  const float* be_l1 = (const float*)d_in[13];
  const float* W_gp = (const float*)d_in[14];
  const float* b_gp = (const float*)d_in[15];
  const float* agent_embed = (const float*)d_in[16];
  const float* Wp1 = (const float*)d_in[17];
  const float* bp1 = (const float*)d_in[18];
  const float* Wp2 = (const float*)d_in[19];
  const float* bp2 = (const float*)d_in[20];
  const float* Wp3 = (const float*)d_in[21];
  const float* bp3 = (const float*)d_in[22];
  const float* Wv1 = (const float*)d_in[23];
  const float* bv1 = (const float*)d_in[24];
  const float* Wv2 = (const float*)d_in[25];
  const float* bv2 = (const float*)d_in[26];
  const float* Wv3 = (const float*)d_in[27];
  const float* bv3 = (const float*)d_in[28];

  char* wsp = (char*)d_ws;
  auto alloc = [&](size_t bytes) {
    char* p = wsp;
    wsp += (bytes + 255) & ~(size_t)255;
    return p;
  };
  float* h0 = (float*)alloc((size_t)N_ * 64 * 4);
  float* agg = (float*)alloc((size_t)N_ * 64 * 4);
  float* deg = (float*)alloc((size_t)N_ * 4);
  float* h1 = (float*)alloc((size_t)N_ * 64 * 4);
  float* meanv = (float*)alloc(64 * 4);
  float* ge = (float*)alloc(64 * 4);
  float* biasA = (float*)alloc(8 * 1024 * 4);
  float* biasV = (float*)alloc(1024 * 4);
  bf16* joint = (bf16*)alloc((size_t)4096 * 4096 * 2);
  bf16* Wp1t = (bf16*)alloc((size_t)1024 * 512 * 2);
  bf16* Wp2t = (bf16*)alloc((size_t)1024 * 1024 * 2);
  bf16* Wp3t = (bf16*)alloc((size_t)64 * 1024 * 2);
  bf16* Wv1t = (bf16*)alloc((size_t)1024 * 4096 * 2);
  bf16* Wv2t = (bf16*)alloc((size_t)1024 * 1024 * 2);
  bf16* C1 = (bf16*)alloc((size_t)32768 * 1024 * 2);
  bf16* C2 = (bf16*)alloc((size_t)32768 * 1024 * 2);
  bf16* hv = (bf16*)alloc((size_t)4096 * 1024 * 2);
  bf16* hv2 = (bf16*)alloc((size_t)4096 * 1024 * 2);

  float* logits = (float*)d_out;
  float* value = (float*)d_out + (size_t)A_ * B_ * ACT_;

  hipMemsetAsync(agg, 0, (size_t)N_ * 64 * 4, stream);
  hipMemsetAsync(deg, 0, (size_t)N_ * 4, stream);

  gnn_l0_k<<<N_, 64, 0, stream>>>(node_types, node_agents, type_embed, gagent_embed, W_l0, b_l0, g_l0, be_l0, h0);
  edge_k<<<(E_ * 64) / 256, 256, 0, stream>>>(edges, h0, agg, deg);
  gnn_l1_k<<<N_, 64, 0, stream>>>(h0, agg, deg, W_l1, b_l1, g_l1, be_l1, h1);
  colmean_k<<<64, 256, 0, stream>>>(h1, meanv);
  ge_k<<<1, 64, 0, stream>>>(meanv, W_gp, b_gp, ge);
  biasA_k<<<32, 256, 0, stream>>>(ge, agent_embed, Wp1, bp1, biasA);
  biasV_k<<<4, 256, 0, stream>>>(ge, Wv1, bv1, biasV);

  conv_joint_k<<<(A_ * B_ * OBS_) / 8 / 256, 256, 0, stream>>>(obs, joint);
  wtrans_k<<<dim3(1024 / 32, 512 / 32), 256, 0, stream>>>(Wp1, Wp1t, 512, 1024);
  wtrans_k<<<dim3(1024 / 32, 1024 / 32), 256, 0, stream>>>(Wp2, Wp2t, 1024, 1024);
  wtrans_k<<<dim3(64 / 32, 1024 / 32), 256, 0, stream>>>(Wp3, Wp3t, 1024, 64);
  wtrans_k<<<dim3(1024 / 32, 4096 / 32), 256, 0, stream>>>(Wv1, Wv1t, 4096, 1024);
  wtrans_k<<<dim3(1024 / 32, 1024 / 32), 256, 0, stream>>>(Wv2, Wv2t, 1024, 1024);

  // P1: C1 = relu(obs2d @ Wp1[0:512] + biasA[agent])  M=32768 N=1024 K=512, tile 256x128
  pgemm_k<8, 4, 2, 2, 1, 1, true, bf16>
      <<<dim3(8, 128), 256, 0, stream>>>(joint, Wp1t, biasA, C1, 32768, 1024, 512);
  // P2: C2 = relu(C1 @ Wp2 + bp2)                     M=32768 N=1024 K=1024, tile 256x128
  pgemm_k<8, 4, 2, 2, 0, 0, true, bf16>
      <<<dim3(8, 128), 256, 0, stream>>>(C1, Wp2t, bp2, C2, 32768, 1024, 1024);
  // P3: logits = C2 @ Wp3 + bp3                       M=32768 N=64 K=1024, tile 128x64
  pgemm_k<4, 4, 2, 1, 0, 0, false, float>
      <<<dim3(1, 256), 128, 0, stream>>>(C2, Wp3t, bp3, logits, 32768, 64, 1024);
  // V1: hv = relu(joint @ Wv1 + biasV)                M=4096 N=1024 K=4096, tile 128x128
  pgemm_k<4, 4, 2, 2, 0, 0, true, bf16>
      <<<dim3(8, 32), 256, 0, stream>>>(joint, Wv1t, biasV, hv, 4096, 1024, 4096);
  // V2: hv2 = relu(hv @ Wv2 + bv2)                    M=4096 N=1024 K=1024, tile 128x128
  pgemm_k<4, 4, 2, 2, 0, 0, true, bf16>
      <<<dim3(8, 32), 256, 0, stream>>>(hv, Wv2t, bv2, hv2, 4096, 1024, 1024);
  // V3: value = hv2 @ Wv3 + bv3
  v3_k<<<1024, 256, 0, stream>>>(hv2, Wv3, bv3, value);
}

// Round 5
// 305.902 us; speedup vs baseline: 10.1060x; 1.1297x over previous
//
#include <hip/hip_runtime.h>
#include <hip/hip_bf16.h>

#define A_ 8
#define B_ 4096
#define OBS_ 512
#define ACT_ 64
#define H_ 1024
#define G_ 64
#define N_ 10000
#define E_ 40000

using bf16 = __hip_bfloat16;
typedef __attribute__((ext_vector_type(8))) short short8;
typedef __attribute__((ext_vector_type(4))) float f32x4;

__device__ __forceinline__ float wsum(float v) {
#pragma unroll
  for (int off = 32; off >= 1; off >>= 1) v += __shfl_xor(v, off, 64);
  return v;
}

__device__ __forceinline__ void storeC(float* p, float v) { *p = v; }
__device__ __forceinline__ void storeC(bf16* p, float v) { *p = __float2bfloat16(v); }

__device__ __forceinline__ unsigned short f2bu(float x) {
  bf16 h = __float2bfloat16(x);
  unsigned short u;
  __builtin_memcpy(&u, &h, 2);
  return u;
}

__device__ __forceinline__ void gload_lds16(const bf16* g, const void* lds_uniform) {
  __builtin_amdgcn_global_load_lds(
      (const __attribute__((address_space(1))) unsigned int*)g,
      (__attribute__((address_space(3))) unsigned int*)lds_uniform, 16, 0, 0);
}

template <int N>
__device__ __forceinline__ void waitvm() {
#define WV_CASE(n) if constexpr (N == n) asm volatile("s_waitcnt vmcnt(" #n ")" ::: "memory");
  WV_CASE(0) WV_CASE(3) WV_CASE(4) WV_CASE(6) WV_CASE(8) WV_CASE(9) WV_CASE(12) WV_CASE(16)
  static_assert(N == 0 || N == 3 || N == 4 || N == 6 || N == 8 || N == 9 || N == 12 || N == 16,
                "vmcnt value not in table");
#undef WV_CASE
}

// ---------------- GNN ----------------
__global__ void gnn_l0_k(const int* __restrict__ node_types, const int* __restrict__ node_agents,
                         const float* __restrict__ type_embed, const float* __restrict__ gagent_embed,
                         const float* __restrict__ W, const float* __restrict__ b,
                         const float* __restrict__ g, const float* __restrict__ be,
                         float* __restrict__ h0, float* __restrict__ agg, float* __restrict__ deg) {
  int n = blockIdx.x, t = threadIdx.x;  // 64 threads = 1 wave
  __shared__ float x[64];
  int ty = node_types[n], ag = node_agents[n];
  x[t] = (t < 32) ? type_embed[ty * 32 + t] : gagent_embed[ag * 32 + (t - 32)];
  agg[(size_t)n * 64 + t] = 0.f;  // fused memset
  if (t == 0) deg[n] = 0.f;
  __syncthreads();
  float acc = b[t];
#pragma unroll 8
  for (int i = 0; i < 64; i++) acc += x[i] * W[i * 64 + t];
  acc = fmaxf(acc, 0.f);
  float m = wsum(acc) * (1.f / 64.f);
  float d = acc - m;
  float v = wsum(d * d) * (1.f / 64.f);
  h0[(size_t)n * 64 + t] = d * rsqrtf(v + 1e-5f) * g[t] + be[t];
}

__global__ void edge_k(const int* __restrict__ edges, const float* __restrict__ h0,
                       float* __restrict__ agg, float* __restrict__ deg) {
  int idx = blockIdx.x * 256 + threadIdx.x;
  if (idx >= E_ * 64) return;
  int e = idx >> 6, c = idx & 63;
  int s = edges[e * 2 + 0], d = edges[e * 2 + 1];
  atomicAdd(&agg[(size_t)d * 64 + c], h0[(size_t)s * 64 + c]);
  atomicAdd(&agg[(size_t)s * 64 + c], h0[(size_t)d * 64 + c]);
  if (c == 0) { atomicAdd(&deg[d], 1.f); atomicAdd(&deg[s], 1.f); }
}

__global__ void gnn_l1_k(const float* __restrict__ h0, const float* __restrict__ agg,
                         const float* __restrict__ deg, const float* __restrict__ W,
                         const float* __restrict__ b, const float* __restrict__ g,
                         const float* __restrict__ be, float* __restrict__ h1) {
  int n = blockIdx.x, t = threadIdx.x;  // 64 threads
  __shared__ float x[128];
  x[t] = h0[(size_t)n * 64 + t];
  x[64 + t] = agg[(size_t)n * 64 + t] / fmaxf(deg[n], 1.0f);
  __syncthreads();
  float acc = b[t];
#pragma unroll 8
  for (int i = 0; i < 128; i++) acc += x[i] * W[i * 64 + t];
  acc = fmaxf(acc, 0.f);
  float m = wsum(acc) * (1.f / 64.f);
  float d = acc - m;
  float v = wsum(d * d) * (1.f / 64.f);
  h1[(size_t)n * 64 + t] = d * rsqrtf(v + 1e-5f) * g[t] + be[t];
}

__global__ void colmean_k(const float* __restrict__ h1, float* __restrict__ meanv) {
  int c = blockIdx.x, t = threadIdx.x;
  float s = 0.f;
  for (int n = t; n < N_; n += 256) s += h1[(size_t)n * 64 + c];
  __shared__ float red[256];
  red[t] = s;
  __syncthreads();
  for (int off = 128; off >= 1; off >>= 1) {
    if (t < off) red[t] += red[t + off];
    __syncthreads();
  }
  if (t == 0) meanv[c] = red[0] / (float)N_;
}

// fused: ge = meanv@Wgp+bgp (recomputed per block, trivial), then biasA (blocks 0-31) / biasV (32-35)
__global__ void fused_bias_k(const float* __restrict__ meanv, const float* __restrict__ Wgp,
                             const float* __restrict__ bgp, const float* __restrict__ agent_embed,
                             const float* __restrict__ Wp1, const float* __restrict__ bp1,
                             const float* __restrict__ Wv1, const float* __restrict__ bv1,
                             float* __restrict__ biasA, float* __restrict__ biasV) {
  __shared__ float ge[64];
  int t = threadIdx.x;
  if (t < 64) {
    float s = bgp[t];
    for (int g2 = 0; g2 < 64; g2++) s += meanv[g2] * Wgp[g2 * 64 + t];
    ge[t] = s;
  }
  __syncthreads();
  int blk = blockIdx.x;
  if (blk < 32) {
    int idx = blk * 256 + t;
    int a = idx >> 10, o = idx & 1023;
    float s = bp1[o];
    for (int g2 = 0; g2 < 64; g2++) s += ge[g2] * Wp1[(size_t)(512 + g2) * 1024 + o];
    for (int e = 0; e < 16; e++) s += agent_embed[a * 16 + e] * Wp1[(size_t)(576 + e) * 1024 + o];
    biasA[idx] = s;
  } else {
    int o = (blk - 32) * 256 + t;
    float s = bv1[o];
    for (int g2 = 0; g2 < 64; g2++) s += ge[g2] * Wv1[(size_t)(4096 + g2) * 1024 + o];
    biasV[o] = s;
  }
}

// ---------------- conversions ----------------
__global__ void conv_joint_k(const float* __restrict__ obs, bf16* __restrict__ joint) {
  size_t i = ((size_t)blockIdx.x * 256 + threadIdx.x) * 8;
  int a = (int)(i >> 21);
  int rem = (int)(i & ((1u << 21) - 1));
  int b = rem >> 9, k = rem & 511;
  const float* p = obs + i;
  short8 o;
#pragma unroll
  for (int t = 0; t < 8; t++) o[t] = (short)f2bu(p[t]);
  *(short8*)(joint + (size_t)b * 4096 + a * 512 + k) = o;
}

__global__ void wtrans_k(const float* __restrict__ W, bf16* __restrict__ Wt, int K, int N) {
  __shared__ float t[32][33];
  int n0 = blockIdx.x * 32, k0 = blockIdx.y * 32;
  int tx = threadIdx.x & 31, ty = threadIdx.x >> 5;  // 32x8
#pragma unroll
  for (int r = ty; r < 32; r += 8) t[r][tx] = W[(size_t)(k0 + r) * N + n0 + tx];
  __syncthreads();
#pragma unroll
  for (int r = ty; r < 32; r += 8) Wt[(size_t)(n0 + r) * K + k0 + tx] = __float2bfloat16(t[tx][r]);
}

// ---------------- MFMA GEMM: DEPTH-deep multi-buffer pipeline, counted vmcnt ----------------
// Per K-tile: stage(T+DEPTH) -> vmcnt(DEPTH*G) -> barrier -> frag reads + MFMA -> barrier.
// NB=DEPTH+1 LDS buffers; vmcnt never drains to 0 in the main loop.
// A: row-major [M][K] bf16 (AMODE 0) or joint-gather (AMODE 1). Bt: [N][K] bf16.
// BIASMODE 0: bias[col]; 1: bias[(row>>12)*1024 + col]
template <int FM, int FN, int WAVES_M, int WAVES_N, int DEPTH, int AMODE, int BIASMODE, bool RELU,
          typename TC>
__launch_bounds__(WAVES_M * WAVES_N * 64, 2)
__global__ void pgemm_k(const bf16* __restrict__ Ap, const bf16* __restrict__ Bt,
                        const float* __restrict__ biasp, TC* __restrict__ Cp,
                        int M, int N, int K) {
  constexpr int NTHR = WAVES_M * WAVES_N * 64;
  constexpr int AR = WAVES_M * FM * 16;  // tile A-rows (BM)
  constexpr int BR = WAVES_N * FN * 16;  // tile B-rows (BN)
  constexpr int RPG = NTHR / 4;          // rows per stage group (64B rows, 16B/lane)
  constexpr int AG = AR / RPG;
  constexpr int BG = BR / RPG;
  constexpr int G = AG + BG;             // gloads per K-tile per wave
  constexpr int GRP = NTHR * 16;
  constexpr int ABYTES = AR * 64;
  constexpr int SBUF = (AR + BR) * 64;
  constexpr int NB = DEPTH + 1;
  __shared__ char smem[NB * SBUF];

  const int tid = threadIdx.x;
  const int wid = tid >> 6, lane = tid & 63;
  const int wm = wid / WAVES_N, wn = wid % WAVES_N;
  const int l15 = lane & 15;

  // T1: bijective XCD swizzle (nwg % 8 == 0 for all launches here)
  const int nwg = gridDim.x * gridDim.y;
  int fid = blockIdx.y * gridDim.x + blockIdx.x;
  int swz = (fid & 7) * (nwg >> 3) + (fid >> 3);
  const int m0 = (swz / gridDim.x) * AR;
  const int n0 = (swz % gridDim.x) * BR;

  f32x4 acc[FM][FN];
#pragma unroll
  for (int i = 0; i < FM; i++)
#pragma unroll
    for (int j = 0; j < FN; j++) acc[i][j] = (f32x4){0.f, 0.f, 0.f, 0.f};

  // hoisted per-thread staging pointers (pre-swizzled global src, linear LDS dst)
  const bf16* pa[AG];
  const bf16* pb[BG];
  {
    int row = tid >> 2;
    int c = (tid & 3) ^ ((tid >> 3) & 3);
#pragma unroll
    for (int q = 0; q < AG; ++q) {
      int r = m0 + q * RPG + row;
      if (AMODE == 0)
        pa[q] = Ap + (size_t)r * K + c * 8;
      else
        pa[q] = Ap + (((size_t)(r & (B_ - 1))) << 12) + ((size_t)(r >> 12) << 9) + c * 8;
    }
#pragma unroll
    for (int q = 0; q < BG; ++q) {
      int r = n0 + q * RPG + row;
      pb[q] = Bt + (size_t)r * K + c * 8;
    }
  }

  // fragment LDS byte offsets (matching XOR swizzle)
  const int cA = (lane >> 4) ^ ((l15 >> 1) & 3);
  const int offA0 = (wm * FM * 16 + l15) * 64 + cA * 16;
  const int offB0 = ABYTES + (wn * FN * 16 + l15) * 64 + cA * 16;

  auto stage = [&](int buf) {
    char* base = smem + buf * SBUF;
#pragma unroll
    for (int q = 0; q < AG; ++q) {
      gload_lds16(pa[q], base + q * GRP + wid * 1024);
      pa[q] += 32;
    }
#pragma unroll
    for (int q = 0; q < BG; ++q) {
      gload_lds16(pb[q], base + ABYTES + q * GRP + wid * 1024);
      pb[q] += 32;
    }
  };

  auto comp = [&](int buf) {
    const char* sb = smem + buf * SBUF;
    short8 bfr[FN];
#pragma unroll
    for (int j = 0; j < FN; ++j) bfr[j] = *(const short8*)(sb + offB0 + j * 1024);
    constexpr int FH = (FM > 4) ? FM / 2 : FM;  // split A-halves to cap live VGPRs
#pragma unroll
    for (int h = 0; h < FM / FH; ++h) {
      short8 afr[FH];
#pragma unroll
      for (int i = 0; i < FH; ++i) afr[i] = *(const short8*)(sb + offA0 + (h * FH + i) * 1024);
      __builtin_amdgcn_s_setprio(1);
#pragma unroll
      for (int i = 0; i < FH; ++i)
#pragma unroll
        for (int j = 0; j < FN; ++j)
          acc[h * FH + i][j] =
              __builtin_amdgcn_mfma_f32_16x16x32_bf16(afr[i], bfr[j], acc[h * FH + i][j], 0, 0, 0);
      __builtin_amdgcn_s_setprio(0);
    }
  };

  const int nt = K >> 5;  // requires nt > DEPTH
#pragma unroll
  for (int q = 0; q < DEPTH; ++q) stage(q);
  int cbuf = 0, sbi = DEPTH;
  for (int T = 0; T < nt - DEPTH; ++T) {
    stage(sbi);
    if (++sbi == NB) sbi = 0;
    waitvm<DEPTH * G>();
    __builtin_amdgcn_s_barrier();
    asm volatile("" ::: "memory");
    comp(cbuf);
    if (++cbuf == NB) cbuf = 0;
    asm volatile("" ::: "memory");
    __builtin_amdgcn_s_barrier();
  }
// drain: d = tiles still in flight after the current one
#define DRAIN(d)                       \
  {                                    \
    waitvm<(d) * G>();                 \
    __builtin_amdgcn_s_barrier();      \
    asm volatile("" ::: "memory");     \
    comp(cbuf);                        \
    if (++cbuf == NB) cbuf = 0;        \
    asm volatile("" ::: "memory");     \
  }
  if constexpr (DEPTH == 4) { DRAIN(3) DRAIN(2) }
  DRAIN(1)
  DRAIN(0)
#undef DRAIN

  // epilogue: C/D layout col=lane&15, row=(lane>>4)*4+reg
#pragma unroll
  for (int i = 0; i < FM; ++i) {
    int rb = m0 + wm * FM * 16 + i * 16 + (lane >> 4) * 4;
#pragma unroll
    for (int j = 0; j < FN; ++j) {
      int col = n0 + wn * FN * 16 + j * 16 + l15;
#pragma unroll
      for (int r = 0; r < 4; r++) {
        int row = rb + r;
        float bias = (BIASMODE == 0) ? biasp[col] : biasp[((row >> 12) << 10) + col];
        float v = acc[i][j][r] + bias;
        if (RELU) v = fmaxf(v, 0.f);
        storeC(&Cp[(size_t)row * N + col], v);
      }
    }
  }
}

__global__ void v3_k(const bf16* __restrict__ hv2, const float* __restrict__ Wv3,
                     const float* __restrict__ bv3, float* __restrict__ out) {
  int wid = threadIdx.x >> 6, lane = threadIdx.x & 63;
  int row = blockIdx.x * 4 + wid;
  float s = 0.f;
#pragma unroll
  for (int k = lane; k < 1024; k += 64) s += __bfloat162float(hv2[(size_t)row * 1024 + k]) * Wv3[k];
  s = wsum(s);
  if (lane == 0) out[row] = s + bv3[0];
}

extern "C" void kernel_launch(void* const* d_in, const int* in_sizes, int n_in,
                              void* d_out, int out_size, void* d_ws, size_t ws_size,
                              hipStream_t stream) {
  const float* obs = (const float*)d_in[0];
  const int* node_types = (const int*)d_in[1];
  const int* node_agents = (const int*)d_in[2];
  const int* edges = (const int*)d_in[3];
  const float* type_embed = (const float*)d_in[4];
  const float* gagent_embed = (const float*)d_in[5];
  const float* W_l0 = (const float*)d_in[6];
  const float* b_l0 = (const float*)d_in[7];
  const float* g_l0 = (const float*)d_in[8];
  const float* be_l0 = (const float*)d_in[9];
  const float* W_l1 = (const float*)d_in[10];
  const float* b_l1 = (const float*)d_in[11];
  const float* g_l1 = (const float*)d_in[12];
  const float* be_l1 = (const float*)d_in[13];
  const float* W_gp = (const float*)d_in[14];
  const float* b_gp = (const float*)d_in[15];
  const float* agent_embed = (const float*)d_in[16];
  const float* Wp1 = (const float*)d_in[17];
  const float* bp1 = (const float*)d_in[18];
  const float* Wp2 = (const float*)d_in[19];
  const float* bp2 = (const float*)d_in[20];
  const float* Wp3 = (const float*)d_in[21];
  const float* bp3 = (const float*)d_in[22];
  const float* Wv1 = (const float*)d_in[23];
  const float* bv1 = (const float*)d_in[24];
  const float* Wv2 = (const float*)d_in[25];
  const float* bv2 = (const float*)d_in[26];
  const float* Wv3 = (const float*)d_in[27];
  const float* bv3 = (const float*)d_in[28];

  char* wsp = (char*)d_ws;
  auto alloc = [&](size_t bytes) {
    char* p = wsp;
    wsp += (bytes + 255) & ~(size_t)255;
    return p;
  };
  float* h0 = (float*)alloc((size_t)N_ * 64 * 4);
  float* agg = (float*)alloc((size_t)N_ * 64 * 4);
  float* deg = (float*)alloc((size_t)N_ * 4);
  float* h1 = (float*)alloc((size_t)N_ * 64 * 4);
  float* meanv = (float*)alloc(64 * 4);
  float* biasA = (float*)alloc(8 * 1024 * 4);
  float* biasV = (float*)alloc(1024 * 4);
  bf16* joint = (bf16*)alloc((size_t)4096 * 4096 * 2);
  bf16* Wp1t = (bf16*)alloc((size_t)1024 * 512 * 2);
  bf16* Wp2t = (bf16*)alloc((size_t)1024 * 1024 * 2);
  bf16* Wp3t = (bf16*)alloc((size_t)64 * 1024 * 2);
  bf16* Wv1t = (bf16*)alloc((size_t)1024 * 4096 * 2);
  bf16* Wv2t = (bf16*)alloc((size_t)1024 * 1024 * 2);
  bf16* C1 = (bf16*)alloc((size_t)32768 * 1024 * 2);
  bf16* C2 = (bf16*)alloc((size_t)32768 * 1024 * 2);
  bf16* hv = (bf16*)alloc((size_t)4096 * 1024 * 2);
  bf16* hv2 = (bf16*)alloc((size_t)4096 * 1024 * 2);

  float* logits = (float*)d_out;
  float* value = (float*)d_out + (size_t)A_ * B_ * ACT_;

  gnn_l0_k<<<N_, 64, 0, stream>>>(node_types, node_agents, type_embed, gagent_embed, W_l0, b_l0,
                                  g_l0, be_l0, h0, agg, deg);
  edge_k<<<(E_ * 64) / 256, 256, 0, stream>>>(edges, h0, agg, deg);
  gnn_l1_k<<<N_, 64, 0, stream>>>(h0, agg, deg, W_l1, b_l1, g_l1, be_l1, h1);
  colmean_k<<<64, 256, 0, stream>>>(h1, meanv);
  fused_bias_k<<<36, 256, 0, stream>>>(meanv, W_gp, b_gp, agent_embed, Wp1, bp1, Wv1, bv1, biasA,
                                       biasV);

  conv_joint_k<<<(A_ * B_ * OBS_) / 8 / 256, 256, 0, stream>>>(obs, joint);
  wtrans_k<<<dim3(1024 / 32, 512 / 32), 256, 0, stream>>>(Wp1, Wp1t, 512, 1024);
  wtrans_k<<<dim3(1024 / 32, 1024 / 32), 256, 0, stream>>>(Wp2, Wp2t, 1024, 1024);
  wtrans_k<<<dim3(64 / 32, 1024 / 32), 256, 0, stream>>>(Wp3, Wp3t, 1024, 64);
  wtrans_k<<<dim3(1024 / 32, 4096 / 32), 256, 0, stream>>>(Wv1, Wv1t, 4096, 1024);
  wtrans_k<<<dim3(1024 / 32, 1024 / 32), 256, 0, stream>>>(Wv2, Wv2t, 1024, 1024);

  // P1: C1 = relu(obs2d @ Wp1[0:512] + biasA[agent])  M=32768 N=1024 K=512, 256x128, D2
  pgemm_k<8, 4, 2, 2, 2, 1, 1, true, bf16>
      <<<dim3(8, 128), 256, 0, stream>>>(joint, Wp1t, biasA, C1, 32768, 1024, 512);
  // P2: C2 = relu(C1 @ Wp2 + bp2)                     M=32768 N=1024 K=1024, 256x128, D2
  pgemm_k<8, 4, 2, 2, 2, 0, 0, true, bf16>
      <<<dim3(8, 128), 256, 0, stream>>>(C1, Wp2t, bp2, C2, 32768, 1024, 1024);
  // P3: logits = C2 @ Wp3 + bp3                       M=32768 N=64 K=1024, 128x64, D4
  pgemm_k<4, 2, 2, 2, 4, 0, 0, false, float>
      <<<dim3(1, 256), 256, 0, stream>>>(C2, Wp3t, bp3, logits, 32768, 64, 1024);
  // V1: hv = relu(joint @ Wv1 + biasV)                M=4096 N=1024 K=4096, 128x128, D4
  pgemm_k<4, 4, 2, 2, 4, 0, 0, true, bf16>
      <<<dim3(8, 32), 256, 0, stream>>>(joint, Wv1t, biasV, hv, 4096, 1024, 4096);
  // V2: hv2 = relu(hv @ Wv2 + bv2)                    M=4096 N=1024 K=1024, 128x128, D4
  pgemm_k<4, 4, 2, 2, 4, 0, 0, true, bf16>
      <<<dim3(8, 32), 256, 0, stream>>>(hv, Wv2t, bv2, hv2, 4096, 1024, 1024);
  // V3: value = hv2 @ Wv3 + bv3
  v3_k<<<1024, 256, 0, stream>>>(hv2, Wv3, bv3, value);
}

// Round 6
// 305.851 us; speedup vs baseline: 10.1077x; 1.0002x over previous
//
#include <hip/hip_runtime.h>
#include <hip/hip_bf16.h>

#define A_ 8
#define B_ 4096
#define OBS_ 512
#define ACT_ 64
#define H_ 1024
#define G_ 64
#define N_ 10000
#define E_ 40000

using bf16 = __hip_bfloat16;
typedef __attribute__((ext_vector_type(8))) short short8;
typedef __attribute__((ext_vector_type(4))) float f32x4;

__device__ __forceinline__ float wsum(float v) {
#pragma unroll
  for (int off = 32; off >= 1; off >>= 1) v += __shfl_xor(v, off, 64);
  return v;
}

__device__ __forceinline__ void storeC(float* p, float v) { *p = v; }
__device__ __forceinline__ void storeC(bf16* p, float v) { *p = __float2bfloat16(v); }

__device__ __forceinline__ unsigned short f2bu(float x) {
  bf16 h = __float2bfloat16(x);
  unsigned short u;
  __builtin_memcpy(&u, &h, 2);
  return u;
}

__device__ __forceinline__ void gload_lds16(const bf16* g, const void* lds_uniform) {
  __builtin_amdgcn_global_load_lds(
      (const __attribute__((address_space(1))) unsigned int*)g,
      (__attribute__((address_space(3))) unsigned int*)lds_uniform, 16, 0, 0);
}

template <int N>
__device__ __forceinline__ void waitvm() {
#define WV_CASE(n) if constexpr (N == n) asm volatile("s_waitcnt vmcnt(" #n ")" ::: "memory");
  WV_CASE(0) WV_CASE(1) WV_CASE(2) WV_CASE(3) WV_CASE(4) WV_CASE(5) WV_CASE(6) WV_CASE(7)
  WV_CASE(8) WV_CASE(9) WV_CASE(10) WV_CASE(12) WV_CASE(16)
  static_assert(N <= 16, "vmcnt too large");
#undef WV_CASE
}

// ---------------- GNN ----------------
__global__ void gnn_l0_k(const int* __restrict__ node_types, const int* __restrict__ node_agents,
                         const float* __restrict__ type_embed, const float* __restrict__ gagent_embed,
                         const float* __restrict__ W, const float* __restrict__ b,
                         const float* __restrict__ g, const float* __restrict__ be,
                         float* __restrict__ h0, float* __restrict__ agg, float* __restrict__ deg) {
  int n = blockIdx.x, t = threadIdx.x;  // 64 threads = 1 wave
  __shared__ float x[64];
  int ty = node_types[n], ag = node_agents[n];
  x[t] = (t < 32) ? type_embed[ty * 32 + t] : gagent_embed[ag * 32 + (t - 32)];
  agg[(size_t)n * 64 + t] = 0.f;  // fused memset
  if (t == 0) deg[n] = 0.f;
  __syncthreads();
  float acc = b[t];
#pragma unroll 8
  for (int i = 0; i < 64; i++) acc += x[i] * W[i * 64 + t];
  acc = fmaxf(acc, 0.f);
  float m = wsum(acc) * (1.f / 64.f);
  float d = acc - m;
  float v = wsum(d * d) * (1.f / 64.f);
  h0[(size_t)n * 64 + t] = d * rsqrtf(v + 1e-5f) * g[t] + be[t];
}

__global__ void edge_k(const int* __restrict__ edges, const float* __restrict__ h0,
                       float* __restrict__ agg, float* __restrict__ deg) {
  int idx = blockIdx.x * 256 + threadIdx.x;
  if (idx >= E_ * 64) return;
  int e = idx >> 6, c = idx & 63;
  int s = edges[e * 2 + 0], d = edges[e * 2 + 1];
  atomicAdd(&agg[(size_t)d * 64 + c], h0[(size_t)s * 64 + c]);
  atomicAdd(&agg[(size_t)s * 64 + c], h0[(size_t)d * 64 + c]);
  if (c == 0) { atomicAdd(&deg[d], 1.f); atomicAdd(&deg[s], 1.f); }
}

__global__ void gnn_l1_k(const float* __restrict__ h0, const float* __restrict__ agg,
                         const float* __restrict__ deg, const float* __restrict__ W,
                         const float* __restrict__ b, const float* __restrict__ g,
                         const float* __restrict__ be, float* __restrict__ h1) {
  int n = blockIdx.x, t = threadIdx.x;  // 64 threads
  __shared__ float x[128];
  x[t] = h0[(size_t)n * 64 + t];
  x[64 + t] = agg[(size_t)n * 64 + t] / fmaxf(deg[n], 1.0f);
  __syncthreads();
  float acc = b[t];
#pragma unroll 8
  for (int i = 0; i < 128; i++) acc += x[i] * W[i * 64 + t];
  acc = fmaxf(acc, 0.f);
  float m = wsum(acc) * (1.f / 64.f);
  float d = acc - m;
  float v = wsum(d * d) * (1.f / 64.f);
  h1[(size_t)n * 64 + t] = d * rsqrtf(v + 1e-5f) * g[t] + be[t];
}

__global__ void colmean_k(const float* __restrict__ h1, float* __restrict__ meanv) {
  int c = blockIdx.x, t = threadIdx.x;
  float s = 0.f;
  for (int n = t; n < N_; n += 256) s += h1[(size_t)n * 64 + c];
  __shared__ float red[256];
  red[t] = s;
  __syncthreads();
  for (int off = 128; off >= 1; off >>= 1) {
    if (t < off) red[t] += red[t + off];
    __syncthreads();
  }
  if (t == 0) meanv[c] = red[0] / (float)N_;
}

__global__ void fused_bias_k(const float* __restrict__ meanv, const float* __restrict__ Wgp,
                             const float* __restrict__ bgp, const float* __restrict__ agent_embed,
                             const float* __restrict__ Wp1, const float* __restrict__ bp1,
                             const float* __restrict__ Wv1, const float* __restrict__ bv1,
                             float* __restrict__ biasA, float* __restrict__ biasV) {
  __shared__ float ge[64];
  int t = threadIdx.x;
  if (t < 64) {
    float s = bgp[t];
    for (int g2 = 0; g2 < 64; g2++) s += meanv[g2] * Wgp[g2 * 64 + t];
    ge[t] = s;
  }
  __syncthreads();
  int blk = blockIdx.x;
  if (blk < 32) {
    int idx = blk * 256 + t;
    int a = idx >> 10, o = idx & 1023;
    float s = bp1[o];
    for (int g2 = 0; g2 < 64; g2++) s += ge[g2] * Wp1[(size_t)(512 + g2) * 1024 + o];
    for (int e = 0; e < 16; e++) s += agent_embed[a * 16 + e] * Wp1[(size_t)(576 + e) * 1024 + o];
    biasA[idx] = s;
  } else {
    int o = (blk - 32) * 256 + t;
    float s = bv1[o];
    for (int g2 = 0; g2 < 64; g2++) s += ge[g2] * Wv1[(size_t)(4096 + g2) * 1024 + o];
    biasV[o] = s;
  }
}

// ---------------- conversions ----------------
__global__ void conv_joint_k(const float* __restrict__ obs, bf16* __restrict__ joint) {
  size_t i = ((size_t)blockIdx.x * 256 + threadIdx.x) * 8;
  int a = (int)(i >> 21);
  int rem = (int)(i & ((1u << 21) - 1));
  int b = rem >> 9, k = rem & 511;
  const float* p = obs + i;
  short8 o;
#pragma unroll
  for (int t = 0; t < 8; t++) o[t] = (short)f2bu(p[t]);
  *(short8*)(joint + (size_t)b * 4096 + a * 512 + k) = o;
}

__global__ void wtrans_k(const float* __restrict__ W, bf16* __restrict__ Wt, int K, int N) {
  __shared__ float t[32][33];
  int n0 = blockIdx.x * 32, k0 = blockIdx.y * 32;
  int tx = threadIdx.x & 31, ty = threadIdx.x >> 5;  // 32x8
#pragma unroll
  for (int r = ty; r < 32; r += 8) t[r][tx] = W[(size_t)(k0 + r) * N + n0 + tx];
  __syncthreads();
#pragma unroll
  for (int r = ty; r < 32; r += 8) Wt[(size_t)(n0 + r) * K + k0 + tx] = __float2bfloat16(t[tx][r]);
}

// ======== g8_k: 256x256 tile, BK=32, 8 waves (2x4), 4 sub-phases/K-tile, triple buffer =======
// Per wave: 128x64 output = acc[8][4]. Per K-tile: 4 regions x {1 G-load, quadrant ds_reads,
// barrier, 8 MFMA (setprio), barrier}. vmcnt counted only at tile boundary (2-tile cover).
#define MM1(i, j, af, bf) \
  acc[i][j] = __builtin_amdgcn_mfma_f32_16x16x32_bf16(af, bf, acc[i][j], 0, 0, 0)
#define MM4x2(h, v)                                                         \
  MM1((h) * 4 + 0, (v) * 2 + 0, afr0, bfr0); MM1((h) * 4 + 0, (v) * 2 + 1, afr0, bfr1); \
  MM1((h) * 4 + 1, (v) * 2 + 0, afr1, bfr0); MM1((h) * 4 + 1, (v) * 2 + 1, afr1, bfr1); \
  MM1((h) * 4 + 2, (v) * 2 + 0, afr2, bfr0); MM1((h) * 4 + 2, (v) * 2 + 1, afr2, bfr1); \
  MM1((h) * 4 + 3, (v) * 2 + 0, afr3, bfr0); MM1((h) * 4 + 3, (v) * 2 + 1, afr3, bfr1)

#define BAR()                          \
  __builtin_amdgcn_s_barrier();        \
  asm volatile("" ::: "memory")

#define G8_BODY(WN_, STG_)                                                       \
  {                                                                              \
    const char* sb = smem + cbuf * SBUF;                                         \
    char* so = smem + sbi * SBUF;                                                \
    short8 afr0, afr1, afr2, afr3, bfr0, bfr1;                                   \
    /* sp0 (h0,v0) */                                                            \
    if (STG_) { gload_lds16(pA0, so + wid * 1024); pA0 += 32; }                  \
    waitvm<WN_>();                                                               \
    BAR();                                                                       \
    afr0 = *(const short8*)(sb + offA + 0 * 1024);                               \
    afr1 = *(const short8*)(sb + offA + 1 * 1024);                               \
    afr2 = *(const short8*)(sb + offA + 2 * 1024);                               \
    afr3 = *(const short8*)(sb + offA + 3 * 1024);                               \
    bfr0 = *(const short8*)(sb + offB + 0 * 1024);                               \
    bfr1 = *(const short8*)(sb + offB + 1 * 1024);                               \
    BAR();                                                                       \
    __builtin_amdgcn_s_setprio(1);                                               \
    MM4x2(0, 0);                                                                 \
    __builtin_amdgcn_s_setprio(0);                                               \
    BAR();                                                                       \
    /* sp1 (h0,v1) */                                                            \
    if (STG_) { gload_lds16(pA1, so + 8192 + wid * 1024); pA1 += 32; }           \
    bfr0 = *(const short8*)(sb + offB + 2 * 1024);                               \
    bfr1 = *(const short8*)(sb + offB + 3 * 1024);                               \
    BAR();                                                                       \
    __builtin_amdgcn_s_setprio(1);                                               \
    MM4x2(0, 1);                                                                 \
    __builtin_amdgcn_s_setprio(0);                                               \
    BAR();                                                                       \
    /* sp2 (h1,v1) */                                                            \
    if (STG_) { gload_lds16(pB0, so + ABYTES + wid * 1024); pB0 += 32; }         \
    afr0 = *(const short8*)(sb + offA + 4 * 1024);                               \
    afr1 = *(const short8*)(sb + offA + 5 * 1024);                               \
    afr2 = *(const short8*)(sb + offA + 6 * 1024);                               \
    afr3 = *(const short8*)(sb + offA + 7 * 1024);                               \
    BAR();                                                                       \
    __builtin_amdgcn_s_setprio(1);                                               \
    MM4x2(1, 1);                                                                 \
    __builtin_amdgcn_s_setprio(0);                                               \
    BAR();                                                                       \
    /* sp3 (h1,v0) */                                                            \
    if (STG_) { gload_lds16(pB1, so + ABYTES + 8192 + wid * 1024); pB1 += 32; }  \
    bfr0 = *(const short8*)(sb + offB + 0 * 1024);                               \
    bfr1 = *(const short8*)(sb + offB + 1 * 1024);                               \
    BAR();                                                                       \
    __builtin_amdgcn_s_setprio(1);                                               \
    MM4x2(1, 0);                                                                 \
    __builtin_amdgcn_s_setprio(0);                                               \
    BAR();                                                                       \
    if (++cbuf == 3) cbuf = 0;                                                   \
    if (STG_) { if (++sbi == 3) sbi = 0; }                                       \
  }

template <int AMODE, int BIASMODE, bool RELU, typename TC>
__launch_bounds__(512, 1)
__global__ void g8_k(const bf16* __restrict__ Ap, const bf16* __restrict__ Bt,
                     const float* __restrict__ biasp, TC* __restrict__ Cp,
                     int M, int N, int K) {
  constexpr int SBUF = 512 * 64;    // (256+256) rows x 64B
  constexpr int ABYTES = 256 * 64;  // A region per buffer
  __shared__ char smem[3 * SBUF];   // 96 KB triple buffer

  const int tid = threadIdx.x;
  const int wid = tid >> 6, lane = tid & 63;
  const int wm = wid >> 2, wn = wid & 3;
  const int l15 = lane & 15;

  // T1: bijective XCD swizzle (nwg % 8 == 0)
  const int nwg = gridDim.x * gridDim.y;
  int fid = blockIdx.y * gridDim.x + blockIdx.x;
  int swz = (fid & 7) * (nwg >> 3) + (fid >> 3);
  const int m0 = (swz / gridDim.x) * 256;
  const int n0 = (swz % gridDim.x) * 256;

  f32x4 acc[8][4];
#pragma unroll
  for (int i = 0; i < 8; i++)
#pragma unroll
    for (int j = 0; j < 4; j++) acc[i][j] = (f32x4){0.f, 0.f, 0.f, 0.f};

  // staging pointers: 512 thr x 16B = 128 rows (64B each) per group; 2 A-groups + 2 B-groups
  const bf16 *pA0, *pA1, *pB0, *pB1;
  {
    int row = tid >> 2;
    int c = (tid & 3) ^ ((tid >> 3) & 3);  // XOR swizzle on 16B slots
    int rA0 = m0 + row, rA1 = m0 + 128 + row;
    if (AMODE == 0) {
      pA0 = Ap + (size_t)rA0 * K + c * 8;
      pA1 = Ap + (size_t)rA1 * K + c * 8;
    } else {
      pA0 = Ap + (((size_t)(rA0 & (B_ - 1))) << 12) + ((size_t)(rA0 >> 12) << 9) + c * 8;
      pA1 = Ap + (((size_t)(rA1 & (B_ - 1))) << 12) + ((size_t)(rA1 >> 12) << 9) + c * 8;
    }
    pB0 = Bt + (size_t)(n0 + row) * K + c * 8;
    pB1 = Bt + (size_t)(n0 + 128 + row) * K + c * 8;
  }

  // fragment LDS byte offsets (matching XOR swizzle; row-base-independent)
  const int cA = (lane >> 4) ^ ((l15 >> 1) & 3);
  const int offA = (wm * 128 + l15) * 64 + cA * 16;
  const int offB = ABYTES + (wn * 64 + l15) * 64 + cA * 16;

  const int nt = K >> 5;  // requires nt >= 3
  // prologue: tiles 0,1 -> bufs 0,1 (8 loads)
#pragma unroll
  for (int b = 0; b < 2; ++b) {
    char* so = smem + b * SBUF;
    gload_lds16(pA0, so + wid * 1024); pA0 += 32;
    gload_lds16(pA1, so + 8192 + wid * 1024); pA1 += 32;
    gload_lds16(pB0, so + ABYTES + wid * 1024); pB0 += 32;
    gload_lds16(pB1, so + ABYTES + 8192 + wid * 1024); pB1 += 32;
  }
  int cbuf = 0, sbi = 2;
  for (int T = 0; T < nt - 2; ++T) G8_BODY(5, 1)
  G8_BODY(4, 0)
  G8_BODY(0, 0)

  // epilogue: C/D layout col=lane&15, row=(lane>>4)*4+reg
#pragma unroll
  for (int i = 0; i < 8; ++i) {
    int rb = m0 + wm * 128 + i * 16 + (lane >> 4) * 4;
#pragma unroll
    for (int j = 0; j < 4; ++j) {
      int col = n0 + wn * 64 + j * 16 + l15;
#pragma unroll
      for (int r = 0; r < 4; r++) {
        int row = rb + r;
        float bias = (BIASMODE == 0) ? biasp[col] : biasp[((row >> 12) << 10) + col];
        float v = acc[i][j][r] + bias;
        if (RELU) v = fmaxf(v, 0.f);
        storeC(&Cp[(size_t)row * N + col], v);
      }
    }
  }
}

// ---------------- MFMA GEMM: DEPTH-deep multi-buffer pipeline, counted vmcnt ----------------
template <int FM, int FN, int WAVES_M, int WAVES_N, int DEPTH, int AMODE, int BIASMODE, bool RELU,
          typename TC>
__launch_bounds__(WAVES_M * WAVES_N * 64, 2)
__global__ void pgemm_k(const bf16* __restrict__ Ap, const bf16* __restrict__ Bt,
                        const float* __restrict__ biasp, TC* __restrict__ Cp,
                        int M, int N, int K) {
  constexpr int NTHR = WAVES_M * WAVES_N * 64;
  constexpr int AR = WAVES_M * FM * 16;
  constexpr int BR = WAVES_N * FN * 16;
  constexpr int RPG = NTHR / 4;
  constexpr int AG = AR / RPG;
  constexpr int BG = BR / RPG;
  constexpr int G = AG + BG;
  constexpr int GRP = NTHR * 16;
  constexpr int ABYTES = AR * 64;
  constexpr int SBUF = (AR + BR) * 64;
  constexpr int NB = DEPTH + 1;
  __shared__ char smem[NB * SBUF];

  const int tid = threadIdx.x;
  const int wid = tid >> 6, lane = tid & 63;
  const int wm = wid / WAVES_N, wn = wid % WAVES_N;
  const int l15 = lane & 15;

  const int nwg = gridDim.x * gridDim.y;
  int fid = blockIdx.y * gridDim.x + blockIdx.x;
  int swz = (fid & 7) * (nwg >> 3) + (fid >> 3);
  const int m0 = (swz / gridDim.x) * AR;
  const int n0 = (swz % gridDim.x) * BR;

  f32x4 acc[FM][FN];
#pragma unroll
  for (int i = 0; i < FM; i++)
#pragma unroll
    for (int j = 0; j < FN; j++) acc[i][j] = (f32x4){0.f, 0.f, 0.f, 0.f};

  const bf16* pa[AG];
  const bf16* pb[BG];
  {
    int row = tid >> 2;
    int c = (tid & 3) ^ ((tid >> 3) & 3);
#pragma unroll
    for (int q = 0; q < AG; ++q) {
      int r = m0 + q * RPG + row;
      if (AMODE == 0)
        pa[q] = Ap + (size_t)r * K + c * 8;
      else
        pa[q] = Ap + (((size_t)(r & (B_ - 1))) << 12) + ((size_t)(r >> 12) << 9) + c * 8;
    }
#pragma unroll
    for (int q = 0; q < BG; ++q) {
      int r = n0 + q * RPG + row;
      pb[q] = Bt + (size_t)r * K + c * 8;
    }
  }

  const int cA = (lane >> 4) ^ ((l15 >> 1) & 3);
  const int offA0 = (wm * FM * 16 + l15) * 64 + cA * 16;
  const int offB0 = ABYTES + (wn * FN * 16 + l15) * 64 + cA * 16;

  auto stage = [&](int buf) {
    char* base = smem + buf * SBUF;
#pragma unroll
    for (int q = 0; q < AG; ++q) {
      gload_lds16(pa[q], base + q * GRP + wid * 1024);
      pa[q] += 32;
    }
#pragma unroll
    for (int q = 0; q < BG; ++q) {
      gload_lds16(pb[q], base + ABYTES + q * GRP + wid * 1024);
      pb[q] += 32;
    }
  };

  auto comp = [&](int buf) {
    const char* sb = smem + buf * SBUF;
    short8 bfr[FN];
#pragma unroll
    for (int j = 0; j < FN; ++j) bfr[j] = *(const short8*)(sb + offB0 + j * 1024);
    constexpr int FH = (FM > 4) ? FM / 2 : FM;
#pragma unroll
    for (int h = 0; h < FM / FH; ++h) {
      short8 afr[FH];
#pragma unroll
      for (int i = 0; i < FH; ++i) afr[i] = *(const short8*)(sb + offA0 + (h * FH + i) * 1024);
      __builtin_amdgcn_s_setprio(1);
#pragma unroll
      for (int i = 0; i < FH; ++i)
#pragma unroll
        for (int j = 0; j < FN; ++j)
          acc[h * FH + i][j] =
              __builtin_amdgcn_mfma_f32_16x16x32_bf16(afr[i], bfr[j], acc[h * FH + i][j], 0, 0, 0);
      __builtin_amdgcn_s_setprio(0);
    }
  };

  const int nt = K >> 5;
#pragma unroll
  for (int q = 0; q < DEPTH; ++q) stage(q);
  int cbuf = 0, sbi = DEPTH;
  for (int T = 0; T < nt - DEPTH; ++T) {
    stage(sbi);
    if (++sbi == NB) sbi = 0;
    waitvm<DEPTH * G>();
    __builtin_amdgcn_s_barrier();
    asm volatile("" ::: "memory");
    comp(cbuf);
    if (++cbuf == NB) cbuf = 0;
    asm volatile("" ::: "memory");
    __builtin_amdgcn_s_barrier();
  }
#define DRAIN(d)                       \
  {                                    \
    waitvm<(d) * G>();                 \
    __builtin_amdgcn_s_barrier();      \
    asm volatile("" ::: "memory");     \
    comp(cbuf);                        \
    if (++cbuf == NB) cbuf = 0;        \
    asm volatile("" ::: "memory");     \
  }
  if constexpr (DEPTH == 4) { DRAIN(3) DRAIN(2) }
  DRAIN(1)
  DRAIN(0)
#undef DRAIN

#pragma unroll
  for (int i = 0; i < FM; ++i) {
    int rb = m0 + wm * FM * 16 + i * 16 + (lane >> 4) * 4;
#pragma unroll
    for (int j = 0; j < FN; ++j) {
      int col = n0 + wn * FN * 16 + j * 16 + l15;
#pragma unroll
      for (int r = 0; r < 4; r++) {
        int row = rb + r;
        float bias = (BIASMODE == 0) ? biasp[col] : biasp[((row >> 12) << 10) + col];
        float v = acc[i][j][r] + bias;
        if (RELU) v = fmaxf(v, 0.f);
        storeC(&Cp[(size_t)row * N + col], v);
      }
    }
  }
}

__global__ void v3_k(const bf16* __restrict__ hv2, const float* __restrict__ Wv3,
                     const float* __restrict__ bv3, float* __restrict__ out) {
  int wid = threadIdx.x >> 6, lane = threadIdx.x & 63;
  int row = blockIdx.x * 4 + wid;
  float s = 0.f;
#pragma unroll
  for (int k = lane; k < 1024; k += 64) s += __bfloat162float(hv2[(size_t)row * 1024 + k]) * Wv3[k];
  s = wsum(s);
  if (lane == 0) out[row] = s + bv3[0];
}

extern "C" void kernel_launch(void* const* d_in, const int* in_sizes, int n_in,
                              void* d_out, int out_size, void* d_ws, size_t ws_size,
                              hipStream_t stream) {
  const float* obs = (const float*)d_in[0];
  const int* node_types = (const int*)d_in[1];
  const int* node_agents = (const int*)d_in[2];
  const int* edges = (const int*)d_in[3];
  const float* type_embed = (const float*)d_in[4];
  const float* gagent_embed = (const float*)d_in[5];
  const float* W_l0 = (const float*)d_in[6];
  const float* b_l0 = (const float*)d_in[7];
  const float* g_l0 = (const float*)d_in[8];
  const float* be_l0 = (const float*)d_in[9];
  const float* W_l1 = (const float*)d_in[10];
  const float* b_l1 = (const float*)d_in[11];
  const float* g_l1 = (const float*)d_in[12];
  const float* be_l1 = (const float*)d_in[13];
  const float* W_gp = (const float*)d_in[14];
  const float* b_gp = (const float*)d_in[15];
  const float* agent_embed = (const float*)d_in[16];
  const float* Wp1 = (const float*)d_in[17];
  const float* bp1 = (const float*)d_in[18];
  const float* Wp2 = (const float*)d_in[19];
  const float* bp2 = (const float*)d_in[20];
  const float* Wp3 = (const float*)d_in[21];
  const float* bp3 = (const float*)d_in[22];
  const float* Wv1 = (const float*)d_in[23];
  const float* bv1 = (const float*)d_in[24];
  const float* Wv2 = (const float*)d_in[25];
  const float* bv2 = (const float*)d_in[26];
  const float* Wv3 = (const float*)d_in[27];
  const float* bv3 = (const float*)d_in[28];

  char* wsp = (char*)d_ws;
  auto alloc = [&](size_t bytes) {
    char* p = wsp;
    wsp += (bytes + 255) & ~(size_t)255;
    return p;
  };
  float* h0 = (float*)alloc((size_t)N_ * 64 * 4);
  float* agg = (float*)alloc((size_t)N_ * 64 * 4);
  float* deg = (float*)alloc((size_t)N_ * 4);
  float* h1 = (float*)alloc((size_t)N_ * 64 * 4);
  float* meanv = (float*)alloc(64 * 4);
  float* biasA = (float*)alloc(8 * 1024 * 4);
  float* biasV = (float*)alloc(1024 * 4);
  bf16* joint = (bf16*)alloc((size_t)4096 * 4096 * 2);
  bf16* Wp1t = (bf16*)alloc((size_t)1024 * 512 * 2);
  bf16* Wp2t = (bf16*)alloc((size_t)1024 * 1024 * 2);
  bf16* Wp3t = (bf16*)alloc((size_t)64 * 1024 * 2);
  bf16* Wv1t = (bf16*)alloc((size_t)1024 * 4096 * 2);
  bf16* Wv2t = (bf16*)alloc((size_t)1024 * 1024 * 2);
  bf16* C1 = (bf16*)alloc((size_t)32768 * 1024 * 2);
  bf16* C2 = (bf16*)alloc((size_t)32768 * 1024 * 2);
  bf16* hv = (bf16*)alloc((size_t)4096 * 1024 * 2);
  bf16* hv2 = (bf16*)alloc((size_t)4096 * 1024 * 2);

  float* logits = (float*)d_out;
  float* value = (float*)d_out + (size_t)A_ * B_ * ACT_;

  gnn_l0_k<<<N_, 64, 0, stream>>>(node_types, node_agents, type_embed, gagent_embed, W_l0, b_l0,
                                  g_l0, be_l0, h0, agg, deg);
  edge_k<<<(E_ * 64) / 256, 256, 0, stream>>>(edges, h0, agg, deg);
  gnn_l1_k<<<N_, 64, 0, stream>>>(h0, agg, deg, W_l1, b_l1, g_l1, be_l1, h1);
  colmean_k<<<64, 256, 0, stream>>>(h1, meanv);
  fused_bias_k<<<36, 256, 0, stream>>>(meanv, W_gp, b_gp, agent_embed, Wp1, bp1, Wv1, bv1, biasA,
                                       biasV);

  conv_joint_k<<<(A_ * B_ * OBS_) / 8 / 256, 256, 0, stream>>>(obs, joint);
  wtrans_k<<<dim3(1024 / 32, 512 / 32), 256, 0, stream>>>(Wp1, Wp1t, 512, 1024);
  wtrans_k<<<dim3(1024 / 32, 1024 / 32), 256, 0, stream>>>(Wp2, Wp2t, 1024, 1024);
  wtrans_k<<<dim3(64 / 32, 1024 / 32), 256, 0, stream>>>(Wp3, Wp3t, 1024, 64);
  wtrans_k<<<dim3(1024 / 32, 4096 / 32), 256, 0, stream>>>(Wv1, Wv1t, 4096, 1024);
  wtrans_k<<<dim3(1024 / 32, 1024 / 32), 256, 0, stream>>>(Wv2, Wv2t, 1024, 1024);

  // P1: C1 = relu(obs2d @ Wp1[0:512] + biasA[agent])  M=32768 N=1024 K=512, g8 256x256
  g8_k<1, 1, true, bf16>
      <<<dim3(4, 128), 512, 0, stream>>>(joint, Wp1t, biasA, C1, 32768, 1024, 512);
  // P2: C2 = relu(C1 @ Wp2 + bp2)                     M=32768 N=1024 K=1024, g8 256x256
  g8_k<0, 0, true, bf16>
      <<<dim3(4, 128), 512, 0, stream>>>(C1, Wp2t, bp2, C2, 32768, 1024, 1024);
  // P3: logits = C2 @ Wp3 + bp3                       M=32768 N=64 K=1024, 128x64, D4
  pgemm_k<4, 2, 2, 2, 4, 0, 0, false, float>
      <<<dim3(1, 256), 256, 0, stream>>>(C2, Wp3t, bp3, logits, 32768, 64, 1024);
  // V1: hv = relu(joint @ Wv1 + biasV)                M=4096 N=1024 K=4096, 128x128, 8 waves, D4
  pgemm_k<4, 2, 2, 4, 4, 0, 0, true, bf16>
      <<<dim3(8, 32), 512, 0, stream>>>(joint, Wv1t, biasV, hv, 4096, 1024, 4096);
  // V2: hv2 = relu(hv @ Wv2 + bv2)                    M=4096 N=1024 K=1024, 128x128, 8 waves, D4
  pgemm_k<4, 2, 2, 4, 4, 0, 0, true, bf16>
      <<<dim3(8, 32), 512, 0, stream>>>(hv, Wv2t, bv2, hv2, 4096, 1024, 1024);
  // V3: value = hv2 @ Wv3 + bv3
  v3_k<<<1024, 256, 0, stream>>>(hv2, Wv3, bv3, value);
}

// Round 8
// 303.366 us; speedup vs baseline: 10.1905x; 1.0082x over previous
//
#include <hip/hip_runtime.h>
#include <hip/hip_bf16.h>

#define A_ 8
#define B_ 4096
#define OBS_ 512
#define ACT_ 64
#define H_ 1024
#define G_ 64
#define N_ 10000
#define E_ 40000

using bf16 = __hip_bfloat16;
typedef __attribute__((ext_vector_type(8))) short short8;
typedef __attribute__((ext_vector_type(4))) float f32x4;

__device__ __forceinline__ float wsum(float v) {
#pragma unroll
  for (int off = 32; off >= 1; off >>= 1) v += __shfl_xor(v, off, 64);
  return v;
}

__device__ __forceinline__ void storeC(float* p, float v) { *p = v; }
__device__ __forceinline__ void storeC(bf16* p, float v) { *p = __float2bfloat16(v); }

__device__ __forceinline__ unsigned short f2bu(float x) {
  bf16 h = __float2bfloat16(x);
  unsigned short u;
  __builtin_memcpy(&u, &h, 2);
  return u;
}

__device__ __forceinline__ void gload_lds16(const bf16* g, const void* lds_uniform) {
  __builtin_amdgcn_global_load_lds(
      (const __attribute__((address_space(1))) unsigned int*)g,
      (__attribute__((address_space(3))) unsigned int*)lds_uniform, 16, 0, 0);
}

template <int N>
__device__ __forceinline__ void waitvm() {
#define WV_CASE(n) if constexpr (N == n) asm volatile("s_waitcnt vmcnt(" #n ")" ::: "memory");
  WV_CASE(0) WV_CASE(1) WV_CASE(2) WV_CASE(3) WV_CASE(4) WV_CASE(5) WV_CASE(6) WV_CASE(7)
  WV_CASE(8) WV_CASE(9) WV_CASE(10) WV_CASE(12) WV_CASE(16)
  static_assert(N <= 16, "vmcnt too large");
#undef WV_CASE
}

// ---------------- GNN ----------------
__global__ void gnn_l0_k(const int* __restrict__ node_types, const int* __restrict__ node_agents,
                         const float* __restrict__ type_embed, const float* __restrict__ gagent_embed,
                         const float* __restrict__ W, const float* __restrict__ b,
                         const float* __restrict__ g, const float* __restrict__ be,
                         float* __restrict__ h0, float* __restrict__ agg, float* __restrict__ deg) {
  int n = blockIdx.x, t = threadIdx.x;  // 64 threads = 1 wave
  __shared__ float x[64];
  int ty = node_types[n], ag = node_agents[n];
  x[t] = (t < 32) ? type_embed[ty * 32 + t] : gagent_embed[ag * 32 + (t - 32)];
  agg[(size_t)n * 64 + t] = 0.f;  // fused memset
  if (t == 0) deg[n] = 0.f;
  __syncthreads();
  float acc = b[t];
#pragma unroll 8
  for (int i = 0; i < 64; i++) acc += x[i] * W[i * 64 + t];
  acc = fmaxf(acc, 0.f);
  float m = wsum(acc) * (1.f / 64.f);
  float d = acc - m;
  float v = wsum(d * d) * (1.f / 64.f);
  h0[(size_t)n * 64 + t] = d * rsqrtf(v + 1e-5f) * g[t] + be[t];
}

__global__ void edge_k(const int* __restrict__ edges, const float* __restrict__ h0,
                       float* __restrict__ agg, float* __restrict__ deg) {
  int idx = blockIdx.x * 256 + threadIdx.x;
  if (idx >= E_ * 64) return;
  int e = idx >> 6, c = idx & 63;
  int s = edges[e * 2 + 0], d = edges[e * 2 + 1];
  atomicAdd(&agg[(size_t)d * 64 + c], h0[(size_t)s * 64 + c]);
  atomicAdd(&agg[(size_t)s * 64 + c], h0[(size_t)d * 64 + c]);
  if (c == 0) { atomicAdd(&deg[d], 1.f); atomicAdd(&deg[s], 1.f); }
}

__global__ void gnn_l1_k(const float* __restrict__ h0, const float* __restrict__ agg,
                         const float* __restrict__ deg, const float* __restrict__ W,
                         const float* __restrict__ b, const float* __restrict__ g,
                         const float* __restrict__ be, float* __restrict__ h1) {
  int n = blockIdx.x, t = threadIdx.x;  // 64 threads
  __shared__ float x[128];
  x[t] = h0[(size_t)n * 64 + t];
  x[64 + t] = agg[(size_t)n * 64 + t] / fmaxf(deg[n], 1.0f);
  __syncthreads();
  float acc = b[t];
#pragma unroll 8
  for (int i = 0; i < 128; i++) acc += x[i] * W[i * 64 + t];
  acc = fmaxf(acc, 0.f);
  float m = wsum(acc) * (1.f / 64.f);
  float d = acc - m;
  float v = wsum(d * d) * (1.f / 64.f);
  h1[(size_t)n * 64 + t] = d * rsqrtf(v + 1e-5f) * g[t] + be[t];
}

__global__ void colmean_k(const float* __restrict__ h1, float* __restrict__ meanv) {
  int c = blockIdx.x, t = threadIdx.x;
  float s = 0.f;
  for (int n = t; n < N_; n += 256) s += h1[(size_t)n * 64 + c];
  __shared__ float red[256];
  red[t] = s;
  __syncthreads();
  for (int off = 128; off >= 1; off >>= 1) {
    if (t < off) red[t] += red[t + off];
    __syncthreads();
  }
  if (t == 0) meanv[c] = red[0] / (float)N_;
}

__global__ void fused_bias_k(const float* __restrict__ meanv, const float* __restrict__ Wgp,
                             const float* __restrict__ bgp, const float* __restrict__ agent_embed,
                             const float* __restrict__ Wp1, const float* __restrict__ bp1,
                             const float* __restrict__ Wv1, const float* __restrict__ bv1,
                             float* __restrict__ biasA, float* __restrict__ biasV) {
  __shared__ float ge[64];
  int t = threadIdx.x;
  if (t < 64) {
    float s = bgp[t];
    for (int g2 = 0; g2 < 64; g2++) s += meanv[g2] * Wgp[g2 * 64 + t];
    ge[t] = s;
  }
  __syncthreads();
  int blk = blockIdx.x;
  if (blk < 32) {
    int idx = blk * 256 + t;
    int a = idx >> 10, o = idx & 1023;
    float s = bp1[o];
    for (int g2 = 0; g2 < 64; g2++) s += ge[g2] * Wp1[(size_t)(512 + g2) * 1024 + o];
    for (int e = 0; e < 16; e++) s += agent_embed[a * 16 + e] * Wp1[(size_t)(576 + e) * 1024 + o];
    biasA[idx] = s;
  } else {
    int o = (blk - 32) * 256 + t;
    float s = bv1[o];
    for (int g2 = 0; g2 < 64; g2++) s += ge[g2] * Wv1[(size_t)(4096 + g2) * 1024 + o];
    biasV[o] = s;
  }
}

// ---------------- conversions ----------------
__global__ void conv_joint_k(const float* __restrict__ obs, bf16* __restrict__ joint) {
  size_t i = ((size_t)blockIdx.x * 256 + threadIdx.x) * 8;
  int a = (int)(i >> 21);
  int rem = (int)(i & ((1u << 21) - 1));
  int b = rem >> 9, k = rem & 511;
  const float* p = obs + i;
  short8 o;
#pragma unroll
  for (int t = 0; t < 8; t++) o[t] = (short)f2bu(p[t]);
  *(short8*)(joint + (size_t)b * 4096 + a * 512 + k) = o;
}

__global__ void wtrans_k(const float* __restrict__ W, bf16* __restrict__ Wt, int K, int N) {
  __shared__ float t[32][33];
  int n0 = blockIdx.x * 32, k0 = blockIdx.y * 32;
  int tx = threadIdx.x & 31, ty = threadIdx.x >> 5;  // 32x8
#pragma unroll
  for (int r = ty; r < 32; r += 8) t[r][tx] = W[(size_t)(k0 + r) * N + n0 + tx];
  __syncthreads();
#pragma unroll
  for (int r = ty; r < 32; r += 8) Wt[(size_t)(n0 + r) * K + k0 + tx] = __float2bfloat16(t[tx][r]);
}

// ======== g10_k: 256x256, BK=64, double buffer (128 KB), 4 phases/K-tile ====================
// INVARIANT: at top of iter t, tile t's 8 gloads are complete AND barrier'd.
// Per phase: {ds_read quadrant frags (buf cb, safe) | 2 gloads tile t+1 -> buf ob} -> barrier ->
//            setprio(1) 16 MFMA setprio(0) -> barrier.  vmcnt(0) once per K-tile at iter end
//            (cover = ~3 phases since the 8 loads are spread 2-per-phase).
// LDS rows = 128 B (8 slots of 16 B), XOR slot swizzle: slot = chunk ^ (row&7) (involution).
#define BARR()                        \
  asm volatile("" ::: "memory");      \
  __builtin_amdgcn_s_barrier();       \
  asm volatile("" ::: "memory")

#define RD8(off) (*(const short8*)(sb + (off)))

#define MMQ(FI0)                                                                     \
  __builtin_amdgcn_s_setprio(1);                                                     \
  acc[FI0 + 0][0] = __builtin_amdgcn_mfma_f32_16x16x32_bf16(a0, b0, acc[FI0 + 0][0], 0, 0, 0); \
  acc[FI0 + 0][1] = __builtin_amdgcn_mfma_f32_16x16x32_bf16(a0, b1, acc[FI0 + 0][1], 0, 0, 0); \
  acc[FI0 + 0][2] = __builtin_amdgcn_mfma_f32_16x16x32_bf16(a0, b2, acc[FI0 + 0][2], 0, 0, 0); \
  acc[FI0 + 0][3] = __builtin_amdgcn_mfma_f32_16x16x32_bf16(a0, b3, acc[FI0 + 0][3], 0, 0, 0); \
  acc[FI0 + 1][0] = __builtin_amdgcn_mfma_f32_16x16x32_bf16(a1, b0, acc[FI0 + 1][0], 0, 0, 0); \
  acc[FI0 + 1][1] = __builtin_amdgcn_mfma_f32_16x16x32_bf16(a1, b1, acc[FI0 + 1][1], 0, 0, 0); \
  acc[FI0 + 1][2] = __builtin_amdgcn_mfma_f32_16x16x32_bf16(a1, b2, acc[FI0 + 1][2], 0, 0, 0); \
  acc[FI0 + 1][3] = __builtin_amdgcn_mfma_f32_16x16x32_bf16(a1, b3, acc[FI0 + 1][3], 0, 0, 0); \
  acc[FI0 + 2][0] = __builtin_amdgcn_mfma_f32_16x16x32_bf16(a2, b0, acc[FI0 + 2][0], 0, 0, 0); \
  acc[FI0 + 2][1] = __builtin_amdgcn_mfma_f32_16x16x32_bf16(a2, b1, acc[FI0 + 2][1], 0, 0, 0); \
  acc[FI0 + 2][2] = __builtin_amdgcn_mfma_f32_16x16x32_bf16(a2, b2, acc[FI0 + 2][2], 0, 0, 0); \
  acc[FI0 + 2][3] = __builtin_amdgcn_mfma_f32_16x16x32_bf16(a2, b3, acc[FI0 + 2][3], 0, 0, 0); \
  acc[FI0 + 3][0] = __builtin_amdgcn_mfma_f32_16x16x32_bf16(a3, b0, acc[FI0 + 3][0], 0, 0, 0); \
  acc[FI0 + 3][1] = __builtin_amdgcn_mfma_f32_16x16x32_bf16(a3, b1, acc[FI0 + 3][1], 0, 0, 0); \
  acc[FI0 + 3][2] = __builtin_amdgcn_mfma_f32_16x16x32_bf16(a3, b2, acc[FI0 + 3][2], 0, 0, 0); \
  acc[FI0 + 3][3] = __builtin_amdgcn_mfma_f32_16x16x32_bf16(a3, b3, acc[FI0 + 3][3], 0, 0, 0); \
  __builtin_amdgcn_s_setprio(0)

template <int AMODE, int BIASMODE, bool RELU, typename TC>
__launch_bounds__(512, 1)
__global__ void g10_k(const bf16* __restrict__ Ap, const bf16* __restrict__ Bt,
                      const float* __restrict__ biasp, TC* __restrict__ Cp,
                      int M, int N, int K) {
  constexpr int SBUF = 65536;      // (256 A-rows + 256 B-rows) x 128 B
  __shared__ char smem[2 * SBUF];  // 128 KB double buffer

  const int tid = threadIdx.x;
  const int wid = tid >> 6, lane = tid & 63;
  const int wm = wid >> 2, wn = wid & 3;
  const int l15 = lane & 15;

  // T1: bijective XCD swizzle (nwg % 8 == 0)
  const int nwg = gridDim.x * gridDim.y;
  int fid = blockIdx.y * gridDim.x + blockIdx.x;
  int swz = (fid & 7) * (nwg >> 3) + (fid >> 3);
  const int m0 = (swz / gridDim.x) * 256;
  const int n0 = (swz % gridDim.x) * 256;

  f32x4 acc[8][4];
#pragma unroll
  for (int i = 0; i < 8; i++)
#pragma unroll
    for (int j = 0; j < 4; j++) acc[i][j] = (f32x4){0.f, 0.f, 0.f, 0.f};

  // staging: 8 gload groups, each 64 rows x 128 B; thread -> row = g*64 + tid>>3, slot = tid&7,
  // pre-swizzled source chunk c = slot ^ (row&7)
  const bf16* pg[8];
  {
    int srow = tid >> 3;
    int c = (tid & 7) ^ (srow & 7);
#pragma unroll
    for (int g = 0; g < 4; ++g) {
      int r = m0 + g * 64 + srow;
      if (AMODE == 0)
        pg[g] = Ap + (size_t)r * K + c * 8;
      else
        pg[g] = Ap + (((size_t)(r & (B_ - 1))) << 12) + ((size_t)(r >> 12) << 9) + c * 8;
    }
#pragma unroll
    for (int g = 4; g < 8; ++g) {
      int r = n0 + (g - 4) * 64 + srow;
      pg[g] = Bt + (size_t)r * K + c * 8;
    }
  }

  // fragment byte offsets; slot(kk) = (kk*4 + (lane>>4)) ^ (l15&7); kk toggles byte bit 6
  const int slot0 = (lane >> 4) ^ (l15 & 7);
  const int aof0 = (wm * 128 + l15) * 128 + slot0 * 16;
  const int bof0 = 32768 + (wn * 64 + l15) * 128 + slot0 * 16;
  const int aof1 = aof0 ^ 64;
  const int bof1 = bof0 ^ 64;

#define STG(g, buf)                                                    \
  {                                                                    \
    gload_lds16(pg[g], smem + (buf) * SBUF + (g) * 8192 + wid * 1024); \
    pg[g] += 64;                                                       \
  }

  // prologue: stage all of tile 0 into buf 0, wait, barrier  -> invariant established
#pragma unroll
  for (int g = 0; g < 8; ++g) STG(g, 0)
  waitvm<0>();
  BARR();

  const int nt = K >> 6;  // K-tiles of 64; nt >= 2
  for (int t = 0; t < nt; ++t) {
    const int cb = t & 1, ob = cb ^ 1;
    const bool last = (t == nt - 1);
    const char* sb = smem + cb * SBUF;
    short8 a0, a1, a2, a3, b0, b1, b2, b3;
    // ---- phase 0: kk=0, A frags 0-3 + B(kk=0)
    a0 = RD8(aof0 + 0 * 2048); a1 = RD8(aof0 + 1 * 2048);
    a2 = RD8(aof0 + 2 * 2048); a3 = RD8(aof0 + 3 * 2048);
    b0 = RD8(bof0 + 0 * 2048); b1 = RD8(bof0 + 1 * 2048);
    b2 = RD8(bof0 + 2 * 2048); b3 = RD8(bof0 + 3 * 2048);
    if (!last) { STG(0, ob) STG(1, ob) }
    BARR();
    MMQ(0);
    BARR();
    // ---- phase 1: kk=0, A frags 4-7 (reuse b0..b3)
    a0 = RD8(aof0 + 4 * 2048); a1 = RD8(aof0 + 5 * 2048);
    a2 = RD8(aof0 + 6 * 2048); a3 = RD8(aof0 + 7 * 2048);
    if (!last) { STG(2, ob) STG(3, ob) }
    BARR();
    MMQ(4);
    BARR();
    // ---- phase 2: kk=1, A frags 0-3 + B(kk=1)
    a0 = RD8(aof1 + 0 * 2048); a1 = RD8(aof1 + 1 * 2048);
    a2 = RD8(aof1 + 2 * 2048); a3 = RD8(aof1 + 3 * 2048);
    b0 = RD8(bof1 + 0 * 2048); b1 = RD8(bof1 + 1 * 2048);
    b2 = RD8(bof1 + 2 * 2048); b3 = RD8(bof1 + 3 * 2048);
    if (!last) { STG(4, ob) STG(5, ob) }
    BARR();
    MMQ(0);
    BARR();
    // ---- phase 3: kk=1, A frags 4-7
    a0 = RD8(aof1 + 4 * 2048); a1 = RD8(aof1 + 5 * 2048);
    a2 = RD8(aof1 + 6 * 2048); a3 = RD8(aof1 + 7 * 2048);
    if (!last) { STG(6, ob) STG(7, ob) }
    BARR();
    MMQ(4);
    if (!last) waitvm<0>();  // tile t+1 arrived (issued 2/phase, ~3 phases of cover)
    BARR();                  // -> invariant for iter t+1; also protects buf reuse
  }
#undef STG

  // epilogue: C/D layout col=lane&15, row=(lane>>4)*4+reg
#pragma unroll
  for (int i = 0; i < 8; ++i) {
    int rb = m0 + wm * 128 + i * 16 + (lane >> 4) * 4;
#pragma unroll
    for (int j = 0; j < 4; ++j) {
      int col = n0 + wn * 64 + j * 16 + l15;
#pragma unroll
      for (int r = 0; r < 4; r++) {
        int row = rb + r;
        float bias = (BIASMODE == 0) ? biasp[col] : biasp[((row >> 12) << 10) + col];
        float v = acc[i][j][r] + bias;
        if (RELU) v = fmaxf(v, 0.f);
        storeC(&Cp[(size_t)row * N + col], v);
      }
    }
  }
}

// ---------------- MFMA GEMM: DEPTH-deep multi-buffer pipeline, counted vmcnt ----------------
template <int FM, int FN, int WAVES_M, int WAVES_N, int DEPTH, int AMODE, int BIASMODE, bool RELU,
          typename TC>
__launch_bounds__(WAVES_M * WAVES_N * 64, 2)
__global__ void pgemm_k(const bf16* __restrict__ Ap, const bf16* __restrict__ Bt,
                        const float* __restrict__ biasp, TC* __restrict__ Cp,
                        int M, int N, int K) {
  constexpr int NTHR = WAVES_M * WAVES_N * 64;
  constexpr int AR = WAVES_M * FM * 16;
  constexpr int BR = WAVES_N * FN * 16;
  constexpr int RPG = NTHR / 4;
  constexpr int AG = AR / RPG;
  constexpr int BG = BR / RPG;
  constexpr int G = AG + BG;
  constexpr int GRP = NTHR * 16;
  constexpr int ABYTES = AR * 64;
  constexpr int SBUF = (AR + BR) * 64;
  constexpr int NB = DEPTH + 1;
  __shared__ char smem[NB * SBUF];

  const int tid = threadIdx.x;
  const int wid = tid >> 6, lane = tid & 63;
  const int wm = wid / WAVES_N, wn = wid % WAVES_N;
  const int l15 = lane & 15;

  const int nwg = gridDim.x * gridDim.y;
  int fid = blockIdx.y * gridDim.x + blockIdx.x;
  int swz = (fid & 7) * (nwg >> 3) + (fid >> 3);
  const int m0 = (swz / gridDim.x) * AR;
  const int n0 = (swz % gridDim.x) * BR;

  f32x4 acc[FM][FN];
#pragma unroll
  for (int i = 0; i < FM; i++)
#pragma unroll
    for (int j = 0; j < FN; j++) acc[i][j] = (f32x4){0.f, 0.f, 0.f, 0.f};

  const bf16* pa[AG];
  const bf16* pb[BG];
  {
    int row = tid >> 2;
    int c = (tid & 3) ^ ((tid >> 3) & 3);
#pragma unroll
    for (int q = 0; q < AG; ++q) {
      int r = m0 + q * RPG + row;
      if (AMODE == 0)
        pa[q] = Ap + (size_t)r * K + c * 8;
      else
        pa[q] = Ap + (((size_t)(r & (B_ - 1))) << 12) + ((size_t)(r >> 12) << 9) + c * 8;
    }
#pragma unroll
    for (int q = 0; q < BG; ++q) {
      int r = n0 + q * RPG + row;
      pb[q] = Bt + (size_t)r * K + c * 8;
    }
  }

  const int cA = (lane >> 4) ^ ((l15 >> 1) & 3);
  const int offA0 = (wm * FM * 16 + l15) * 64 + cA * 16;
  const int offB0 = ABYTES + (wn * FN * 16 + l15) * 64 + cA * 16;

  auto stage = [&](int buf) {
    char* base = smem + buf * SBUF;
#pragma unroll
    for (int q = 0; q < AG; ++q) {
      gload_lds16(pa[q], base + q * GRP + wid * 1024);
      pa[q] += 32;
    }
#pragma unroll
    for (int q = 0; q < BG; ++q) {
      gload_lds16(pb[q], base + ABYTES + q * GRP + wid * 1024);
      pb[q] += 32;
    }
  };

  auto comp = [&](int buf) {
    const char* sb = smem + buf * SBUF;
    short8 bfr[FN];
#pragma unroll
    for (int j = 0; j < FN; ++j) bfr[j] = *(const short8*)(sb + offB0 + j * 1024);
    constexpr int FH = (FM > 4) ? FM / 2 : FM;
#pragma unroll
    for (int h = 0; h < FM / FH; ++h) {
      short8 afr[FH];
#pragma unroll
      for (int i = 0; i < FH; ++i) afr[i] = *(const short8*)(sb + offA0 + (h * FH + i) * 1024);
      __builtin_amdgcn_s_setprio(1);
#pragma unroll
      for (int i = 0; i < FH; ++i)
#pragma unroll
        for (int j = 0; j < FN; ++j)
          acc[h * FH + i][j] =
              __builtin_amdgcn_mfma_f32_16x16x32_bf16(afr[i], bfr[j], acc[h * FH + i][j], 0, 0, 0);
      __builtin_amdgcn_s_setprio(0);
    }
  };

  const int nt = K >> 5;
#pragma unroll
  for (int q = 0; q < DEPTH; ++q) stage(q);
  int cbuf = 0, sbi = DEPTH;
  for (int T = 0; T < nt - DEPTH; ++T) {
    stage(sbi);
    if (++sbi == NB) sbi = 0;
    waitvm<DEPTH * G>();
    __builtin_amdgcn_s_barrier();
    asm volatile("" ::: "memory");
    comp(cbuf);
    if (++cbuf == NB) cbuf = 0;
    asm volatile("" ::: "memory");
    __builtin_amdgcn_s_barrier();
  }
#define DRAIN(d)                       \
  {                                    \
    waitvm<(d) * G>();                 \
    __builtin_amdgcn_s_barrier();      \
    asm volatile("" ::: "memory");     \
    comp(cbuf);                        \
    if (++cbuf == NB) cbuf = 0;        \
    asm volatile("" ::: "memory");     \
  }
  if constexpr (DEPTH == 4) { DRAIN(3) DRAIN(2) }
  DRAIN(1)
  DRAIN(0)
#undef DRAIN

#pragma unroll
  for (int i = 0; i < FM; ++i) {
    int rb = m0 + wm * FM * 16 + i * 16 + (lane >> 4) * 4;
#pragma unroll
    for (int j = 0; j < FN; ++j) {
      int col = n0 + wn * FN * 16 + j * 16 + l15;
#pragma unroll
      for (int r = 0; r < 4; r++) {
        int row = rb + r;
        float bias = (BIASMODE == 0) ? biasp[col] : biasp[((row >> 12) << 10) + col];
        float v = acc[i][j][r] + bias;
        if (RELU) v = fmaxf(v, 0.f);
        storeC(&Cp[(size_t)row * N + col], v);
      }
    }
  }
}

__global__ void v3_k(const bf16* __restrict__ hv2, const float* __restrict__ Wv3,
                     const float* __restrict__ bv3, float* __restrict__ out) {
  int wid = threadIdx.x >> 6, lane = threadIdx.x & 63;
  int row = blockIdx.x * 4 + wid;
  float s = 0.f;
#pragma unroll
  for (int k = lane; k < 1024; k += 64) s += __bfloat162float(hv2[(size_t)row * 1024 + k]) * Wv3[k];
  s = wsum(s);
  if (lane == 0) out[row] = s + bv3[0];
}

extern "C" void kernel_launch(void* const* d_in, const int* in_sizes, int n_in,
                              void* d_out, int out_size, void* d_ws, size_t ws_size,
                              hipStream_t stream) {
  const float* obs = (const float*)d_in[0];
  const int* node_types = (const int*)d_in[1];
  const int* node_agents = (const int*)d_in[2];
  const int* edges = (const int*)d_in[3];
  const float* type_embed = (const float*)d_in[4];
  const float* gagent_embed = (const float*)d_in[5];
  const float* W_l0 = (const float*)d_in[6];
  const float* b_l0 = (const float*)d_in[7];
  const float* g_l0 = (const float*)d_in[8];
  const float* be_l0 = (const float*)d_in[9];
  const float* W_l1 = (const float*)d_in[10];
  const float* b_l1 = (const float*)d_in[11];
  const float* g_l1 = (const float*)d_in[12];
  const float* be_l1 = (const float*)d_in[13];
  const float* W_gp = (const float*)d_in[14];
  const float* b_gp = (const float*)d_in[15];
  const float* agent_embed = (const float*)d_in[16];
  const float* Wp1 = (const float*)d_in[17];
  const float* bp1 = (const float*)d_in[18];
  const float* Wp2 = (const float*)d_in[19];
  const float* bp2 = (const float*)d_in[20];
  const float* Wp3 = (const float*)d_in[21];
  const float* bp3 = (const float*)d_in[22];
  const float* Wv1 = (const float*)d_in[23];
  const float* bv1 = (const float*)d_in[24];
  const float* Wv2 = (const float*)d_in[25];
  const float* bv2 = (const float*)d_in[26];
  const float* Wv3 = (const float*)d_in[27];
  const float* bv3 = (const float*)d_in[28];

  char* wsp = (char*)d_ws;
  auto alloc = [&](size_t bytes) {
    char* p = wsp;
    wsp += (bytes + 255) & ~(size_t)255;
    return p;
  };
  float* h0 = (float*)alloc((size_t)N_ * 64 * 4);
  float* agg = (float*)alloc((size_t)N_ * 64 * 4);
  float* deg = (float*)alloc((size_t)N_ * 4);
  float* h1 = (float*)alloc((size_t)N_ * 64 * 4);
  float* meanv = (float*)alloc(64 * 4);
  float* biasA = (float*)alloc(8 * 1024 * 4);
  float* biasV = (float*)alloc(1024 * 4);
  bf16* joint = (bf16*)alloc((size_t)4096 * 4096 * 2);
  bf16* Wp1t = (bf16*)alloc((size_t)1024 * 512 * 2);
  bf16* Wp2t = (bf16*)alloc((size_t)1024 * 1024 * 2);
  bf16* Wp3t = (bf16*)alloc((size_t)64 * 1024 * 2);
  bf16* Wv1t = (bf16*)alloc((size_t)1024 * 4096 * 2);
  bf16* Wv2t = (bf16*)alloc((size_t)1024 * 1024 * 2);
  bf16* C1 = (bf16*)alloc((size_t)32768 * 1024 * 2);
  bf16* C2 = (bf16*)alloc((size_t)32768 * 1024 * 2);
  bf16* hv = (bf16*)alloc((size_t)4096 * 1024 * 2);
  bf16* hv2 = (bf16*)alloc((size_t)4096 * 1024 * 2);

  float* logits = (float*)d_out;
  float* value = (float*)d_out + (size_t)A_ * B_ * ACT_;

  gnn_l0_k<<<N_, 64, 0, stream>>>(node_types, node_agents, type_embed, gagent_embed, W_l0, b_l0,
                                  g_l0, be_l0, h0, agg, deg);
  edge_k<<<(E_ * 64) / 256, 256, 0, stream>>>(edges, h0, agg, deg);
  gnn_l1_k<<<N_, 64, 0, stream>>>(h0, agg, deg, W_l1, b_l1, g_l1, be_l1, h1);
  colmean_k<<<64, 256, 0, stream>>>(h1, meanv);
  fused_bias_k<<<36, 256, 0, stream>>>(meanv, W_gp, b_gp, agent_embed, Wp1, bp1, Wv1, bv1, biasA,
                                       biasV);

  conv_joint_k<<<(A_ * B_ * OBS_) / 8 / 256, 256, 0, stream>>>(obs, joint);
  wtrans_k<<<dim3(1024 / 32, 512 / 32), 256, 0, stream>>>(Wp1, Wp1t, 512, 1024);
  wtrans_k<<<dim3(1024 / 32, 1024 / 32), 256, 0, stream>>>(Wp2, Wp2t, 1024, 1024);
  wtrans_k<<<dim3(64 / 32, 1024 / 32), 256, 0, stream>>>(Wp3, Wp3t, 1024, 64);
  wtrans_k<<<dim3(1024 / 32, 4096 / 32), 256, 0, stream>>>(Wv1, Wv1t, 4096, 1024);
  wtrans_k<<<dim3(1024 / 32, 1024 / 32), 256, 0, stream>>>(Wv2, Wv2t, 1024, 1024);

  // P1: C1 = relu(obs2d @ Wp1[0:512] + biasA[agent])  M=32768 N=1024 K=512, g10 256x256 BK64
  g10_k<1, 1, true, bf16>
      <<<dim3(4, 128), 512, 0, stream>>>(joint, Wp1t, biasA, C1, 32768, 1024, 512);
  // P2: C2 = relu(C1 @ Wp2 + bp2)                     M=32768 N=1024 K=1024, g10 256x256 BK64
  g10_k<0, 0, true, bf16>
      <<<dim3(4, 128), 512, 0, stream>>>(C1, Wp2t, bp2, C2, 32768, 1024, 1024);
  // P3: logits = C2 @ Wp3 + bp3                       M=32768 N=64 K=1024, 128x64, D4
  pgemm_k<4, 2, 2, 2, 4, 0, 0, false, float>
      <<<dim3(1, 256), 256, 0, stream>>>(C2, Wp3t, bp3, logits, 32768, 64, 1024);
  // V1: hv = relu(joint @ Wv1 + biasV)                M=4096 N=1024 K=4096, 128x128, 8 waves, D4
  pgemm_k<4, 2, 2, 4, 4, 0, 0, true, bf16>
      <<<dim3(8, 32), 512, 0, stream>>>(joint, Wv1t, biasV, hv, 4096, 1024, 4096);
  // V2: hv2 = relu(hv @ Wv2 + bv2)                    M=4096 N=1024 K=1024, 128x128, 8 waves, D4
  pgemm_k<4, 2, 2, 4, 4, 0, 0, true, bf16>
      <<<dim3(8, 32), 512, 0, stream>>>(hv, Wv2t, bv2, hv2, 4096, 1024, 1024);
  // V3: value = hv2 @ Wv3 + bv3
  v3_k<<<1024, 256, 0, stream>>>(hv2, Wv3, bv3, value);
}

// Round 9
// 299.229 us; speedup vs baseline: 10.3314x; 1.0138x over previous
//
#include <hip/hip_runtime.h>
#include <hip/hip_bf16.h>

#define A_ 8
#define B_ 4096
#define OBS_ 512
#define ACT_ 64
#define H_ 1024
#define G_ 64
#define N_ 10000
#define E_ 40000

using bf16 = __hip_bfloat16;
typedef __attribute__((ext_vector_type(8))) short short8;
typedef __attribute__((ext_vector_type(4))) float f32x4;

__device__ __forceinline__ float wsum(float v) {
#pragma unroll
  for (int off = 32; off >= 1; off >>= 1) v += __shfl_xor(v, off, 64);
  return v;
}

__device__ __forceinline__ void storeC(float* p, float v) { *p = v; }
__device__ __forceinline__ void storeC(bf16* p, float v) { *p = __float2bfloat16(v); }

__device__ __forceinline__ unsigned short f2bu(float x) {
  bf16 h = __float2bfloat16(x);
  unsigned short u;
  __builtin_memcpy(&u, &h, 2);
  return u;
}

__device__ __forceinline__ void gload_lds16(const bf16* g, const void* lds_uniform) {
  __builtin_amdgcn_global_load_lds(
      (const __attribute__((address_space(1))) unsigned int*)g,
      (__attribute__((address_space(3))) unsigned int*)lds_uniform, 16, 0, 0);
}

template <int N>
__device__ __forceinline__ void waitvm() {
#define WV_CASE(n) if constexpr (N == n) asm volatile("s_waitcnt vmcnt(" #n ")" ::: "memory");
  WV_CASE(0) WV_CASE(1) WV_CASE(2) WV_CASE(3) WV_CASE(4) WV_CASE(5) WV_CASE(6) WV_CASE(7)
  WV_CASE(8) WV_CASE(9) WV_CASE(10) WV_CASE(12) WV_CASE(16)
  static_assert(N <= 16, "vmcnt too large");
#undef WV_CASE
}

// ---------------- GNN ----------------
__global__ void gnn_l0_k(const int* __restrict__ node_types, const int* __restrict__ node_agents,
                         const float* __restrict__ type_embed, const float* __restrict__ gagent_embed,
                         const float* __restrict__ W, const float* __restrict__ b,
                         const float* __restrict__ g, const float* __restrict__ be,
                         float* __restrict__ h0, float* __restrict__ agg, float* __restrict__ deg) {
  int n = blockIdx.x, t = threadIdx.x;  // 64 threads = 1 wave
  __shared__ float x[64];
  int ty = node_types[n], ag = node_agents[n];
  x[t] = (t < 32) ? type_embed[ty * 32 + t] : gagent_embed[ag * 32 + (t - 32)];
  agg[(size_t)n * 64 + t] = 0.f;  // fused memset
  if (t == 0) deg[n] = 0.f;
  __syncthreads();
  float acc = b[t];
#pragma unroll 8
  for (int i = 0; i < 64; i++) acc += x[i] * W[i * 64 + t];
  acc = fmaxf(acc, 0.f);
  float m = wsum(acc) * (1.f / 64.f);
  float d = acc - m;
  float v = wsum(d * d) * (1.f / 64.f);
  h0[(size_t)n * 64 + t] = d * rsqrtf(v + 1e-5f) * g[t] + be[t];
}

__global__ void edge_k(const int* __restrict__ edges, const float* __restrict__ h0,
                       float* __restrict__ agg, float* __restrict__ deg) {
  int idx = blockIdx.x * 256 + threadIdx.x;
  if (idx >= E_ * 64) return;
  int e = idx >> 6, c = idx & 63;
  int s = edges[e * 2 + 0], d = edges[e * 2 + 1];
  atomicAdd(&agg[(size_t)d * 64 + c], h0[(size_t)s * 64 + c]);
  atomicAdd(&agg[(size_t)s * 64 + c], h0[(size_t)d * 64 + c]);
  if (c == 0) { atomicAdd(&deg[d], 1.f); atomicAdd(&deg[s], 1.f); }
}

__global__ void gnn_l1_k(const float* __restrict__ h0, const float* __restrict__ agg,
                         const float* __restrict__ deg, const float* __restrict__ W,
                         const float* __restrict__ b, const float* __restrict__ g,
                         const float* __restrict__ be, float* __restrict__ h1) {
  int n = blockIdx.x, t = threadIdx.x;  // 64 threads
  __shared__ float x[128];
  x[t] = h0[(size_t)n * 64 + t];
  x[64 + t] = agg[(size_t)n * 64 + t] / fmaxf(deg[n], 1.0f);
  __syncthreads();
  float acc = b[t];
#pragma unroll 8
  for (int i = 0; i < 128; i++) acc += x[i] * W[i * 64 + t];
  acc = fmaxf(acc, 0.f);
  float m = wsum(acc) * (1.f / 64.f);
  float d = acc - m;
  float v = wsum(d * d) * (1.f / 64.f);
  h1[(size_t)n * 64 + t] = d * rsqrtf(v + 1e-5f) * g[t] + be[t];
}

__global__ void colmean_k(const float* __restrict__ h1, float* __restrict__ meanv) {
  int c = blockIdx.x, t = threadIdx.x;
  float s = 0.f;
  for (int n = t; n < N_; n += 256) s += h1[(size_t)n * 64 + c];
  __shared__ float red[256];
  red[t] = s;
  __syncthreads();
  for (int off = 128; off >= 1; off >>= 1) {
    if (t < off) red[t] += red[t + off];
    __syncthreads();
  }
  if (t == 0) meanv[c] = red[0] / (float)N_;
}

__global__ void fused_bias_k(const float* __restrict__ meanv, const float* __restrict__ Wgp,
                             const float* __restrict__ bgp, const float* __restrict__ agent_embed,
                             const float* __restrict__ Wp1, const float* __restrict__ bp1,
                             const float* __restrict__ Wv1, const float* __restrict__ bv1,
                             float* __restrict__ biasA, float* __restrict__ biasV) {
  __shared__ float ge[64];
  int t = threadIdx.x;
  if (t < 64) {
    float s = bgp[t];
    for (int g2 = 0; g2 < 64; g2++) s += meanv[g2] * Wgp[g2 * 64 + t];
    ge[t] = s;
  }
  __syncthreads();
  int blk = blockIdx.x;
  if (blk < 32) {
    int idx = blk * 256 + t;
    int a = idx >> 10, o = idx & 1023;
    float s = bp1[o];
    for (int g2 = 0; g2 < 64; g2++) s += ge[g2] * Wp1[(size_t)(512 + g2) * 1024 + o];
    for (int e = 0; e < 16; e++) s += agent_embed[a * 16 + e] * Wp1[(size_t)(576 + e) * 1024 + o];
    biasA[idx] = s;
  } else {
    int o = (blk - 32) * 256 + t;
    float s = bv1[o];
    for (int g2 = 0; g2 < 64; g2++) s += ge[g2] * Wv1[(size_t)(4096 + g2) * 1024 + o];
    biasV[o] = s;
  }
}

// ---------------- conversions ----------------
__global__ void conv_joint_k(const float* __restrict__ obs, bf16* __restrict__ joint) {
  size_t i = ((size_t)blockIdx.x * 256 + threadIdx.x) * 8;
  int a = (int)(i >> 21);
  int rem = (int)(i & ((1u << 21) - 1));
  int b = rem >> 9, k = rem & 511;
  const float* p = obs + i;
  short8 o;
#pragma unroll
  for (int t = 0; t < 8; t++) o[t] = (short)f2bu(p[t]);
  *(short8*)(joint + (size_t)b * 4096 + a * 512 + k) = o;
}

__global__ void wtrans_k(const float* __restrict__ W, bf16* __restrict__ Wt, int K, int N) {
  __shared__ float t[32][33];
  int n0 = blockIdx.x * 32, k0 = blockIdx.y * 32;
  int tx = threadIdx.x & 31, ty = threadIdx.x >> 5;  // 32x8
#pragma unroll
  for (int r = ty; r < 32; r += 8) t[r][tx] = W[(size_t)(k0 + r) * N + n0 + tx];
  __syncthreads();
#pragma unroll
  for (int r = ty; r < 32; r += 8) Wt[(size_t)(n0 + r) * K + k0 + tx] = __float2bfloat16(t[tx][r]);
}

// ======== g11_k: 256x256, BK=64, double buffer, 4 phases/K-tile, COUNTED vmcnt (T4) =========
// Load groups (64 rows x 128 B each): g0/g1 = A rows 0-127, g2/g3 = A rows 128-255,
// g4-g7 = B rows. Phase needs: p0 {g0,g2,g4-g7}; p1 {g1,g3}; p2/p3: already covered.
// Issue order for tile t+1: p0:{g0,g2} p1:{g4,g5} p2:{g6,g7} p3:{g1,g3}.
// End-of-iter wait: vmcnt(2) (oldest 6 done = all p0 needs; tail {g1,g3} may fly).
// p0-end wait: vmcnt(2) (outstanding = tail{g1,g3} + just-issued {g0,g2}@t+2; in-order retire).
// Last iteration: no staging -> both waits degrade to vmcnt(0).
#define BARR()                        \
  asm volatile("" ::: "memory");      \
  __builtin_amdgcn_s_barrier();       \
  asm volatile("" ::: "memory")

#define RD8(off) (*(const short8*)(sb + (off)))

#define MMQ(FI0)                                                                     \
  __builtin_amdgcn_s_setprio(1);                                                     \
  acc[FI0 + 0][0] = __builtin_amdgcn_mfma_f32_16x16x32_bf16(a0, b0, acc[FI0 + 0][0], 0, 0, 0); \
  acc[FI0 + 0][1] = __builtin_amdgcn_mfma_f32_16x16x32_bf16(a0, b1, acc[FI0 + 0][1], 0, 0, 0); \
  acc[FI0 + 0][2] = __builtin_amdgcn_mfma_f32_16x16x32_bf16(a0, b2, acc[FI0 + 0][2], 0, 0, 0); \
  acc[FI0 + 0][3] = __builtin_amdgcn_mfma_f32_16x16x32_bf16(a0, b3, acc[FI0 + 0][3], 0, 0, 0); \
  acc[FI0 + 1][0] = __builtin_amdgcn_mfma_f32_16x16x32_bf16(a1, b0, acc[FI0 + 1][0], 0, 0, 0); \
  acc[FI0 + 1][1] = __builtin_amdgcn_mfma_f32_16x16x32_bf16(a1, b1, acc[FI0 + 1][1], 0, 0, 0); \
  acc[FI0 + 1][2] = __builtin_amdgcn_mfma_f32_16x16x32_bf16(a1, b2, acc[FI0 + 1][2], 0, 0, 0); \
  acc[FI0 + 1][3] = __builtin_amdgcn_mfma_f32_16x16x32_bf16(a1, b3, acc[FI0 + 1][3], 0, 0, 0); \
  acc[FI0 + 2][0] = __builtin_amdgcn_mfma_f32_16x16x32_bf16(a2, b0, acc[FI0 + 2][0], 0, 0, 0); \
  acc[FI0 + 2][1] = __builtin_amdgcn_mfma_f32_16x16x32_bf16(a2, b1, acc[FI0 + 2][1], 0, 0, 0); \
  acc[FI0 + 2][2] = __builtin_amdgcn_mfma_f32_16x16x32_bf16(a2, b2, acc[FI0 + 2][2], 0, 0, 0); \
  acc[FI0 + 2][3] = __builtin_amdgcn_mfma_f32_16x16x32_bf16(a2, b3, acc[FI0 + 2][3], 0, 0, 0); \
  acc[FI0 + 3][0] = __builtin_amdgcn_mfma_f32_16x16x32_bf16(a3, b0, acc[FI0 + 3][0], 0, 0, 0); \
  acc[FI0 + 3][1] = __builtin_amdgcn_mfma_f32_16x16x32_bf16(a3, b1, acc[FI0 + 3][1], 0, 0, 0); \
  acc[FI0 + 3][2] = __builtin_amdgcn_mfma_f32_16x16x32_bf16(a3, b2, acc[FI0 + 3][2], 0, 0, 0); \
  acc[FI0 + 3][3] = __builtin_amdgcn_mfma_f32_16x16x32_bf16(a3, b3, acc[FI0 + 3][3], 0, 0, 0); \
  __builtin_amdgcn_s_setprio(0)

template <int AMODE, int BIASMODE, bool RELU, typename TC>
__launch_bounds__(512, 1)
__global__ void g11_k(const bf16* __restrict__ Ap, const bf16* __restrict__ Bt,
                      const float* __restrict__ biasp, TC* __restrict__ Cp,
                      int M, int N, int K) {
  constexpr int SBUF = 65536;      // (256 A-rows + 256 B-rows) x 128 B
  __shared__ char smem[2 * SBUF];  // 128 KB double buffer

  const int tid = threadIdx.x;
  const int wid = tid >> 6, lane = tid & 63;
  const int wm = wid >> 2, wn = wid & 3;
  const int l15 = lane & 15;

  // T1: bijective XCD swizzle (nwg % 8 == 0)
  const int nwg = gridDim.x * gridDim.y;
  int fid = blockIdx.y * gridDim.x + blockIdx.x;
  int swz = (fid & 7) * (nwg >> 3) + (fid >> 3);
  const int m0 = (swz / gridDim.x) * 256;
  const int n0 = (swz % gridDim.x) * 256;

  f32x4 acc[8][4];
#pragma unroll
  for (int i = 0; i < 8; i++)
#pragma unroll
    for (int j = 0; j < 4; j++) acc[i][j] = (f32x4){0.f, 0.f, 0.f, 0.f};

  // staging: 8 gload groups, each 64 rows x 128 B; thread -> row = g*64 + tid>>3, slot = tid&7,
  // pre-swizzled source chunk c = slot ^ (row&7)
  const bf16* pg[8];
  {
    int srow = tid >> 3;
    int c = (tid & 7) ^ (srow & 7);
#pragma unroll
    for (int g = 0; g < 4; ++g) {
      int r = m0 + g * 64 + srow;
      if (AMODE == 0)
        pg[g] = Ap + (size_t)r * K + c * 8;
      else
        pg[g] = Ap + (((size_t)(r & (B_ - 1))) << 12) + ((size_t)(r >> 12) << 9) + c * 8;
    }
#pragma unroll
    for (int g = 4; g < 8; ++g) {
      int r = n0 + (g - 4) * 64 + srow;
      pg[g] = Bt + (size_t)r * K + c * 8;
    }
  }

  // fragment byte offsets; slot(kk) = (kk*4 + (lane>>4)) ^ (l15&7); kk toggles byte bit 6
  const int slot0 = (lane >> 4) ^ (l15 & 7);
  const int aof0 = (wm * 128 + l15) * 128 + slot0 * 16;
  const int bof0 = 32768 + (wn * 64 + l15) * 128 + slot0 * 16;
  const int aof1 = aof0 ^ 64;
  const int bof1 = bof0 ^ 64;

#define STG(g, buf)                                                    \
  {                                                                    \
    gload_lds16(pg[g], smem + (buf) * SBUF + (g) * 8192 + wid * 1024); \
    pg[g] += 64;                                                       \
  }

  // prologue: stage tile 0 into buf 0 (issue order irrelevant here), full drain
  STG(0, 0) STG(2, 0) STG(4, 0) STG(5, 0) STG(6, 0) STG(7, 0) STG(1, 0) STG(3, 0)
  waitvm<0>();
  BARR();

  const int nt = K >> 6;  // K-tiles of 64; nt >= 2
  for (int t = 0; t < nt; ++t) {
    const int cb = t & 1, ob = cb ^ 1;
    const bool last = (t == nt - 1);
    const char* sb = smem + cb * SBUF;
    short8 a0, a1, a2, a3, b0, b1, b2, b3;
    // ---- phase 0: kk=0, A frags 0-3 (groups g0/g2) + B kk=0 (g4-g7)
    a0 = RD8(aof0 + 0 * 2048); a1 = RD8(aof0 + 1 * 2048);
    a2 = RD8(aof0 + 2 * 2048); a3 = RD8(aof0 + 3 * 2048);
    b0 = RD8(bof0 + 0 * 2048); b1 = RD8(bof0 + 1 * 2048);
    b2 = RD8(bof0 + 2 * 2048); b3 = RD8(bof0 + 3 * 2048);
    if (!last) { STG(0, ob) STG(2, ob) }
    BARR();
    MMQ(0);
    if (last) waitvm<0>(); else waitvm<2>();  // tail {g1,g3} of tile t retired before p1 reads
    BARR();
    // ---- phase 1: kk=0, A frags 4-7 (groups g1/g3), reuse b0..b3
    a0 = RD8(aof0 + 4 * 2048); a1 = RD8(aof0 + 5 * 2048);
    a2 = RD8(aof0 + 6 * 2048); a3 = RD8(aof0 + 7 * 2048);
    if (!last) { STG(4, ob) STG(5, ob) }
    BARR();
    MMQ(4);
    BARR();
    // ---- phase 2: kk=1, A frags 0-3 + B kk=1 (same groups, other 64B half)
    a0 = RD8(aof1 + 0 * 2048); a1 = RD8(aof1 + 1 * 2048);
    a2 = RD8(aof1 + 2 * 2048); a3 = RD8(aof1 + 3 * 2048);
    b0 = RD8(bof1 + 0 * 2048); b1 = RD8(bof1 + 1 * 2048);
    b2 = RD8(bof1 + 2 * 2048); b3 = RD8(bof1 + 3 * 2048);
    if (!last) { STG(6, ob) STG(7, ob) }
    BARR();
    MMQ(0);
    BARR();
    // ---- phase 3: kk=1, A frags 4-7
    a0 = RD8(aof1 + 4 * 2048); a1 = RD8(aof1 + 5 * 2048);
    a2 = RD8(aof1 + 6 * 2048); a3 = RD8(aof1 + 7 * 2048);
    if (!last) { STG(1, ob) STG(3, ob) }
    BARR();
    MMQ(4);
    // counted end-of-iter wait: oldest 6 of tile t+1 (g0,g2,g4-g7) done; tail {g1,g3} may fly
    if (!last) waitvm<2>(); else waitvm<0>();
    BARR();
  }
#undef STG

  // epilogue: C/D layout col=lane&15, row=(lane>>4)*4+reg
#pragma unroll
  for (int i = 0; i < 8; ++i) {
    int rb = m0 + wm * 128 + i * 16 + (lane >> 4) * 4;
#pragma unroll
    for (int j = 0; j < 4; ++j) {
      int col = n0 + wn * 64 + j * 16 + l15;
#pragma unroll
      for (int r = 0; r < 4; r++) {
        int row = rb + r;
        float bias = (BIASMODE == 0) ? biasp[col] : biasp[((row >> 12) << 10) + col];
        float v = acc[i][j][r] + bias;
        if (RELU) v = fmaxf(v, 0.f);
        storeC(&Cp[(size_t)row * N + col], v);
      }
    }
  }
}

// ---------------- MFMA GEMM: DEPTH-deep multi-buffer pipeline, counted vmcnt ----------------
template <int FM, int FN, int WAVES_M, int WAVES_N, int DEPTH, int AMODE, int BIASMODE, bool RELU,
          typename TC>
__launch_bounds__(WAVES_M * WAVES_N * 64, 2)
__global__ void pgemm_k(const bf16* __restrict__ Ap, const bf16* __restrict__ Bt,
                        const float* __restrict__ biasp, TC* __restrict__ Cp,
                        int M, int N, int K) {
  constexpr int NTHR = WAVES_M * WAVES_N * 64;
  constexpr int AR = WAVES_M * FM * 16;
  constexpr int BR = WAVES_N * FN * 16;
  constexpr int RPG = NTHR / 4;
  constexpr int AG = AR / RPG;
  constexpr int BG = BR / RPG;
  constexpr int G = AG + BG;
  constexpr int GRP = NTHR * 16;
  constexpr int ABYTES = AR * 64;
  constexpr int SBUF = (AR + BR) * 64;
  constexpr int NB = DEPTH + 1;
  __shared__ char smem[NB * SBUF];

  const int tid = threadIdx.x;
  const int wid = tid >> 6, lane = tid & 63;
  const int wm = wid / WAVES_N, wn = wid % WAVES_N;
  const int l15 = lane & 15;

  const int nwg = gridDim.x * gridDim.y;
  int fid = blockIdx.y * gridDim.x + blockIdx.x;
  int swz = (fid & 7) * (nwg >> 3) + (fid >> 3);
  const int m0 = (swz / gridDim.x) * AR;
  const int n0 = (swz % gridDim.x) * BR;

  f32x4 acc[FM][FN];
#pragma unroll
  for (int i = 0; i < FM; i++)
#pragma unroll
    for (int j = 0; j < FN; j++) acc[i][j] = (f32x4){0.f, 0.f, 0.f, 0.f};

  const bf16* pa[AG];
  const bf16* pb[BG];
  {
    int row = tid >> 2;
    int c = (tid & 3) ^ ((tid >> 3) & 3);
#pragma unroll
    for (int q = 0; q < AG; ++q) {
      int r = m0 + q * RPG + row;
      if (AMODE == 0)
        pa[q] = Ap + (size_t)r * K + c * 8;
      else
        pa[q] = Ap + (((size_t)(r & (B_ - 1))) << 12) + ((size_t)(r >> 12) << 9) + c * 8;
    }
#pragma unroll
    for (int q = 0; q < BG; ++q) {
      int r = n0 + q * RPG + row;
      pb[q] = Bt + (size_t)r * K + c * 8;
    }
  }

  const int cA = (lane >> 4) ^ ((l15 >> 1) & 3);
  const int offA0 = (wm * FM * 16 + l15) * 64 + cA * 16;
  const int offB0 = ABYTES + (wn * FN * 16 + l15) * 64 + cA * 16;

  auto stage = [&](int buf) {
    char* base = smem + buf * SBUF;
#pragma unroll
    for (int q = 0; q < AG; ++q) {
      gload_lds16(pa[q], base + q * GRP + wid * 1024);
      pa[q] += 32;
    }
#pragma unroll
    for (int q = 0; q < BG; ++q) {
      gload_lds16(pb[q], base + ABYTES + q * GRP + wid * 1024);
      pb[q] += 32;
    }
  };

  auto comp = [&](int buf) {
    const char* sb = smem + buf * SBUF;
    short8 bfr[FN];
#pragma unroll
    for (int j = 0; j < FN; ++j) bfr[j] = *(const short8*)(sb + offB0 + j * 1024);
    constexpr int FH = (FM > 4) ? FM / 2 : FM;
#pragma unroll
    for (int h = 0; h < FM / FH; ++h) {
      short8 afr[FH];
#pragma unroll
      for (int i = 0; i < FH; ++i) afr[i] = *(const short8*)(sb + offA0 + (h * FH + i) * 1024);
      __builtin_amdgcn_s_setprio(1);
#pragma unroll
      for (int i = 0; i < FH; ++i)
#pragma unroll
        for (int j = 0; j < FN; ++j)
          acc[h * FH + i][j] =
              __builtin_amdgcn_mfma_f32_16x16x32_bf16(afr[i], bfr[j], acc[h * FH + i][j], 0, 0, 0);
      __builtin_amdgcn_s_setprio(0);
    }
  };

  const int nt = K >> 5;
#pragma unroll
  for (int q = 0; q < DEPTH; ++q) stage(q);
  int cbuf = 0, sbi = DEPTH;
  for (int T = 0; T < nt - DEPTH; ++T) {
    stage(sbi);
    if (++sbi == NB) sbi = 0;
    waitvm<DEPTH * G>();
    __builtin_amdgcn_s_barrier();
    asm volatile("" ::: "memory");
    comp(cbuf);
    if (++cbuf == NB) cbuf = 0;
    asm volatile("" ::: "memory");
    __builtin_amdgcn_s_barrier();
  }
#define DRAIN(d)                       \
  {                                    \
    waitvm<(d) * G>();                 \
    __builtin_amdgcn_s_barrier();      \
    asm volatile("" ::: "memory");     \
    comp(cbuf);                        \
    if (++cbuf == NB) cbuf = 0;        \
    asm volatile("" ::: "memory");     \
  }
  if constexpr (DEPTH == 4) { DRAIN(3) DRAIN(2) }
  DRAIN(1)
  DRAIN(0)
#undef DRAIN

#pragma unroll
  for (int i = 0; i < FM; ++i) {
    int rb = m0 + wm * FM * 16 + i * 16 + (lane >> 4) * 4;
#pragma unroll
    for (int j = 0; j < FN; ++j) {
      int col = n0 + wn * FN * 16 + j * 16 + l15;
#pragma unroll
      for (int r = 0; r < 4; r++) {
        int row = rb + r;
        float bias = (BIASMODE == 0) ? biasp[col] : biasp[((row >> 12) << 10) + col];
        float v = acc[i][j][r] + bias;
        if (RELU) v = fmaxf(v, 0.f);
        storeC(&Cp[(size_t)row * N + col], v);
      }
    }
  }
}

__global__ void v3_k(const bf16* __restrict__ hv2, const float* __restrict__ Wv3,
                     const float* __restrict__ bv3, float* __restrict__ out) {
  int wid = threadIdx.x >> 6, lane = threadIdx.x & 63;
  int row = blockIdx.x * 4 + wid;
  float s = 0.f;
#pragma unroll
  for (int k = lane; k < 1024; k += 64) s += __bfloat162float(hv2[(size_t)row * 1024 + k]) * Wv3[k];
  s = wsum(s);
  if (lane == 0) out[row] = s + bv3[0];
}

extern "C" void kernel_launch(void* const* d_in, const int* in_sizes, int n_in,
                              void* d_out, int out_size, void* d_ws, size_t ws_size,
                              hipStream_t stream) {
  const float* obs = (const float*)d_in[0];
  const int* node_types = (const int*)d_in[1];
  const int* node_agents = (const int*)d_in[2];
  const int* edges = (const int*)d_in[3];
  const float* type_embed = (const float*)d_in[4];
  const float* gagent_embed = (const float*)d_in[5];
  const float* W_l0 = (const float*)d_in[6];
  const float* b_l0 = (const float*)d_in[7];
  const float* g_l0 = (const float*)d_in[8];
  const float* be_l0 = (const float*)d_in[9];
  const float* W_l1 = (const float*)d_in[10];
  const float* b_l1 = (const float*)d_in[11];
  const float* g_l1 = (const float*)d_in[12];
  const float* be_l1 = (const float*)d_in[13];
  const float* W_gp = (const float*)d_in[14];
  const float* b_gp = (const float*)d_in[15];
  const float* agent_embed = (const float*)d_in[16];
  const float* Wp1 = (const float*)d_in[17];
  const float* bp1 = (const float*)d_in[18];
  const float* Wp2 = (const float*)d_in[19];
  const float* bp2 = (const float*)d_in[20];
  const float* Wp3 = (const float*)d_in[21];
  const float* bp3 = (const float*)d_in[22];
  const float* Wv1 = (const float*)d_in[23];
  const float* bv1 = (const float*)d_in[24];
  const float* Wv2 = (const float*)d_in[25];
  const float* bv2 = (const float*)d_in[26];
  const float* Wv3 = (const float*)d_in[27];
  const float* bv3 = (const float*)d_in[28];

  char* wsp = (char*)d_ws;
  auto alloc = [&](size_t bytes) {
    char* p = wsp;
    wsp += (bytes + 255) & ~(size_t)255;
    return p;
  };
  float* h0 = (float*)alloc((size_t)N_ * 64 * 4);
  float* agg = (float*)alloc((size_t)N_ * 64 * 4);
  float* deg = (float*)alloc((size_t)N_ * 4);
  float* h1 = (float*)alloc((size_t)N_ * 64 * 4);
  float* meanv = (float*)alloc(64 * 4);
  float* biasA = (float*)alloc(8 * 1024 * 4);
  float* biasV = (float*)alloc(1024 * 4);
  bf16* joint = (bf16*)alloc((size_t)4096 * 4096 * 2);
  bf16* Wp1t = (bf16*)alloc((size_t)1024 * 512 * 2);
  bf16* Wp2t = (bf16*)alloc((size_t)1024 * 1024 * 2);
  bf16* Wp3t = (bf16*)alloc((size_t)64 * 1024 * 2);
  bf16* Wv1t = (bf16*)alloc((size_t)1024 * 4096 * 2);
  bf16* Wv2t = (bf16*)alloc((size_t)1024 * 1024 * 2);
  bf16* C1 = (bf16*)alloc((size_t)32768 * 1024 * 2);
  bf16* C2 = (bf16*)alloc((size_t)32768 * 1024 * 2);
  bf16* hv = (bf16*)alloc((size_t)4096 * 1024 * 2);
  bf16* hv2 = (bf16*)alloc((size_t)4096 * 1024 * 2);

  float* logits = (float*)d_out;
  float* value = (float*)d_out + (size_t)A_ * B_ * ACT_;

  gnn_l0_k<<<N_, 64, 0, stream>>>(node_types, node_agents, type_embed, gagent_embed, W_l0, b_l0,
                                  g_l0, be_l0, h0, agg, deg);
  edge_k<<<(E_ * 64) / 256, 256, 0, stream>>>(edges, h0, agg, deg);
  gnn_l1_k<<<N_, 64, 0, stream>>>(h0, agg, deg, W_l1, b_l1, g_l1, be_l1, h1);
  colmean_k<<<64, 256, 0, stream>>>(h1, meanv);
  fused_bias_k<<<36, 256, 0, stream>>>(meanv, W_gp, b_gp, agent_embed, Wp1, bp1, Wv1, bv1, biasA,
                                       biasV);

  conv_joint_k<<<(A_ * B_ * OBS_) / 8 / 256, 256, 0, stream>>>(obs, joint);
  wtrans_k<<<dim3(1024 / 32, 512 / 32), 256, 0, stream>>>(Wp1, Wp1t, 512, 1024);
  wtrans_k<<<dim3(1024 / 32, 1024 / 32), 256, 0, stream>>>(Wp2, Wp2t, 1024, 1024);
  wtrans_k<<<dim3(64 / 32, 1024 / 32), 256, 0, stream>>>(Wp3, Wp3t, 1024, 64);
  wtrans_k<<<dim3(1024 / 32, 4096 / 32), 256, 0, stream>>>(Wv1, Wv1t, 4096, 1024);
  wtrans_k<<<dim3(1024 / 32, 1024 / 32), 256, 0, stream>>>(Wv2, Wv2t, 1024, 1024);

  // P1: C1 = relu(obs2d @ Wp1[0:512] + biasA[agent])  M=32768 N=1024 K=512, g11 256x256 BK64
  g11_k<1, 1, true, bf16>
      <<<dim3(4, 128), 512, 0, stream>>>(joint, Wp1t, biasA, C1, 32768, 1024, 512);
  // P2: C2 = relu(C1 @ Wp2 + bp2)                     M=32768 N=1024 K=1024, g11 256x256 BK64
  g11_k<0, 0, true, bf16>
      <<<dim3(4, 128), 512, 0, stream>>>(C1, Wp2t, bp2, C2, 32768, 1024, 1024);
  // P3: logits = C2 @ Wp3 + bp3                       M=32768 N=64 K=1024, 128x64, D4
  pgemm_k<4, 2, 2, 2, 4, 0, 0, false, float>
      <<<dim3(1, 256), 256, 0, stream>>>(C2, Wp3t, bp3, logits, 32768, 64, 1024);
  // V1: hv = relu(joint @ Wv1 + biasV)                M=4096 N=1024 K=4096, 128x128, 8 waves, D4
  pgemm_k<4, 2, 2, 4, 4, 0, 0, true, bf16>
      <<<dim3(8, 32), 512, 0, stream>>>(joint, Wv1t, biasV, hv, 4096, 1024, 4096);
  // V2: hv2 = relu(hv @ Wv2 + bv2)                    M=4096 N=1024 K=1024, 128x128, 8 waves, D4
  pgemm_k<4, 2, 2, 4, 4, 0, 0, true, bf16>
      <<<dim3(8, 32), 512, 0, stream>>>(hv, Wv2t, bv2, hv2, 4096, 1024, 1024);
  // V3: value = hv2 @ Wv3 + bv3
  v3_k<<<1024, 256, 0, stream>>>(hv2, Wv3, bv3, value);
}

// Round 10
// 279.259 us; speedup vs baseline: 11.0702x; 1.0715x over previous
//
#include <hip/hip_runtime.h>
#include <hip/hip_bf16.h>

#define A_ 8
#define B_ 4096
#define OBS_ 512
#define ACT_ 64
#define H_ 1024
#define G_ 64
#define N_ 10000
#define E_ 40000

using bf16 = __hip_bfloat16;
typedef __attribute__((ext_vector_type(8))) short short8;
typedef __attribute__((ext_vector_type(4))) float f32x4;

__device__ __forceinline__ float wsum(float v) {
#pragma unroll
  for (int off = 32; off >= 1; off >>= 1) v += __shfl_xor(v, off, 64);
  return v;
}

__device__ __forceinline__ void storeC(float* p, float v) { *p = v; }
__device__ __forceinline__ void storeC(bf16* p, float v) { *p = __float2bfloat16(v); }

__device__ __forceinline__ unsigned short f2bu(float x) {
  bf16 h = __float2bfloat16(x);
  unsigned short u;
  __builtin_memcpy(&u, &h, 2);
  return u;
}

__device__ __forceinline__ void gload_lds16(const bf16* g, const void* lds_uniform) {
  __builtin_amdgcn_global_load_lds(
      (const __attribute__((address_space(1))) unsigned int*)g,
      (__attribute__((address_space(3))) unsigned int*)lds_uniform, 16, 0, 0);
}

template <int N>
__device__ __forceinline__ void waitvm() {
#define WV_CASE(n) if constexpr (N == n) asm volatile("s_waitcnt vmcnt(" #n ")" ::: "memory");
  WV_CASE(0) WV_CASE(1) WV_CASE(2) WV_CASE(3) WV_CASE(4) WV_CASE(5) WV_CASE(6) WV_CASE(7)
  WV_CASE(8) WV_CASE(9) WV_CASE(10) WV_CASE(12) WV_CASE(16)
  static_assert(N <= 16, "vmcnt too large");
#undef WV_CASE
}

// ======= prep_k: conv_joint (blocks 0-8191) + 5x wtrans (8192-14911) + gnn_l0 (14912-17411) ===
__global__ __launch_bounds__(256) void prep_k(
    const float* __restrict__ obs, bf16* __restrict__ joint,
    const float* __restrict__ Wp1, bf16* __restrict__ Wp1t,
    const float* __restrict__ Wp2, bf16* __restrict__ Wp2t,
    const float* __restrict__ Wp3, bf16* __restrict__ Wp3t,
    const float* __restrict__ Wv1, bf16* __restrict__ Wv1t,
    const float* __restrict__ Wv2, bf16* __restrict__ Wv2t,
    const int* __restrict__ node_types, const int* __restrict__ node_agents,
    const float* __restrict__ type_embed, const float* __restrict__ gagent_embed,
    const float* __restrict__ W_l0, const float* __restrict__ b_l0,
    const float* __restrict__ g_l0, const float* __restrict__ be_l0,
    float* __restrict__ h0, float* __restrict__ agg, float* __restrict__ deg) {
  __shared__ float shb[32 * 33];
  const int bid = blockIdx.x, tid = threadIdx.x;
  if (bid < 8192) {
    // conv_joint: joint[b][a*512+k] = bf16(obs[a][b][k])
    size_t i = ((size_t)bid * 256 + tid) * 8;
    int a = (int)(i >> 21);
    int rem = (int)(i & ((1u << 21) - 1));
    int b = rem >> 9, k = rem & 511;
    const float* p = obs + i;
    short8 o;
#pragma unroll
    for (int t = 0; t < 8; t++) o[t] = (short)f2bu(p[t]);
    *(short8*)(joint + (size_t)b * 4096 + a * 512 + k) = o;
  } else if (bid < 14912) {
    // wtrans: Wt[n][k] = bf16(W[k][n])
    int b = bid - 8192;
    const float* W;
    bf16* Wt;
    int K, N;
    if (b < 512) { W = Wp1; Wt = Wp1t; K = 512; N = 1024; }
    else if (b < 1536) { W = Wp2; Wt = Wp2t; K = 1024; N = 1024; b -= 512; }
    else if (b < 1600) { W = Wp3; Wt = Wp3t; K = 1024; N = 64; b -= 1536; }
    else if (b < 5696) { W = Wv1; Wt = Wv1t; K = 4096; N = 1024; b -= 1600; }
    else { W = Wv2; Wt = Wv2t; K = 1024; N = 1024; b -= 5696; }
    int nx = N >> 5;
    int n0 = (b % nx) * 32, k0 = (b / nx) * 32;
    int tx = tid & 31, ty = tid >> 5;
    float(*t2)[33] = (float(*)[33])shb;
#pragma unroll
    for (int r = ty; r < 32; r += 8) t2[r][tx] = W[(size_t)(k0 + r) * N + n0 + tx];
    __syncthreads();
#pragma unroll
    for (int r = ty; r < 32; r += 8)
      Wt[(size_t)(n0 + r) * K + k0 + tx] = __float2bfloat16(t2[tx][r]);
  } else {
    // gnn_l0: 4 nodes per block (one wave each) + agg/deg zeroing
    int nb = bid - 14912;
    int w = tid >> 6, t = tid & 63;
    int n = nb * 4 + w;
    float* xx = shb + w * 64;
    int ty2 = node_types[n], ag = node_agents[n];
    xx[t] = (t < 32) ? type_embed[ty2 * 32 + t] : gagent_embed[ag * 32 + (t - 32)];
    agg[(size_t)n * 64 + t] = 0.f;
    if (t == 0) deg[n] = 0.f;
    __syncthreads();
    float acc = b_l0[t];
#pragma unroll 8
    for (int i = 0; i < 64; i++) acc += xx[i] * W_l0[i * 64 + t];
    acc = fmaxf(acc, 0.f);
    float m = wsum(acc) * (1.f / 64.f);
    float d = acc - m;
    float v = wsum(d * d) * (1.f / 64.f);
    h0[(size_t)n * 64 + t] = d * rsqrtf(v + 1e-5f) * g_l0[t] + be_l0[t];
  }
}

__global__ void edge_k(const int* __restrict__ edges, const float* __restrict__ h0,
                       float* __restrict__ agg, float* __restrict__ deg) {
  int idx = blockIdx.x * 256 + threadIdx.x;
  if (idx >= E_ * 64) return;
  int e = idx >> 6, c = idx & 63;
  int s = edges[e * 2 + 0], d = edges[e * 2 + 1];
  atomicAdd(&agg[(size_t)d * 64 + c], h0[(size_t)s * 64 + c]);
  atomicAdd(&agg[(size_t)s * 64 + c], h0[(size_t)d * 64 + c]);
  if (c == 0) { atomicAdd(&deg[d], 1.f); atomicAdd(&deg[s], 1.f); }
}

__global__ __launch_bounds__(256) void gnn_l1_k(
    const float* __restrict__ h0, const float* __restrict__ agg, const float* __restrict__ deg,
    const float* __restrict__ W, const float* __restrict__ b, const float* __restrict__ g,
    const float* __restrict__ be, float* __restrict__ h1) {
  __shared__ float x[4][128];
  int w = threadIdx.x >> 6, t = threadIdx.x & 63;
  int n = blockIdx.x * 4 + w;
  x[w][t] = h0[(size_t)n * 64 + t];
  x[w][64 + t] = agg[(size_t)n * 64 + t] / fmaxf(deg[n], 1.0f);
  __syncthreads();
  float acc = b[t];
#pragma unroll 8
  for (int i = 0; i < 128; i++) acc += x[w][i] * W[i * 64 + t];
  acc = fmaxf(acc, 0.f);
  float m = wsum(acc) * (1.f / 64.f);
  float d = acc - m;
  float v = wsum(d * d) * (1.f / 64.f);
  h1[(size_t)n * 64 + t] = d * rsqrtf(v + 1e-5f) * g[t] + be[t];
}

__global__ void colmean_k(const float* __restrict__ h1, float* __restrict__ meanv) {
  int c = blockIdx.x, t = threadIdx.x;
  float s = 0.f;
  for (int n = t; n < N_; n += 256) s += h1[(size_t)n * 64 + c];
  __shared__ float red[256];
  red[t] = s;
  __syncthreads();
  for (int off = 128; off >= 1; off >>= 1) {
    if (t < off) red[t] += red[t + off];
    __syncthreads();
  }
  if (t == 0) meanv[c] = red[0] / (float)N_;
}

// fused: ge recompute + biasA (blocks 0-31) / biasV (32-35); also inits value[row] = bv3[0]
__global__ void fused_bias_k(const float* __restrict__ meanv, const float* __restrict__ Wgp,
                             const float* __restrict__ bgp, const float* __restrict__ agent_embed,
                             const float* __restrict__ Wp1, const float* __restrict__ bp1,
                             const float* __restrict__ Wv1, const float* __restrict__ bv1,
                             const float* __restrict__ bv3,
                             float* __restrict__ biasA, float* __restrict__ biasV,
                             float* __restrict__ value) {
  __shared__ float ge[64];
  int t = threadIdx.x;
  int gidx = blockIdx.x * 256 + t;
  if (gidx < B_) value[gidx] = bv3[0];  // V3 accumulator init (re-done every launch)
  if (t < 64) {
    float s = bgp[t];
    for (int g2 = 0; g2 < 64; g2++) s += meanv[g2] * Wgp[g2 * 64 + t];
    ge[t] = s;
  }
  __syncthreads();
  int blk = blockIdx.x;
  if (blk < 32) {
    int idx = blk * 256 + t;
    int a = idx >> 10, o = idx & 1023;
    float s = bp1[o];
    for (int g2 = 0; g2 < 64; g2++) s += ge[g2] * Wp1[(size_t)(512 + g2) * 1024 + o];
    for (int e = 0; e < 16; e++) s += agent_embed[a * 16 + e] * Wp1[(size_t)(576 + e) * 1024 + o];
    biasA[idx] = s;
  } else {
    int o = (blk - 32) * 256 + t;
    float s = bv1[o];
    for (int g2 = 0; g2 < 64; g2++) s += ge[g2] * Wv1[(size_t)(4096 + g2) * 1024 + o];
    biasV[o] = s;
  }
}

// ======== g11_k: 256x256, BK=64, double buffer, 4 phases/K-tile, COUNTED vmcnt (R9-best) ====
#define BARR()                        \
  asm volatile("" ::: "memory");      \
  __builtin_amdgcn_s_barrier();       \
  asm volatile("" ::: "memory")

#define RD8(off) (*(const short8*)(sb + (off)))

#define MMQ(FI0)                                                                     \
  __builtin_amdgcn_s_setprio(1);                                                     \
  acc[FI0 + 0][0] = __builtin_amdgcn_mfma_f32_16x16x32_bf16(a0, b0, acc[FI0 + 0][0], 0, 0, 0); \
  acc[FI0 + 0][1] = __builtin_amdgcn_mfma_f32_16x16x32_bf16(a0, b1, acc[FI0 + 0][1], 0, 0, 0); \
  acc[FI0 + 0][2] = __builtin_amdgcn_mfma_f32_16x16x32_bf16(a0, b2, acc[FI0 + 0][2], 0, 0, 0); \
  acc[FI0 + 0][3] = __builtin_amdgcn_mfma_f32_16x16x32_bf16(a0, b3, acc[FI0 + 0][3], 0, 0, 0); \
  acc[FI0 + 1][0] = __builtin_amdgcn_mfma_f32_16x16x32_bf16(a1, b0, acc[FI0 + 1][0], 0, 0, 0); \
  acc[FI0 + 1][1] = __builtin_amdgcn_mfma_f32_16x16x32_bf16(a1, b1, acc[FI0 + 1][1], 0, 0, 0); \
  acc[FI0 + 1][2] = __builtin_amdgcn_mfma_f32_16x16x32_bf16(a1, b2, acc[FI0 + 1][2], 0, 0, 0); \
  acc[FI0 + 1][3] = __builtin_amdgcn_mfma_f32_16x16x32_bf16(a1, b3, acc[FI0 + 1][3], 0, 0, 0); \
  acc[FI0 + 2][0] = __builtin_amdgcn_mfma_f32_16x16x32_bf16(a2, b0, acc[FI0 + 2][0], 0, 0, 0); \
  acc[FI0 + 2][1] = __builtin_amdgcn_mfma_f32_16x16x32_bf16(a2, b1, acc[FI0 + 2][1], 0, 0, 0); \
  acc[FI0 + 2][2] = __builtin_amdgcn_mfma_f32_16x16x32_bf16(a2, b2, acc[FI0 + 2][2], 0, 0, 0); \
  acc[FI0 + 2][3] = __builtin_amdgcn_mfma_f32_16x16x32_bf16(a2, b3, acc[FI0 + 2][3], 0, 0, 0); \
  acc[FI0 + 3][0] = __builtin_amdgcn_mfma_f32_16x16x32_bf16(a3, b0, acc[FI0 + 3][0], 0, 0, 0); \
  acc[FI0 + 3][1] = __builtin_amdgcn_mfma_f32_16x16x32_bf16(a3, b1, acc[FI0 + 3][1], 0, 0, 0); \
  acc[FI0 + 3][2] = __builtin_amdgcn_mfma_f32_16x16x32_bf16(a3, b2, acc[FI0 + 3][2], 0, 0, 0); \
  acc[FI0 + 3][3] = __builtin_amdgcn_mfma_f32_16x16x32_bf16(a3, b3, acc[FI0 + 3][3], 0, 0, 0); \
  __builtin_amdgcn_s_setprio(0)

template <int AMODE, int BIASMODE, bool RELU, typename TC>
__launch_bounds__(512, 1)
__global__ void g11_k(const bf16* __restrict__ Ap, const bf16* __restrict__ Bt,
                      const float* __restrict__ biasp, TC* __restrict__ Cp,
                      int M, int N, int K) {
  constexpr int SBUF = 65536;
  __shared__ char smem[2 * SBUF];

  const int tid = threadIdx.x;
  const int wid = tid >> 6, lane = tid & 63;
  const int wm = wid >> 2, wn = wid & 3;
  const int l15 = lane & 15;

  const int nwg = gridDim.x * gridDim.y;
  int fid = blockIdx.y * gridDim.x + blockIdx.x;
  int swz = (fid & 7) * (nwg >> 3) + (fid >> 3);
  const int m0 = (swz / gridDim.x) * 256;
  const int n0 = (swz % gridDim.x) * 256;

  f32x4 acc[8][4];
#pragma unroll
  for (int i = 0; i < 8; i++)
#pragma unroll
    for (int j = 0; j < 4; j++) acc[i][j] = (f32x4){0.f, 0.f, 0.f, 0.f};

  const bf16* pg[8];
  {
    int srow = tid >> 3;
    int c = (tid & 7) ^ (srow & 7);
#pragma unroll
    for (int g = 0; g < 4; ++g) {
      int r = m0 + g * 64 + srow;
      if (AMODE == 0)
        pg[g] = Ap + (size_t)r * K + c * 8;
      else
        pg[g] = Ap + (((size_t)(r & (B_ - 1))) << 12) + ((size_t)(r >> 12) << 9) + c * 8;
    }
#pragma unroll
    for (int g = 4; g < 8; ++g) {
      int r = n0 + (g - 4) * 64 + srow;
      pg[g] = Bt + (size_t)r * K + c * 8;
    }
  }

  const int slot0 = (lane >> 4) ^ (l15 & 7);
  const int aof0 = (wm * 128 + l15) * 128 + slot0 * 16;
  const int bof0 = 32768 + (wn * 64 + l15) * 128 + slot0 * 16;
  const int aof1 = aof0 ^ 64;
  const int bof1 = bof0 ^ 64;

#define STG(g, buf)                                                    \
  {                                                                    \
    gload_lds16(pg[g], smem + (buf) * SBUF + (g) * 8192 + wid * 1024); \
    pg[g] += 64;                                                       \
  }

  STG(0, 0) STG(2, 0) STG(4, 0) STG(5, 0) STG(6, 0) STG(7, 0) STG(1, 0) STG(3, 0)
  waitvm<0>();
  BARR();

  const int nt = K >> 6;
  for (int t = 0; t < nt; ++t) {
    const int cb = t & 1, ob = cb ^ 1;
    const bool last = (t == nt - 1);
    const char* sb = smem + cb * SBUF;
    short8 a0, a1, a2, a3, b0, b1, b2, b3;
    a0 = RD8(aof0 + 0 * 2048); a1 = RD8(aof0 + 1 * 2048);
    a2 = RD8(aof0 + 2 * 2048); a3 = RD8(aof0 + 3 * 2048);
    b0 = RD8(bof0 + 0 * 2048); b1 = RD8(bof0 + 1 * 2048);
    b2 = RD8(bof0 + 2 * 2048); b3 = RD8(bof0 + 3 * 2048);
    if (!last) { STG(0, ob) STG(2, ob) }
    BARR();
    MMQ(0);
    if (last) waitvm<0>(); else waitvm<2>();
    BARR();
    a0 = RD8(aof0 + 4 * 2048); a1 = RD8(aof0 + 5 * 2048);
    a2 = RD8(aof0 + 6 * 2048); a3 = RD8(aof0 + 7 * 2048);
    if (!last) { STG(4, ob) STG(5, ob) }
    BARR();
    MMQ(4);
    BARR();
    a0 = RD8(aof1 + 0 * 2048); a1 = RD8(aof1 + 1 * 2048);
    a2 = RD8(aof1 + 2 * 2048); a3 = RD8(aof1 + 3 * 2048);
    b0 = RD8(bof1 + 0 * 2048); b1 = RD8(bof1 + 1 * 2048);
    b2 = RD8(bof1 + 2 * 2048); b3 = RD8(bof1 + 3 * 2048);
    if (!last) { STG(6, ob) STG(7, ob) }
    BARR();
    MMQ(0);
    BARR();
    a0 = RD8(aof1 + 4 * 2048); a1 = RD8(aof1 + 5 * 2048);
    a2 = RD8(aof1 + 6 * 2048); a3 = RD8(aof1 + 7 * 2048);
    if (!last) { STG(1, ob) STG(3, ob) }
    BARR();
    MMQ(4);
    if (!last) waitvm<2>(); else waitvm<0>();
    BARR();
  }
#undef STG

#pragma unroll
  for (int i = 0; i < 8; ++i) {
    int rb = m0 + wm * 128 + i * 16 + (lane >> 4) * 4;
#pragma unroll
    for (int j = 0; j < 4; ++j) {
      int col = n0 + wn * 64 + j * 16 + l15;
#pragma unroll
      for (int r = 0; r < 4; r++) {
        int row = rb + r;
        float bias = (BIASMODE == 0) ? biasp[col] : biasp[((row >> 12) << 10) + col];
        float v = acc[i][j][r] + bias;
        if (RELU) v = fmaxf(v, 0.f);
        storeC(&Cp[(size_t)row * N + col], v);
      }
    }
  }
}

// ---------------- MFMA GEMM: DEPTH-deep multi-buffer pipeline, counted vmcnt ----------------
// VOUT=1: instead of storing C, accumulate value[row] += relu(C[row,:]+bias) . Wv3 (fused V3)
template <int FM, int FN, int WAVES_M, int WAVES_N, int DEPTH, int AMODE, int BIASMODE, bool RELU,
          typename TC, int VOUT = 0>
__launch_bounds__(WAVES_M * WAVES_N * 64, 2)
__global__ void pgemm_k(const bf16* __restrict__ Ap, const bf16* __restrict__ Bt,
                        const float* __restrict__ biasp, TC* __restrict__ Cp,
                        int M, int N, int K,
                        const float* __restrict__ Wv3 = nullptr,
                        float* __restrict__ vout = nullptr) {
  constexpr int NTHR = WAVES_M * WAVES_N * 64;
  constexpr int AR = WAVES_M * FM * 16;
  constexpr int BR = WAVES_N * FN * 16;
  constexpr int RPG = NTHR / 4;
  constexpr int AG = AR / RPG;
  constexpr int BG = BR / RPG;
  constexpr int G = AG + BG;
  constexpr int GRP = NTHR * 16;
  constexpr int ABYTES = AR * 64;
  constexpr int SBUF = (AR + BR) * 64;
  constexpr int NB = DEPTH + 1;
  __shared__ char smem[NB * SBUF];

  const int tid = threadIdx.x;
  const int wid = tid >> 6, lane = tid & 63;
  const int wm = wid / WAVES_N, wn = wid % WAVES_N;
  const int l15 = lane & 15;

  const int nwg = gridDim.x * gridDim.y;
  int fid = blockIdx.y * gridDim.x + blockIdx.x;
  int swz = (fid & 7) * (nwg >> 3) + (fid >> 3);
  const int m0 = (swz / gridDim.x) * AR;
  const int n0 = (swz % gridDim.x) * BR;

  f32x4 acc[FM][FN];
#pragma unroll
  for (int i = 0; i < FM; i++)
#pragma unroll
    for (int j = 0; j < FN; j++) acc[i][j] = (f32x4){0.f, 0.f, 0.f, 0.f};

  const bf16* pa[AG];
  const bf16* pb[BG];
  {
    int row = tid >> 2;
    int c = (tid & 3) ^ ((tid >> 3) & 3);
#pragma unroll
    for (int q = 0; q < AG; ++q) {
      int r = m0 + q * RPG + row;
      if (AMODE == 0)
        pa[q] = Ap + (size_t)r * K + c * 8;
      else
        pa[q] = Ap + (((size_t)(r & (B_ - 1))) << 12) + ((size_t)(r >> 12) << 9) + c * 8;
    }
#pragma unroll
    for (int q = 0; q < BG; ++q) {
      int r = n0 + q * RPG + row;
      pb[q] = Bt + (size_t)r * K + c * 8;
    }
  }

  const int cA = (lane >> 4) ^ ((l15 >> 1) & 3);
  const int offA0 = (wm * FM * 16 + l15) * 64 + cA * 16;
  const int offB0 = ABYTES + (wn * FN * 16 + l15) * 64 + cA * 16;

  auto stage = [&](int buf) {
    char* base = smem + buf * SBUF;
#pragma unroll
    for (int q = 0; q < AG; ++q) {
      gload_lds16(pa[q], base + q * GRP + wid * 1024);
      pa[q] += 32;
    }
#pragma unroll
    for (int q = 0; q < BG; ++q) {
      gload_lds16(pb[q], base + ABYTES + q * GRP + wid * 1024);
      pb[q] += 32;
    }
  };

  auto comp = [&](int buf) {
    const char* sb = smem + buf * SBUF;
    short8 bfr[FN];
#pragma unroll
    for (int j = 0; j < FN; ++j) bfr[j] = *(const short8*)(sb + offB0 + j * 1024);
    constexpr int FH = (FM > 4) ? FM / 2 : FM;
#pragma unroll
    for (int h = 0; h < FM / FH; ++h) {
      short8 afr[FH];
#pragma unroll
      for (int i = 0; i < FH; ++i) afr[i] = *(const short8*)(sb + offA0 + (h * FH + i) * 1024);
      __builtin_amdgcn_s_setprio(1);
#pragma unroll
      for (int i = 0; i < FH; ++i)
#pragma unroll
        for (int j = 0; j < FN; ++j)
          acc[h * FH + i][j] =
              __builtin_amdgcn_mfma_f32_16x16x32_bf16(afr[i], bfr[j], acc[h * FH + i][j], 0, 0, 0);
      __builtin_amdgcn_s_setprio(0);
    }
  };

  const int nt = K >> 5;
#pragma unroll
  for (int q = 0; q < DEPTH; ++q) stage(q);
  int cbuf = 0, sbi = DEPTH;
  for (int T = 0; T < nt - DEPTH; ++T) {
    stage(sbi);
    if (++sbi == NB) sbi = 0;
    waitvm<DEPTH * G>();
    __builtin_amdgcn_s_barrier();
    asm volatile("" ::: "memory");
    comp(cbuf);
    if (++cbuf == NB) cbuf = 0;
    asm volatile("" ::: "memory");
    __builtin_amdgcn_s_barrier();
  }
#define DRAIN(d)                       \
  {                                    \
    waitvm<(d) * G>();                 \
    __builtin_amdgcn_s_barrier();      \
    asm volatile("" ::: "memory");     \
    comp(cbuf);                        \
    if (++cbuf == NB) cbuf = 0;        \
    asm volatile("" ::: "memory");     \
  }
  if constexpr (DEPTH == 4) { DRAIN(3) DRAIN(2) }
  DRAIN(1)
  DRAIN(0)
#undef DRAIN

#pragma unroll
  for (int i = 0; i < FM; ++i) {
    int rb = m0 + wm * FM * 16 + i * 16 + (lane >> 4) * 4;
    if constexpr (VOUT) {
      // fused V3: per-row dot with Wv3, reduce across the 16 l15-lanes, one atomic per row/wave
#pragma unroll
      for (int r = 0; r < 4; r++) {
        int row = rb + r;
        float s = 0.f;
#pragma unroll
        for (int j = 0; j < FN; ++j) {
          int col = n0 + wn * FN * 16 + j * 16 + l15;
          float v = acc[i][j][r] + biasp[col];
          if (RELU) v = fmaxf(v, 0.f);
          s += v * Wv3[col];
        }
        s += __shfl_xor(s, 1, 64);
        s += __shfl_xor(s, 2, 64);
        s += __shfl_xor(s, 4, 64);
        s += __shfl_xor(s, 8, 64);
        if (l15 == 0) atomicAdd(&vout[row], s);
      }
    } else {
#pragma unroll
      for (int j = 0; j < FN; ++j) {
        int col = n0 + wn * FN * 16 + j * 16 + l15;
#pragma unroll
        for (int r = 0; r < 4; r++) {
          int row = rb + r;
          float bias = (BIASMODE == 0) ? biasp[col] : biasp[((row >> 12) << 10) + col];
          float v = acc[i][j][r] + bias;
          if (RELU) v = fmaxf(v, 0.f);
          storeC(&Cp[(size_t)row * N + col], v);
        }
      }
    }
  }
}

extern "C" void kernel_launch(void* const* d_in, const int* in_sizes, int n_in,
                              void* d_out, int out_size, void* d_ws, size_t ws_size,
                              hipStream_t stream) {
  const float* obs = (const float*)d_in[0];
  const int* node_types = (const int*)d_in[1];
  const int* node_agents = (const int*)d_in[2];
  const int* edges = (const int*)d_in[3];
  const float* type_embed = (const float*)d_in[4];
  const float* gagent_embed = (const float*)d_in[5];
  const float* W_l0 = (const float*)d_in[6];
  const float* b_l0 = (const float*)d_in[7];
  const float* g_l0 = (const float*)d_in[8];
  const float* be_l0 = (const float*)d_in[9];
  const float* W_l1 = (const float*)d_in[10];
  const float* b_l1 = (const float*)d_in[11];
  const float* g_l1 = (const float*)d_in[12];
  const float* be_l1 = (const float*)d_in[13];
  const float* W_gp = (const float*)d_in[14];
  const float* b_gp = (const float*)d_in[15];
  const float* agent_embed = (const float*)d_in[16];
  const float* Wp1 = (const float*)d_in[17];
  const float* bp1 = (const float*)d_in[18];
  const float* Wp2 = (const float*)d_in[19];
  const float* bp2 = (const float*)d_in[20];
  const float* Wp3 = (const float*)d_in[21];
  const float* bp3 = (const float*)d_in[22];
  const float* Wv1 = (const float*)d_in[23];
  const float* bv1 = (const float*)d_in[24];
  const float* Wv2 = (const float*)d_in[25];
  const float* bv2 = (const float*)d_in[26];
  const float* Wv3 = (const float*)d_in[27];
  const float* bv3 = (const float*)d_in[28];

  char* wsp = (char*)d_ws;
  auto alloc = [&](size_t bytes) {
    char* p = wsp;
    wsp += (bytes + 255) & ~(size_t)255;
    return p;
  };
  float* h0 = (float*)alloc((size_t)N_ * 64 * 4);
  float* agg = (float*)alloc((size_t)N_ * 64 * 4);
  float* deg = (float*)alloc((size_t)N_ * 4);
  float* h1 = (float*)alloc((size_t)N_ * 64 * 4);
  float* meanv = (float*)alloc(64 * 4);
  float* biasA = (float*)alloc(8 * 1024 * 4);
  float* biasV = (float*)alloc(1024 * 4);
  bf16* joint = (bf16*)alloc((size_t)4096 * 4096 * 2);
  bf16* Wp1t = (bf16*)alloc((size_t)1024 * 512 * 2);
  bf16* Wp2t = (bf16*)alloc((size_t)1024 * 1024 * 2);
  bf16* Wp3t = (bf16*)alloc((size_t)64 * 1024 * 2);
  bf16* Wv1t = (bf16*)alloc((size_t)1024 * 4096 * 2);
  bf16* Wv2t = (bf16*)alloc((size_t)1024 * 1024 * 2);
  bf16* C1 = (bf16*)alloc((size_t)32768 * 1024 * 2);
  bf16* C2 = (bf16*)alloc((size_t)32768 * 1024 * 2);
  bf16* hv = (bf16*)alloc((size_t)4096 * 1024 * 2);

  float* logits = (float*)d_out;
  float* value = (float*)d_out + (size_t)A_ * B_ * ACT_;

  // prep: conv_joint + 5x wtrans + gnn_l0 (co-scheduled in one launch)
  prep_k<<<17412, 256, 0, stream>>>(obs, joint, Wp1, Wp1t, Wp2, Wp2t, Wp3, Wp3t, Wv1, Wv1t, Wv2,
                                    Wv2t, node_types, node_agents, type_embed, gagent_embed, W_l0,
                                    b_l0, g_l0, be_l0, h0, agg, deg);
  edge_k<<<(E_ * 64) / 256, 256, 0, stream>>>(edges, h0, agg, deg);
  gnn_l1_k<<<N_ / 4, 256, 0, stream>>>(h0, agg, deg, W_l1, b_l1, g_l1, be_l1, h1);
  colmean_k<<<64, 256, 0, stream>>>(h1, meanv);
  fused_bias_k<<<36, 256, 0, stream>>>(meanv, W_gp, b_gp, agent_embed, Wp1, bp1, Wv1, bv1, bv3,
                                       biasA, biasV, value);

  // P1: C1 = relu(obs2d @ Wp1[0:512] + biasA[agent])  M=32768 N=1024 K=512, g11 256x256 BK64
  g11_k<1, 1, true, bf16>
      <<<dim3(4, 128), 512, 0, stream>>>(joint, Wp1t, biasA, C1, 32768, 1024, 512);
  // P2: C2 = relu(C1 @ Wp2 + bp2)                     M=32768 N=1024 K=1024, g11 256x256 BK64
  g11_k<0, 0, true, bf16>
      <<<dim3(4, 128), 512, 0, stream>>>(C1, Wp2t, bp2, C2, 32768, 1024, 1024);
  // P3: logits = C2 @ Wp3 + bp3                       M=32768 N=64 K=1024, 128x64, D4
  pgemm_k<4, 2, 2, 2, 4, 0, 0, false, float>
      <<<dim3(1, 256), 256, 0, stream>>>(C2, Wp3t, bp3, logits, 32768, 64, 1024);
  // V1: hv = relu(joint @ Wv1 + biasV)                M=4096 N=1024 K=4096, 128x128, 8 waves, D4
  pgemm_k<4, 2, 2, 4, 4, 0, 0, true, bf16>
      <<<dim3(8, 32), 512, 0, stream>>>(joint, Wv1t, biasV, hv, 4096, 1024, 4096);
  // V2+V3 fused: value += relu(hv @ Wv2 + bv2) . Wv3  (value pre-initialized to bv3)
  pgemm_k<4, 2, 2, 4, 4, 0, 0, true, bf16, 1>
      <<<dim3(8, 32), 512, 0, stream>>>(hv, Wv2t, bv2, (bf16*)nullptr, 4096, 1024, 1024, Wv3,
                                        value);
}